// Round 6
// baseline (4050.723 us; speedup 1.0000x reference)
//
#include <hip/hip_runtime.h>

// ---------------------------------------------------------------------------
// GCNConvNet: 2x GIN conv (shared aggregation) + dense head. fp32 I/O,
// bf16 MFMA internally (harness grants bf16 tolerance).
// Round 14: r13 NaN root-cause = pre-read BEFORE s_barrier read other waves'
// T+1 staging (vmcnt(0) only drains own wave; cross-wave LDS needs
// vmcnt(0) -> barrier -> read). v5: boundary (vmcnt(0)+s_barrier) moved
// BETWEEN C2 and C3; pre-read of T+1's B+A-C0 now after the barrier but
// under C3's 16-MFMA shadow. Second B register set (bF/bG alternate, loop
// unrolled x2, NT even: K%128==0) since C3 still consumes current B.
// Hazards re-audited: staging T+2 (top of T+1) writes buf T&1 whose last
// readers precede T's boundary barrier; one barrier per tile preserved.
// ---------------------------------------------------------------------------

#define NN 60000
#define NE 960000
#define C_IN 128
#define HID 512
#define DCAT 1024
#define DFC 2048
#define DL1 4096
#define OUTC 64

typedef __bf16 bf16x8 __attribute__((ext_vector_type(8)));
typedef float floatx4 __attribute__((ext_vector_type(4)));

__device__ __forceinline__ unsigned short f2b(float f) {
  unsigned int u = __float_as_uint(f);
  unsigned int r = (u + 0x7fffu + ((u >> 16) & 1u)) >> 16;  // RNE, finite inputs
  return (unsigned short)r;
}

// async global->LDS, 16B per lane; LDS dest = wave-uniform base + lane*16
#define GLOAD_LDS16(g, l)                                                     \
  __builtin_amdgcn_global_load_lds(                                           \
      (__attribute__((address_space(1))) void*)(g),                           \
      (__attribute__((address_space(3))) void*)(l), 16, 0, 0)

// ---------------------------------------------------------------------------
__global__ void k_bnparams(const float* __restrict__ g,
                           const float* __restrict__ be,
                           const float* __restrict__ mn,
                           const float* __restrict__ vr,
                           const float* __restrict__ b1,
                           float* __restrict__ scale, float* __restrict__ shift) {
  int i = blockIdx.x * 256 + threadIdx.x;
  if (i < HID) {
    float s = g[i] * rsqrtf(vr[i] + 1e-5f);
    scale[i] = s;
    shift[i] = (b1[i] - mn[i]) * s + be[i];
  }
}

// fp32 [K,N] -> bf16 [N,K] transpose+downcast, 32x32 tiles
__global__ void k_transpose(const float* __restrict__ in,
                            unsigned short* __restrict__ out, int K, int N) {
  __shared__ float t[32][33];
  int n0 = blockIdx.x * 32, k0 = blockIdx.y * 32;
  int tx = threadIdx.x & 31, ty = threadIdx.x >> 5;  // 32 x 8
#pragma unroll
  for (int i = 0; i < 32; i += 8)
    t[ty + i][tx] = in[(size_t)(k0 + ty + i) * N + n0 + tx];
  __syncthreads();
#pragma unroll
  for (int i = 0; i < 32; i += 8)
    out[(size_t)(n0 + ty + i) * K + k0 + tx] = f2b(t[tx][ty + i]);
}

// ---------------------------------------------------------------------------
// CSR build: deg -> exclusive scan (3 kernels) -> bucket src ids -> gather.
__global__ void k_deg(const int* __restrict__ dst, int* __restrict__ deg) {
  int e = blockIdx.x * 256 + threadIdx.x;
  if (e < NE) atomicAdd(&deg[dst[e]], 1);
}

__global__ void k_scan1(const int* __restrict__ deg, int* __restrict__ offs,
                        int* __restrict__ bsum) {
  __shared__ int t[256];
  int i = blockIdx.x * 256 + threadIdx.x;
  int v = (i < NN) ? deg[i] : 0;
  t[threadIdx.x] = v;
  __syncthreads();
#pragma unroll
  for (int d = 1; d < 256; d <<= 1) {
    int add = (threadIdx.x >= d) ? t[threadIdx.x - d] : 0;
    __syncthreads();
    t[threadIdx.x] += add;
    __syncthreads();
  }
  if (i < NN) offs[i] = t[threadIdx.x] - v;
  if (threadIdx.x == 255) bsum[blockIdx.x] = t[255];
}

__global__ void k_scan2(int* __restrict__ bsum, int nb) {
  __shared__ int t[256];
  int v = (threadIdx.x < nb) ? bsum[threadIdx.x] : 0;
  t[threadIdx.x] = v;
  __syncthreads();
#pragma unroll
  for (int d = 1; d < 256; d <<= 1) {
    int add = (threadIdx.x >= d) ? t[threadIdx.x - d] : 0;
    __syncthreads();
    t[threadIdx.x] += add;
    __syncthreads();
  }
  if (threadIdx.x < nb) bsum[threadIdx.x] = t[threadIdx.x] - v;
}

__global__ void k_scan3(int* __restrict__ offs, const int* __restrict__ bsum,
                        int* __restrict__ cursor) {
  int i = blockIdx.x * 256 + threadIdx.x;
  if (i < NN) {
    int o = offs[i] + bsum[blockIdx.x];
    offs[i] = o;
    cursor[i] = o;
  }
  if (i == 0) offs[NN] = NE;
}

__global__ void k_bucket(const int* __restrict__ src, const int* __restrict__ dst,
                         int* __restrict__ cursor, int* __restrict__ esrc) {
  int e = blockIdx.x * 256 + threadIdx.x;
  if (e < NE) {
    int slot = atomicAdd(&cursor[dst[e]], 1);
    esrc[slot] = src[e];
  }
}

// one wave per node: h0[node] = bf16(x[node] + sum_j x[esrc[j]]), f32 accum
__global__ void k_agg(const float2* __restrict__ x2, const int* __restrict__ offs,
                      const int* __restrict__ esrc, unsigned int* __restrict__ h0u) {
  int node = blockIdx.x * 4 + (threadIdx.x >> 6);
  if (node >= NN) return;
  int lane = threadIdx.x & 63;
  int beg = offs[node], end = offs[node + 1];
  float2 acc = x2[(size_t)node * 64 + lane];
  for (int j = beg; j < end; j++) {
    int s = esrc[j];  // wave-uniform -> broadcast load
    float2 v = x2[(size_t)s * 64 + lane];
    acc.x += v.x;
    acc.y += v.y;
  }
  h0u[(size_t)node * 64 + lane] =
      (unsigned)f2b(acc.x) | ((unsigned)f2b(acc.y) << 16);
}

// ---------------------------------------------------------------------------
// shared epilogue (k_gemm_g): C/D layout col=lane&15, row=quad*4+reg
template <int EPI>
__device__ __forceinline__ void gemm_epilogue(
    floatx4 (&acc)[8][4], unsigned short* C, const float* bias,
    const float* scale, const float* shift, int M, int N, int ldc, int m0,
    int n0, int w, int quad, int r16) {
#pragma unroll
  for (int j = 0; j < 4; j++) {
    int gn = n0 + w * 64 + j * 16 + r16;
    int cn = gn < N ? gn : 0;
    float p0, p1 = 0.f;
    if constexpr (EPI == 2) {
      p0 = scale[cn];
      p1 = shift[cn];
    } else {
      p0 = bias[cn];
    }
#pragma unroll
    for (int i = 0; i < 8; i++) {
#pragma unroll
      for (int t = 0; t < 4; t++) {
        int gm = m0 + i * 16 + quad * 4 + t;
        if (gm < M && gn < N) {
          float v = acc[i][j][t];
          if constexpr (EPI == 0) {
            v += p0;
            C[(size_t)gm * ldc + gn] = f2b(v);
          } else if constexpr (EPI == 1) {
            v += p0; v = v > 0.f ? v : 0.f;
            C[(size_t)gm * ldc + gn] = f2b(v);
          } else if constexpr (EPI == 2) {
            v = v * p0 + p1; v = v > 0.f ? v : 0.f;
            C[(size_t)gm * ldc + gn] = f2b(v);
          } else if constexpr (EPI == 3) {
            v += p0; v = v > 0.f ? v : 0.01f * v;
            C[(size_t)gm * ldc + gn] = f2b(v);
          } else {  // sigmoid -> fp32 network output
            v += p0;
            v = 1.f / (1.f + __expf(-v));
            ((float*)C)[(size_t)gm * ldc + gn] = v;
          }
        }
      }
    }
  }
}

__device__ __forceinline__ void gemm_swizzle(int M, int N, int& m0, int& n0) {
  const int mt_total = (M + 127) >> 7, nt_total = (N + 255) >> 8;
  int mt, nt;
  if ((nt_total & 7) == 0) {
    const int ntpx = nt_total >> 3;
    const int x = blockIdx.x & 7;
    const int s = blockIdx.x >> 3;
    nt = x * ntpx + (s % ntpx);
    mt = s / ntpx;
  } else {
    const int GM = 8;
    const int full = (mt_total / GM) * GM;
    const int boundary = full * nt_total;
    int id = blockIdx.x;
    if (id < boundary) {
      int per_group = GM * nt_total;
      int g = id / per_group, r = id % per_group;
      mt = g * GM + r % GM;
      nt = r / GM;
    } else {
      int r = id - boundary, gm = mt_total - full;
      mt = full + r % gm;
      nt = r / gm;
    }
  }
  m0 = mt << 7;
  n0 = nt << 8;
}

__device__ __forceinline__ void gemm_swizzle256(int M, int N, int& m0, int& n0) {
  const int mt_total = (M + 255) >> 8, nt_total = N >> 8;
  int mt, nt;
  if ((nt_total & 7) == 0) {
    const int ntpx = nt_total >> 3;
    const int x = blockIdx.x & 7;
    const int s = blockIdx.x >> 3;
    nt = x * ntpx + (s % ntpx);
    mt = s / ntpx;
  } else {
    const int GM = 8;
    const int full = (mt_total / GM) * GM;
    const int boundary = full * nt_total;
    int id = blockIdx.x;
    if (id < boundary) {
      int per_group = GM * nt_total;
      int g = id / per_group, r = id % per_group;
      mt = g * GM + r % GM;
      nt = r / GM;
    } else {
      int r = id - boundary, gm = mt_total - full;
      mt = full + r % gm;
      nt = r / gm;
    }
  }
  m0 = mt << 8;
  n0 = nt << 8;
}

// ---------------------------------------------------------------------------
// k_gemm_g (r8 verified): B direct global->reg; A via 4-stage glds pipeline,
// prefetch distance 3. Used for small layers (K=128, K=512, N=64 out).
template <int EPI>
__global__ __launch_bounds__(256, 2) void k_gemm_g(
    const unsigned short* __restrict__ A, const unsigned short* __restrict__ Bt,
    unsigned short* __restrict__ C, const float* __restrict__ bias,
    const float* __restrict__ scale, const float* __restrict__ shift,
    int M, int N, int K, int lda, int ldc) {
  __shared__ __align__(16) unsigned short lsA[4][4][128][8];  // 32 KB

  const int tid = threadIdx.x;
  const int w = tid >> 6;
  const int lane = tid & 63;
  const int quad = lane >> 4;
  const int r16 = lane & 15;

  int m0, n0;
  gemm_swizzle(M, N, m0, n0);

  const int ra0 = min(m0 + lane, M - 1);
  const int ra1 = min(m0 + 64 + lane, M - 1);
  const unsigned short* pA0 = A + (size_t)ra0 * lda + w * 8;
  const unsigned short* pA1 = A + (size_t)ra1 * lda + w * 8;
  const unsigned short* pB[4];
#pragma unroll
  for (int j = 0; j < 4; j++) {
    int rb = min(n0 + w * 64 + j * 16 + r16, N - 1);
    pB[j] = Bt + (size_t)rb * K + quad * 8;
  }

  floatx4 acc[8][4];
#pragma unroll
  for (int i = 0; i < 8; i++)
#pragma unroll
    for (int j = 0; j < 4; j++) acc[i][j] = (floatx4){0.f, 0.f, 0.f, 0.f};

  const int niter = K >> 5;

#define ISSUE_A(st)                                                           \
  do {                                                                        \
    GLOAD_LDS16(pA0, &lsA[st][w][0][0]);                                      \
    GLOAD_LDS16(pA1, &lsA[st][w][64][0]);                                     \
    pA0 += 32; pA1 += 32;                                                     \
  } while (0)

  ISSUE_A(0);
  if (niter > 1) ISSUE_A(1);
  if (niter > 2) ISSUE_A(2);
  bf16x8 bcur[4], bnxt[4];
#pragma unroll
  for (int j = 0; j < 4; j++) {
    bcur[j] = *(const bf16x8*)pB[j];
    pB[j] += 32;
  }

  int st = 0;
  for (int t = 0; t < niter; t++) {
    if (t + 2 < niter) {
      asm volatile("s_waitcnt vmcnt(8)\n\ts_barrier" ::: "memory");
    } else if (t + 1 < niter) {
      asm volatile("s_waitcnt vmcnt(6)\n\ts_barrier" ::: "memory");
    } else {
      asm volatile("s_waitcnt vmcnt(4)\n\ts_barrier" ::: "memory");
    }
    if (t + 3 < niter) {
      int s3 = st + 3;
      if (s3 >= 4) s3 -= 4;
      ISSUE_A(s3);
    }
    if (t + 1 < niter) {
#pragma unroll
      for (int j = 0; j < 4; j++) {
        bnxt[j] = *(const bf16x8*)pB[j];
        pB[j] += 32;
      }
    }

    bf16x8 af[8];
#pragma unroll
    for (int i = 0; i < 8; i++)
      af[i] = *(const bf16x8*)&lsA[st][quad][i * 16 + r16][0];
#pragma unroll
    for (int j = 0; j < 4; j++)
#pragma unroll
      for (int i = 0; i < 8; i++)
        acc[i][j] = __builtin_amdgcn_mfma_f32_16x16x32_bf16(af[i], bcur[j],
                                                            acc[i][j], 0, 0, 0);
#pragma unroll
    for (int j = 0; j < 4; j++) bcur[j] = bnxt[j];
    st = (st + 1) & 3;
  }
#undef ISSUE_A

  gemm_epilogue<EPI>(acc, C, bias, scale, shift, M, N, ldc, m0, n0, w, quad, r16);
}

// ---------------------------------------------------------------------------
// k_gemm8 v5: 256x256 tile, BK=64, 512 threads (8 waves, 2M x 4N), 128 KB
// A+B double-buffered LDS, XOR chunk swizzle (pre-swizzled global source).
// ONE barrier per K-tile, placed BETWEEN C2 and C3. Tile body: stage T+1
// (8 glds, other buffer); C0-C2 MFMA clusters with 1-cluster-lookahead A
// reads; boundary vmcnt(0)+s_barrier (T+1 staging visible to all waves);
// pre-read T+1's B (into alternate set bG/bF) + A-C0 under C3's MFMA
// shadow; C3 MFMA. Loop unrolled x2 (NT even: K%128==0).
// Epilogue: per-wave XOR-swizzled LDS transpose -> 16B coalesced C stores.
template <int EPI>
__global__ __launch_bounds__(512, 2) void k_gemm8(
    const unsigned short* __restrict__ A, const unsigned short* __restrict__ Bt,
    unsigned short* __restrict__ C, const float* __restrict__ bias,
    const float* __restrict__ scale, const float* __restrict__ shift,
    int M, int N, int K, int lda, int ldc) {
  __shared__ __align__(16) unsigned short smem[2][2][256][64];  // 128 KB

  const int tid = threadIdx.x;
  const int w = tid >> 6;   // wave 0..7
  const int lane = tid & 63;
  const int wm = w >> 2;    // 0..1  (M half: rows wm*128..)
  const int wn = w & 3;     // 0..3  (N quarter: cols wn*64..)
  const int quad = lane >> 4;
  const int r16 = lane & 15;

  int m0, n0;
  gemm_swizzle256(M, N, m0, n0);

  // ---- staging addresses (pre-swizzled global source) ----
  const int w8l = w * 8 + (lane >> 3);               // row within 64-row q-block
  const int csrc = (lane & 7) ^ ((lane >> 3) & 7);   // source chunk for lane
  unsigned offA[2][2], offB[2][2];                   // byte offsets
#pragma unroll
  for (int h = 0; h < 2; h++)
#pragma unroll
    for (int q = 0; q < 2; q++) {
      int ra = m0 + h * 128 + q * 64 + w8l;
      ra = ra < M ? ra : (M - 1);
      offA[h][q] = (unsigned)ra * (unsigned)(lda * 2) + (unsigned)(csrc * 16);
      int rb = n0 + h * 128 + q * 64 + w8l;          // N%256==0: no clamp
      offB[h][q] = (unsigned)rb * (unsigned)(K * 2) + (unsigned)(csrc * 16);
    }
  const char* Ac = (const char*)A;
  const char* Bc = (const char*)Bt;
  char* smc = (char*)smem;
  const unsigned wdst = (unsigned)(w * 1024);  // wave's 8-row slice (8*128 B)

#define STG_A(T_, h_)                                                          \
  do {                                                                         \
    unsigned kb_ = (unsigned)(T_) * 128u;                                      \
    unsigned db_ = (unsigned)(((T_) & 1) << 16) + (unsigned)((h_) * 16384) + wdst; \
    GLOAD_LDS16(Ac + offA[h_][0] + kb_, smc + db_);                            \
    GLOAD_LDS16(Ac + offA[h_][1] + kb_, smc + db_ + 8192u);                    \
  } while (0)
#define STG_B(T_, h_)                                                          \
  do {                                                                         \
    unsigned kb_ = (unsigned)(T_) * 128u;                                      \
    unsigned db_ = (unsigned)(((T_) & 1) << 16) + 32768u +                     \
                   (unsigned)((h_) * 16384) + wdst;                            \
    GLOAD_LDS16(Bc + offB[h_][0] + kb_, smc + db_);                            \
    GLOAD_LDS16(Bc + offB[h_][1] + kb_, smc + db_ + 8192u);                    \
  } while (0)

  // ---- fragment read offsets (swizzled chunk = (ks*4+quad) ^ (row&7)) ----
  const int swz = r16 & 7;
  const unsigned cK0 = (unsigned)(((quad) ^ swz) * 16);       // ks=0
  const unsigned cK1 = (unsigned)(((4 + quad) ^ swz) * 16);   // ks=1
  const unsigned rdA = (unsigned)((wm * 128 + r16) * 128);
  const unsigned rdB = 32768u + (unsigned)((wn * 64 + r16) * 128);

#define RD_A(bo_, i_, c_) (*(const bf16x8*)(smc + (bo_) + rdA + (unsigned)((i_)*2048) + (c_)))
#define RD_B(bo_, j_, c_) (*(const bf16x8*)(smc + (bo_) + rdB + (unsigned)((j_)*2048) + (c_)))

  floatx4 acc[8][4];
#pragma unroll
  for (int i = 0; i < 8; i++)
#pragma unroll
    for (int j = 0; j < 4; j++) acc[i][j] = (floatx4){0.f, 0.f, 0.f, 0.f};

  const int NT = K >> 6;  // even (K%128==0 for all var-2 layers)

  // 16-MFMA cluster: i-pair (i0_, i0_+1) x j0-3 x ks0-1, B from BF
#define MM2(i0_, AF, BF)                                                      \
  do {                                                                        \
    __builtin_amdgcn_s_setprio(1);                                            \
    _Pragma("unroll")                                                         \
    for (int jj = 0; jj < 4; jj++) {                                          \
      acc[(i0_)][jj] = __builtin_amdgcn_mfma_f32_16x16x32_bf16(               \
          AF[0][0], BF[jj][0], acc[(i0_)][jj], 0, 0, 0);                      \
      acc[(i0_)][jj] = __builtin_amdgcn_mfma_f32_16x16x32_bf16(               \
          AF[0][1], BF[jj][1], acc[(i0_)][jj], 0, 0, 0);                      \
      acc[(i0_) + 1][jj] = __builtin_amdgcn_mfma_f32_16x16x32_bf16(           \
          AF[1][0], BF[jj][0], acc[(i0_) + 1][jj], 0, 0, 0);                  \
      acc[(i0_) + 1][jj] = __builtin_amdgcn_mfma_f32_16x16x32_bf16(           \
          AF[1][1], BF[jj][1], acc[(i0_) + 1][jj], 0, 0, 0);                  \
    }                                                                         \
    __builtin_amdgcn_s_setprio(0);                                            \
  } while (0)

  // ---- prologue: stage tile 0, land it, pre-read its B + A-C0 ----
  STG_A(0, 0); STG_A(0, 1); STG_B(0, 0); STG_B(0, 1);
  asm volatile("s_waitcnt vmcnt(0)\n\ts_barrier" ::: "memory");

  bf16x8 bF[4][2], bG[4][2], aP[2][2], aQ[2][2];
#pragma unroll
  for (int j = 0; j < 4; j++) { bF[j][0] = RD_B(0u, j, cK0); bF[j][1] = RD_B(0u, j, cK1); }
  aP[0][0] = RD_A(0u, 0, cK0); aP[0][1] = RD_A(0u, 0, cK1);
  aP[1][0] = RD_A(0u, 1, cK0); aP[1][1] = RD_A(0u, 1, cK1);

  // tile body: BC = current B regs, BN = next B regs (pre-read for T_+1)
#define TILE(T_, BC, BN)                                                      \
  do {                                                                        \
    const unsigned bo = (unsigned)(((T_) & 1) << 16);                         \
    const unsigned bo1 = (unsigned)((((T_) + 1) & 1) << 16);                  \
    if ((T_) + 1 < NT) { STG_A((T_) + 1, 0); STG_A((T_) + 1, 1);              \
                         STG_B((T_) + 1, 0); STG_B((T_) + 1, 1); }            \
    /* C0: issue A(i2-3); MFMA i0-1 (operands pre-read last tile) */          \
    aQ[0][0] = RD_A(bo, 2, cK0); aQ[0][1] = RD_A(bo, 2, cK1);                 \
    aQ[1][0] = RD_A(bo, 3, cK0); aQ[1][1] = RD_A(bo, 3, cK1);                 \
    MM2(0, aP, BC);                                                           \
    /* C1: issue A(i4-5); MFMA i2-3 */                                        \
    aP[0][0] = RD_A(bo, 4, cK0); aP[0][1] = RD_A(bo, 4, cK1);                 \
    aP[1][0] = RD_A(bo, 5, cK0); aP[1][1] = RD_A(bo, 5, cK1);                 \
    MM2(2, aQ, BC);                                                           \
    /* C2: issue A(i6-7); MFMA i4-5 */                                        \
    aQ[0][0] = RD_A(bo, 6, cK0); aQ[0][1] = RD_A(bo, 6, cK1);                 \
    aQ[1][0] = RD_A(bo, 7, cK0); aQ[1][1] = RD_A(bo, 7, cK1);                 \
    MM2(4, aP, BC);                                                           \
    /* boundary BEFORE C3: all waves' T+1 staging visible after barrier */    \
    if ((T_) + 1 < NT) {                                                      \
      asm volatile("s_waitcnt vmcnt(0)\n\ts_barrier" ::: "memory");           \
      _Pragma("unroll")                                                       \
      for (int j = 0; j < 4; j++) {                                           \
        BN[j][0] = RD_B(bo1, j, cK0); BN[j][1] = RD_B(bo1, j, cK1);           \
      }                                                                       \
      aP[0][0] = RD_A(bo1, 0, cK0); aP[0][1] = RD_A(bo1, 0, cK1);             \
      aP[1][0] = RD_A(bo1, 1, cK0); aP[1][1] = RD_A(bo1, 1, cK1);             \
    }                                                                         \
    /* C3: MFMA i6-7 (pre-reads above ride under this cluster) */             \
    MM2(6, aQ, BC);                                                           \
  } while (0)

  for (int T = 0; T < NT; T += 2) {
    TILE(T, bF, bG);
    TILE(T + 1, bG, bF);
  }
#undef TILE
#undef MM2
#undef STG_A
#undef STG_B
#undef RD_A
#undef RD_B

  // ---- epilogue: per-wave XOR-swizzled LDS transpose -> 16B stores ----
  __syncthreads();  // all waves done with main-loop LDS
  char* eb = smc + (unsigned)(w * 16384);  // wave-private 16KB (128 rows x 128B)
#pragma unroll
  for (int j = 0; j < 4; j++) {
    int gn = n0 + wn * 64 + j * 16 + r16;
    float p0 = 0.f, p1 = 0.f;
    if constexpr (EPI == 2) {
      p0 = scale[gn];
      p1 = shift[gn];
    } else {
      p0 = bias[gn];
    }
#pragma unroll
    for (int i = 0; i < 8; i++)
#pragma unroll
      for (int t = 0; t < 4; t++) {
        float v = acc[i][j][t];
        if constexpr (EPI == 0) {
          v += p0;
        } else if constexpr (EPI == 1) {
          v += p0; v = v > 0.f ? v : 0.f;
        } else if constexpr (EPI == 2) {
          v = v * p0 + p1; v = v > 0.f ? v : 0.f;
        } else {  // EPI 3 (leaky); EPI 4 unused by k_gemm8
          v += p0; v = v > 0.f ? v : 0.01f * v;
        }
        int row = i * 16 + quad * 4 + t;
        int col = j * 16 + r16;
        *(unsigned short*)(eb + row * 128 + (((col >> 3) ^ (row & 7)) << 4) +
                           ((col & 7) << 1)) = f2b(v);
      }
  }
  // read back own region (no cross-wave sync needed), 16B coalesced stores
#pragma unroll
  for (int r8 = 0; r8 < 16; r8++) {
    int row = r8 * 8 + (lane >> 3);
    int chunkG = lane & 7;
    bf16x8 vv = *(const bf16x8*)(eb + row * 128 + ((chunkG ^ (lane >> 3)) << 4));
    int gm = m0 + wm * 128 + row;
    if (gm < M)
      *(bf16x8*)(C + (size_t)gm * ldc + (n0 + wn * 64 + chunkG * 8)) = vv;
  }
}

// ---------------------------------------------------------------------------
extern "C" void kernel_launch(void* const* d_in, const int* in_sizes, int n_in,
                              void* d_out, int out_size, void* d_ws,
                              size_t ws_size, hipStream_t stream) {
  typedef const float* cf;
  cf x = (cf)d_in[0];
  const int* ei = (const int*)d_in[1];
  const int* srcI = ei;
  const int* dstI = ei + NE;
  cf w1a = (cf)d_in[2],  b1a = (cf)d_in[3];
  cf ga = (cf)d_in[4],   bea = (cf)d_in[5];
  cf mna = (cf)d_in[6],  vra = (cf)d_in[7];
  cf w2a = (cf)d_in[8],  b2a = (cf)d_in[9];
  cf w1b = (cf)d_in[10], b1b = (cf)d_in[11];
  cf gb = (cf)d_in[12],  beb = (cf)d_in[13];
  cf mnb = (cf)d_in[14], vrb = (cf)d_in[15];
  cf w2b = (cf)d_in[16], b2b = (cf)d_in[17];
  cf fc_w = (cf)d_in[18], fc_b = (cf)d_in[19];
  cf l1_w = (cf)d_in[20], l1_b = (cf)d_in[21];
  cf l2_w = (cf)d_in[22], l2_b = (cf)d_in[23];
  cf ow = (cf)d_in[24],   ob = (cf)d_in[25];
  float* outf = (float*)d_out;

  // ---- workspace carve-up ----------------------------------------------------
  char* ws = (char*)d_ws;
  size_t off = 0;
  auto carve = [&](size_t bytes) {
    void* p = ws + off;
    off += (bytes + 255) & ~(size_t)255;
    return p;
  };
  unsigned short* wt1ab = (unsigned short*)carve((size_t)DCAT * C_IN * 2);
  unsigned short* wt2a = (unsigned short*)carve((size_t)HID * HID * 2);
  unsigned short* wt2b = (unsigned short*)carve((size_t)HID * HID * 2);
  unsigned short* wtfc = (unsigned short*)carve((size_t)DFC * DCAT * 2);
  unsigned short* wtl1 = (unsigned short*)carve((size_t)DL1 * DFC * 2);
  unsigned short* wtl2 = (unsigned short*)carve((size_t)DFC * DL1 * 2);
  unsigned short* wtout = (unsigned short*)carve((size_t)OUTC * DFC * 2);
  float* scale_ab = (float*)carve(DCAT * 4);
  float* shift_ab = (float*)carve(DCAT * 4);
  unsigned short* h0 = (unsigned short*)carve((size_t)NN * C_IN * 2);

  // phase-1-only CSR arrays, OVERLAID with phase-2 activation buffers
  size_t off_overlay = off;
  int* deg = (int*)carve((size_t)NN * 4);
  int* offs = (int*)carve((size_t)(NN + 1) * 4);
  int* cursor = (int*)carve((size_t)NN * 4);
  int* bsum = (int*)carve(256 * 4);
  int* esrc = (int*)carve((size_t)NE * 4);

  off = off_overlay;
  size_t rem = (ws_size > off + 4096) ? (ws_size - off - 4096) : 0;
  int mchunk = (int)(rem / ((DFC + DL1) * 2));
  if (mchunk > 15104) mchunk = 15104;
  mchunk &= ~127;
  if (mchunk < 128) mchunk = 128;
  unsigned short* bufA = (unsigned short*)carve((size_t)mchunk * DFC * 2);
  unsigned short* bufB = (unsigned short*)carve((size_t)mchunk * DL1 * 2);
  (void)in_sizes; (void)n_in; (void)out_size;

  // ---- phase 0: params + weight transposes ----------------------------------
  k_bnparams<<<2, 256, 0, stream>>>(ga, bea, mna, vra, b1a, scale_ab, shift_ab);
  k_bnparams<<<2, 256, 0, stream>>>(gb, beb, mnb, vrb, b1b, scale_ab + HID,
                                    shift_ab + HID);
  k_transpose<<<dim3(HID / 32, C_IN / 32), 256, 0, stream>>>(w1a, wt1ab, C_IN, HID);
  k_transpose<<<dim3(HID / 32, C_IN / 32), 256, 0, stream>>>(
      w1b, wt1ab + (size_t)HID * C_IN, C_IN, HID);
  k_transpose<<<dim3(HID / 32, HID / 32), 256, 0, stream>>>(w2a, wt2a, HID, HID);
  k_transpose<<<dim3(HID / 32, HID / 32), 256, 0, stream>>>(w2b, wt2b, HID, HID);
  k_transpose<<<dim3(DFC / 32, DCAT / 32), 256, 0, stream>>>(fc_w, wtfc, DCAT, DFC);
  k_transpose<<<dim3(DL1 / 32, DFC / 32), 256, 0, stream>>>(l1_w, wtl1, DFC, DL1);
  k_transpose<<<dim3(DFC / 32, DL1 / 32), 256, 0, stream>>>(l2_w, wtl2, DL1, DFC);
  k_transpose<<<dim3(OUTC / 32, DFC / 32), 256, 0, stream>>>(ow, wtout, DFC, OUTC);

  // ---- phase 1: CSR build + gather aggregation -------------------------------
  const int NB_NODE = (NN + 255) / 256;
  hipMemsetAsync(deg, 0, (size_t)NN * 4, stream);
  k_deg<<<(NE + 255) / 256, 256, 0, stream>>>(dstI, deg);
  k_scan1<<<NB_NODE, 256, 0, stream>>>(deg, offs, bsum);
  k_scan2<<<1, 256, 0, stream>>>(bsum, NB_NODE);
  k_scan3<<<NB_NODE, 256, 0, stream>>>(offs, bsum, cursor);
  k_bucket<<<(NE + 255) / 256, 256, 0, stream>>>(srcI, dstI, cursor, esrc);
  k_agg<<<(NN + 3) / 4, 256, 0, stream>>>((const float2*)x, offs, esrc,
                                          (unsigned int*)h0);

  // ---- phase 2: GEMM chain ---------------------------------------------------
  // var 1 = G (128x256, B-direct);  var 2 = v5 256x256 (N%256==0, K%128==0)
  auto gemm = [&](int var, int epi, const unsigned short* A,
                  const unsigned short* Bt, unsigned short* Cp, cf bias,
                  const float* sc, const float* sh, int M, int N, int K,
                  int lda, int ldc) {
    if (var == 2) {
      dim3 g(((M + 255) / 256) * (N / 256));
      switch (epi) {
        case 0: k_gemm8<0><<<g, 512, 0, stream>>>(A, Bt, Cp, bias, sc, sh, M, N, K, lda, ldc); break;
        default: k_gemm8<3><<<g, 512, 0, stream>>>(A, Bt, Cp, bias, sc, sh, M, N, K, lda, ldc); break;
      }
    } else {
      dim3 g(((M + 127) / 128) * ((N + 255) / 256));
      switch (epi) {
        case 0: k_gemm_g<0><<<g, 256, 0, stream>>>(A, Bt, Cp, bias, sc, sh, M, N, K, lda, ldc); break;
        case 1: k_gemm_g<1><<<g, 256, 0, stream>>>(A, Bt, Cp, bias, sc, sh, M, N, K, lda, ldc); break;
        case 2: k_gemm_g<2><<<g, 256, 0, stream>>>(A, Bt, Cp, bias, sc, sh, M, N, K, lda, ldc); break;
        case 3: k_gemm_g<3><<<g, 256, 0, stream>>>(A, Bt, Cp, bias, sc, sh, M, N, K, lda, ldc); break;
        default: k_gemm_g<4><<<g, 256, 0, stream>>>(A, Bt, Cp, bias, sc, sh, M, N, K, lda, ldc); break;
      }
    }
  };

  for (int m0 = 0; m0 < NN; m0 += mchunk) {
    const int M = (NN - m0 < mchunk) ? (NN - m0) : mchunk;
    const unsigned short* h0c = h0 + (size_t)m0 * C_IN;
    unsigned short* outc = (unsigned short*)(outf + (size_t)m0 * OUTC);
    // fused branch-1: t1 = BN+ReLU(h0 @ [w1a|w1b])  (M x 1024), bufA ld=1024
    gemm(1, 2, h0c, wt1ab, bufA, nullptr, scale_ab, shift_ab, M, DCAT, C_IN, C_IN, DCAT);
    // branch-2a/b: xcat halves (bufB, ld=1024)
    gemm(1, 1, bufA, wt2a, bufB, b2a, nullptr, nullptr, M, HID, HID, DCAT, DCAT);
    gemm(1, 1, bufA + HID, wt2b, bufB + HID, b2b, nullptr, nullptr, M, HID, HID, DCAT, DCAT);
    // head: xcat(bufB,1024) -> hfc(bufA,2048) -> hl1(bufB,4096) -> hl2(bufA,2048) -> out
    gemm(2, 3, bufB, wtfc, bufA, fc_b, nullptr, nullptr, M, DFC, DCAT, DCAT, DFC);
    gemm(2, 0, bufA, wtl1, bufB, l1_b, nullptr, nullptr, M, DL1, DFC, DFC, DL1);
    gemm(2, 0, bufB, wtl2, bufA, l2_b, nullptr, nullptr, M, DFC, DL1, DL1, DFC);
    gemm(1, 4, bufA, wtout, outc, ob, nullptr, nullptr, M, OUTC, DFC, DFC, OUTC);
  }
}

// Round 7
// 3318.774 us; speedup vs baseline: 1.2205x; 1.2205x over previous
//
#include <hip/hip_runtime.h>

// ---------------------------------------------------------------------------
// GCNConvNet: 2x GIN conv (shared aggregation) + dense head. fp32 I/O,
// bf16 MFMA internally (harness grants bf16 tolerance).
// Round 15: r14 (v5) regression root-cause = 2nd B reg set -> 128 arch +
// 128 acc = 256/wave cliff -> spills (FETCH 274->585MB). Lesson: no extra
// live regs at this occupancy. r13/r14 also showed reads must issue
// PRE-barrier to overlap other waves' MFMA; that needs the target buffer
// published one barrier earlier => prefetch distance >=2.
// k_gemm8 v6: BK=32, QUAD-buffered LDS (4x32KB=128KB), stage distance 3,
// ONE barrier/tile with vmcnt(4) (publishes stage(T+2), keeps stage(T+3)).
// Tile = 4 clusters x 8 MFMA; C0-C2 lookahead A reads; C3 pre-reads next
// tile's B(4)+A-C0(2) barrier-free (buffer published last tile). BK=32
// HALVES fragment sets: arch regs ~95 (vs v3 112), acc[8][4] unchanged.
// ---------------------------------------------------------------------------

#define NN 60000
#define NE 960000
#define C_IN 128
#define HID 512
#define DCAT 1024
#define DFC 2048
#define DL1 4096
#define OUTC 64

typedef __bf16 bf16x8 __attribute__((ext_vector_type(8)));
typedef float floatx4 __attribute__((ext_vector_type(4)));

__device__ __forceinline__ unsigned short f2b(float f) {
  unsigned int u = __float_as_uint(f);
  unsigned int r = (u + 0x7fffu + ((u >> 16) & 1u)) >> 16;  // RNE, finite inputs
  return (unsigned short)r;
}

// async global->LDS, 16B per lane; LDS dest = wave-uniform base + lane*16
#define GLOAD_LDS16(g, l)                                                     \
  __builtin_amdgcn_global_load_lds(                                           \
      (__attribute__((address_space(1))) void*)(g),                           \
      (__attribute__((address_space(3))) void*)(l), 16, 0, 0)

// ---------------------------------------------------------------------------
__global__ void k_bnparams(const float* __restrict__ g,
                           const float* __restrict__ be,
                           const float* __restrict__ mn,
                           const float* __restrict__ vr,
                           const float* __restrict__ b1,
                           float* __restrict__ scale, float* __restrict__ shift) {
  int i = blockIdx.x * 256 + threadIdx.x;
  if (i < HID) {
    float s = g[i] * rsqrtf(vr[i] + 1e-5f);
    scale[i] = s;
    shift[i] = (b1[i] - mn[i]) * s + be[i];
  }
}

// fp32 [K,N] -> bf16 [N,K] transpose+downcast, 32x32 tiles
__global__ void k_transpose(const float* __restrict__ in,
                            unsigned short* __restrict__ out, int K, int N) {
  __shared__ float t[32][33];
  int n0 = blockIdx.x * 32, k0 = blockIdx.y * 32;
  int tx = threadIdx.x & 31, ty = threadIdx.x >> 5;  // 32 x 8
#pragma unroll
  for (int i = 0; i < 32; i += 8)
    t[ty + i][tx] = in[(size_t)(k0 + ty + i) * N + n0 + tx];
  __syncthreads();
#pragma unroll
  for (int i = 0; i < 32; i += 8)
    out[(size_t)(n0 + ty + i) * K + k0 + tx] = f2b(t[tx][ty + i]);
}

// ---------------------------------------------------------------------------
// CSR build: deg -> exclusive scan (3 kernels) -> bucket src ids -> gather.
__global__ void k_deg(const int* __restrict__ dst, int* __restrict__ deg) {
  int e = blockIdx.x * 256 + threadIdx.x;
  if (e < NE) atomicAdd(&deg[dst[e]], 1);
}

__global__ void k_scan1(const int* __restrict__ deg, int* __restrict__ offs,
                        int* __restrict__ bsum) {
  __shared__ int t[256];
  int i = blockIdx.x * 256 + threadIdx.x;
  int v = (i < NN) ? deg[i] : 0;
  t[threadIdx.x] = v;
  __syncthreads();
#pragma unroll
  for (int d = 1; d < 256; d <<= 1) {
    int add = (threadIdx.x >= d) ? t[threadIdx.x - d] : 0;
    __syncthreads();
    t[threadIdx.x] += add;
    __syncthreads();
  }
  if (i < NN) offs[i] = t[threadIdx.x] - v;
  if (threadIdx.x == 255) bsum[blockIdx.x] = t[255];
}

__global__ void k_scan2(int* __restrict__ bsum, int nb) {
  __shared__ int t[256];
  int v = (threadIdx.x < nb) ? bsum[threadIdx.x] : 0;
  t[threadIdx.x] = v;
  __syncthreads();
#pragma unroll
  for (int d = 1; d < 256; d <<= 1) {
    int add = (threadIdx.x >= d) ? t[threadIdx.x - d] : 0;
    __syncthreads();
    t[threadIdx.x] += add;
    __syncthreads();
  }
  if (threadIdx.x < nb) bsum[threadIdx.x] = t[threadIdx.x] - v;
}

__global__ void k_scan3(int* __restrict__ offs, const int* __restrict__ bsum,
                        int* __restrict__ cursor) {
  int i = blockIdx.x * 256 + threadIdx.x;
  if (i < NN) {
    int o = offs[i] + bsum[blockIdx.x];
    offs[i] = o;
    cursor[i] = o;
  }
  if (i == 0) offs[NN] = NE;
}

__global__ void k_bucket(const int* __restrict__ src, const int* __restrict__ dst,
                         int* __restrict__ cursor, int* __restrict__ esrc) {
  int e = blockIdx.x * 256 + threadIdx.x;
  if (e < NE) {
    int slot = atomicAdd(&cursor[dst[e]], 1);
    esrc[slot] = src[e];
  }
}

// one wave per node: h0[node] = bf16(x[node] + sum_j x[esrc[j]]), f32 accum
__global__ void k_agg(const float2* __restrict__ x2, const int* __restrict__ offs,
                      const int* __restrict__ esrc, unsigned int* __restrict__ h0u) {
  int node = blockIdx.x * 4 + (threadIdx.x >> 6);
  if (node >= NN) return;
  int lane = threadIdx.x & 63;
  int beg = offs[node], end = offs[node + 1];
  float2 acc = x2[(size_t)node * 64 + lane];
  for (int j = beg; j < end; j++) {
    int s = esrc[j];  // wave-uniform -> broadcast load
    float2 v = x2[(size_t)s * 64 + lane];
    acc.x += v.x;
    acc.y += v.y;
  }
  h0u[(size_t)node * 64 + lane] =
      (unsigned)f2b(acc.x) | ((unsigned)f2b(acc.y) << 16);
}

// ---------------------------------------------------------------------------
// shared epilogue (k_gemm_g): C/D layout col=lane&15, row=quad*4+reg
template <int EPI>
__device__ __forceinline__ void gemm_epilogue(
    floatx4 (&acc)[8][4], unsigned short* C, const float* bias,
    const float* scale, const float* shift, int M, int N, int ldc, int m0,
    int n0, int w, int quad, int r16) {
#pragma unroll
  for (int j = 0; j < 4; j++) {
    int gn = n0 + w * 64 + j * 16 + r16;
    int cn = gn < N ? gn : 0;
    float p0, p1 = 0.f;
    if constexpr (EPI == 2) {
      p0 = scale[cn];
      p1 = shift[cn];
    } else {
      p0 = bias[cn];
    }
#pragma unroll
    for (int i = 0; i < 8; i++) {
#pragma unroll
      for (int t = 0; t < 4; t++) {
        int gm = m0 + i * 16 + quad * 4 + t;
        if (gm < M && gn < N) {
          float v = acc[i][j][t];
          if constexpr (EPI == 0) {
            v += p0;
            C[(size_t)gm * ldc + gn] = f2b(v);
          } else if constexpr (EPI == 1) {
            v += p0; v = v > 0.f ? v : 0.f;
            C[(size_t)gm * ldc + gn] = f2b(v);
          } else if constexpr (EPI == 2) {
            v = v * p0 + p1; v = v > 0.f ? v : 0.f;
            C[(size_t)gm * ldc + gn] = f2b(v);
          } else if constexpr (EPI == 3) {
            v += p0; v = v > 0.f ? v : 0.01f * v;
            C[(size_t)gm * ldc + gn] = f2b(v);
          } else {  // sigmoid -> fp32 network output
            v += p0;
            v = 1.f / (1.f + __expf(-v));
            ((float*)C)[(size_t)gm * ldc + gn] = v;
          }
        }
      }
    }
  }
}

__device__ __forceinline__ void gemm_swizzle(int M, int N, int& m0, int& n0) {
  const int mt_total = (M + 127) >> 7, nt_total = (N + 255) >> 8;
  int mt, nt;
  if ((nt_total & 7) == 0) {
    const int ntpx = nt_total >> 3;
    const int x = blockIdx.x & 7;
    const int s = blockIdx.x >> 3;
    nt = x * ntpx + (s % ntpx);
    mt = s / ntpx;
  } else {
    const int GM = 8;
    const int full = (mt_total / GM) * GM;
    const int boundary = full * nt_total;
    int id = blockIdx.x;
    if (id < boundary) {
      int per_group = GM * nt_total;
      int g = id / per_group, r = id % per_group;
      mt = g * GM + r % GM;
      nt = r / GM;
    } else {
      int r = id - boundary, gm = mt_total - full;
      mt = full + r % gm;
      nt = r / gm;
    }
  }
  m0 = mt << 7;
  n0 = nt << 8;
}

__device__ __forceinline__ void gemm_swizzle256(int M, int N, int& m0, int& n0) {
  const int mt_total = (M + 255) >> 8, nt_total = N >> 8;
  int mt, nt;
  if ((nt_total & 7) == 0) {
    const int ntpx = nt_total >> 3;
    const int x = blockIdx.x & 7;
    const int s = blockIdx.x >> 3;
    nt = x * ntpx + (s % ntpx);
    mt = s / ntpx;
  } else {
    const int GM = 8;
    const int full = (mt_total / GM) * GM;
    const int boundary = full * nt_total;
    int id = blockIdx.x;
    if (id < boundary) {
      int per_group = GM * nt_total;
      int g = id / per_group, r = id % per_group;
      mt = g * GM + r % GM;
      nt = r / GM;
    } else {
      int r = id - boundary, gm = mt_total - full;
      mt = full + r % gm;
      nt = r / gm;
    }
  }
  m0 = mt << 8;
  n0 = nt << 8;
}

// ---------------------------------------------------------------------------
// k_gemm_g (r8 verified): B direct global->reg; A via 4-stage glds pipeline,
// prefetch distance 3. Used for small layers (K=128, K=512, N=64 out).
template <int EPI>
__global__ __launch_bounds__(256, 2) void k_gemm_g(
    const unsigned short* __restrict__ A, const unsigned short* __restrict__ Bt,
    unsigned short* __restrict__ C, const float* __restrict__ bias,
    const float* __restrict__ scale, const float* __restrict__ shift,
    int M, int N, int K, int lda, int ldc) {
  __shared__ __align__(16) unsigned short lsA[4][4][128][8];  // 32 KB

  const int tid = threadIdx.x;
  const int w = tid >> 6;
  const int lane = tid & 63;
  const int quad = lane >> 4;
  const int r16 = lane & 15;

  int m0, n0;
  gemm_swizzle(M, N, m0, n0);

  const int ra0 = min(m0 + lane, M - 1);
  const int ra1 = min(m0 + 64 + lane, M - 1);
  const unsigned short* pA0 = A + (size_t)ra0 * lda + w * 8;
  const unsigned short* pA1 = A + (size_t)ra1 * lda + w * 8;
  const unsigned short* pB[4];
#pragma unroll
  for (int j = 0; j < 4; j++) {
    int rb = min(n0 + w * 64 + j * 16 + r16, N - 1);
    pB[j] = Bt + (size_t)rb * K + quad * 8;
  }

  floatx4 acc[8][4];
#pragma unroll
  for (int i = 0; i < 8; i++)
#pragma unroll
    for (int j = 0; j < 4; j++) acc[i][j] = (floatx4){0.f, 0.f, 0.f, 0.f};

  const int niter = K >> 5;

#define ISSUE_A(st)                                                           \
  do {                                                                        \
    GLOAD_LDS16(pA0, &lsA[st][w][0][0]);                                      \
    GLOAD_LDS16(pA1, &lsA[st][w][64][0]);                                     \
    pA0 += 32; pA1 += 32;                                                     \
  } while (0)

  ISSUE_A(0);
  if (niter > 1) ISSUE_A(1);
  if (niter > 2) ISSUE_A(2);
  bf16x8 bcur[4], bnxt[4];
#pragma unroll
  for (int j = 0; j < 4; j++) {
    bcur[j] = *(const bf16x8*)pB[j];
    pB[j] += 32;
  }

  int st = 0;
  for (int t = 0; t < niter; t++) {
    if (t + 2 < niter) {
      asm volatile("s_waitcnt vmcnt(8)\n\ts_barrier" ::: "memory");
    } else if (t + 1 < niter) {
      asm volatile("s_waitcnt vmcnt(6)\n\ts_barrier" ::: "memory");
    } else {
      asm volatile("s_waitcnt vmcnt(4)\n\ts_barrier" ::: "memory");
    }
    if (t + 3 < niter) {
      int s3 = st + 3;
      if (s3 >= 4) s3 -= 4;
      ISSUE_A(s3);
    }
    if (t + 1 < niter) {
#pragma unroll
      for (int j = 0; j < 4; j++) {
        bnxt[j] = *(const bf16x8*)pB[j];
        pB[j] += 32;
      }
    }

    bf16x8 af[8];
#pragma unroll
    for (int i = 0; i < 8; i++)
      af[i] = *(const bf16x8*)&lsA[st][quad][i * 16 + r16][0];
#pragma unroll
    for (int j = 0; j < 4; j++)
#pragma unroll
      for (int i = 0; i < 8; i++)
        acc[i][j] = __builtin_amdgcn_mfma_f32_16x16x32_bf16(af[i], bcur[j],
                                                            acc[i][j], 0, 0, 0);
#pragma unroll
    for (int j = 0; j < 4; j++) bcur[j] = bnxt[j];
    st = (st + 1) & 3;
  }
#undef ISSUE_A

  gemm_epilogue<EPI>(acc, C, bias, scale, shift, M, N, ldc, m0, n0, w, quad, r16);
}

// ---------------------------------------------------------------------------
// k_gemm8 v6: 256x256 tile, BK=32, 512 threads (8 waves, 2M x 4N), QUAD-
// buffered LDS (4 x [A 16KB | B 16KB] = 128 KB), XOR chunk swizzle (4 chunks
// of 16B per 64B row; pre-swizzled global source). Stage distance 3:
// stage(T+3) issued at top of T; end-of-T barrier waits vmcnt(4) (keeps
// stage(T+3), publishes stage(T+2)). Per tile 4 clusters x 8 MFMA; C0-C2
// lookahead A reads; C3 pre-reads NEXT tile's B(4 frags)+A(i0-1) with no
// barrier (its buffer was published at end of T-1) -> no post-barrier read
// storm. Registers: bF/bG 16+16, aX/aY 8+8 (BK=32 halves sets; arch ~95).
// Requires N%256==0, K%64==0 (NT even); M edge via row clamp + store guard.
// Epilogue: per-wave XOR-swizzled LDS transpose -> 16B coalesced C stores.
template <int EPI>
__global__ __launch_bounds__(512, 2) void k_gemm8(
    const unsigned short* __restrict__ A, const unsigned short* __restrict__ Bt,
    unsigned short* __restrict__ C, const float* __restrict__ bias,
    const float* __restrict__ scale, const float* __restrict__ shift,
    int M, int N, int K, int lda, int ldc) {
  __shared__ __align__(16) unsigned short smem[4][2][256][32];  // 128 KB

  const int tid = threadIdx.x;
  const int w = tid >> 6;   // wave 0..7
  const int lane = tid & 63;
  const int wm = w >> 2;    // 0..1  (M half: rows wm*128..)
  const int wn = w & 3;     // 0..3  (N quarter: cols wn*64..)
  const int quad = lane >> 4;
  const int r16 = lane & 15;

  int m0, n0;
  gemm_swizzle256(M, N, m0, n0);

  // ---- staging addresses (pre-swizzled global source; 64B rows, 4 chunks) --
  const int w16l = w * 16 + (lane >> 2);             // row within 128-row half
  const int csrc = (lane & 3) ^ ((lane >> 2) & 3);   // source chunk for lane
  unsigned offA[2], offB[2];                         // byte offsets, [h]
#pragma unroll
  for (int h = 0; h < 2; h++) {
    int ra = m0 + h * 128 + w16l;
    ra = ra < M ? ra : (M - 1);
    offA[h] = (unsigned)ra * (unsigned)(lda * 2) + (unsigned)(csrc * 16);
    int rb = n0 + h * 128 + w16l;                    // N%256==0: no clamp
    offB[h] = (unsigned)rb * (unsigned)(K * 2) + (unsigned)(csrc * 16);
  }
  const char* Ac = (const char*)A;
  const char* Bc = (const char*)Bt;
  char* smc = (char*)smem;
  const unsigned wdst = (unsigned)(w * 1024);  // wave's 16-row slice (16*64 B)

  // stage full tile T_ (A 16KB + B 16KB) into buf T_&3; 4 glds per thread
#define STG32(T_)                                                             \
  do {                                                                        \
    unsigned kb_ = (unsigned)(T_) * 64u;                                      \
    unsigned db_ = (unsigned)(((T_) & 3) * 32768) + wdst;                     \
    GLOAD_LDS16(Ac + offA[0] + kb_, smc + db_);                               \
    GLOAD_LDS16(Ac + offA[1] + kb_, smc + db_ + 8192u);                       \
    GLOAD_LDS16(Bc + offB[0] + kb_, smc + db_ + 16384u);                      \
    GLOAD_LDS16(Bc + offB[1] + kb_, smc + db_ + 24576u);                      \
  } while (0)

  // ---- fragment read offsets (swizzled chunk = quad ^ (row&3)) ----
  const unsigned cKq = (unsigned)(((quad ^ (r16 & 3)) & 3) * 16);
  const unsigned rdA = (unsigned)((wm * 128 + r16) * 64) + cKq;
  const unsigned rdB = 16384u + (unsigned)((wn * 64 + r16) * 64) + cKq;

#define RD_A32(so_, i_) (*(const bf16x8*)(smc + (so_) + rdA + (unsigned)((i_)*1024)))
#define RD_B32(so_, j_) (*(const bf16x8*)(smc + (so_) + rdB + (unsigned)((j_)*1024)))

  floatx4 acc[8][4];
#pragma unroll
  for (int i = 0; i < 8; i++)
#pragma unroll
    for (int j = 0; j < 4; j++) acc[i][j] = (floatx4){0.f, 0.f, 0.f, 0.f};

  const int NT = K >> 5;  // even (K%64==0 for all var-2 layers)

  // 8-MFMA cluster: i-pair (i0_, i0_+1) x j0-3, one K-step of 32
#define MM1(i0_, AF, BF)                                                      \
  do {                                                                        \
    __builtin_amdgcn_s_setprio(1);                                            \
    _Pragma("unroll")                                                         \
    for (int jj = 0; jj < 4; jj++) {                                          \
      acc[(i0_)][jj] = __builtin_amdgcn_mfma_f32_16x16x32_bf16(               \
          AF[0], BF[jj], acc[(i0_)][jj], 0, 0, 0);                            \
      acc[(i0_) + 1][jj] = __builtin_amdgcn_mfma_f32_16x16x32_bf16(           \
          AF[1], BF[jj], acc[(i0_) + 1][jj], 0, 0, 0);                        \
    }                                                                         \
    __builtin_amdgcn_s_setprio(0);                                            \
  } while (0)

  // ---- prologue: stage 0,1,2; publish 0 AND 1 (keep 2); pre-read tile 0 ----
  STG32(0);
  if (NT > 1) STG32(1);
  if (NT > 2) STG32(2);
  if (NT > 2) {
    asm volatile("s_waitcnt vmcnt(4)\n\ts_barrier" ::: "memory");
  } else {
    asm volatile("s_waitcnt vmcnt(0)\n\ts_barrier" ::: "memory");
  }

  bf16x8 bF[4], bG[4], aX[2], aY[2];
#pragma unroll
  for (int j = 0; j < 4; j++) bF[j] = RD_B32(0u, j);
  aX[0] = RD_A32(0u, 0);
  aX[1] = RD_A32(0u, 1);

  // tile body: BC = current B regs, BN = next tile's B regs (pre-read in C3)
#define TILE(T_, BC, BN)                                                      \
  do {                                                                        \
    const unsigned so = (unsigned)(((T_) & 3) * 32768);                       \
    const unsigned so1 = (unsigned)((((T_) + 1) & 3) * 32768);                \
    if ((T_) + 3 < NT) STG32((T_) + 3);                                       \
    /* C0: read aY(i2-3); MFMA i0-1 */                                        \
    aY[0] = RD_A32(so, 2); aY[1] = RD_A32(so, 3);                             \
    MM1(0, aX, BC);                                                           \
    /* C1: read aX(i4-5); MFMA i2-3 */                                        \
    aX[0] = RD_A32(so, 4); aX[1] = RD_A32(so, 5);                             \
    MM1(2, aY, BC);                                                           \
    /* C2: read aY(i6-7); MFMA i4-5 */                                        \
    aY[0] = RD_A32(so, 6); aY[1] = RD_A32(so, 7);                             \
    MM1(4, aX, BC);                                                           \
    /* C3: pre-read next tile's B + A(i0-1) (buffer published at end of T-1); \
       MFMA i6-7 rides over the reads */                                      \
    if ((T_) + 1 < NT) {                                                      \
      BN[0] = RD_B32(so1, 0); BN[1] = RD_B32(so1, 1);                         \
      BN[2] = RD_B32(so1, 2); BN[3] = RD_B32(so1, 3);                         \
      aX[0] = RD_A32(so1, 0); aX[1] = RD_A32(so1, 1);                         \
    }                                                                         \
    MM1(6, aY, BC);                                                           \
    /* boundary: publish stage(T+2), keep stage(T+3) in flight */             \
    if ((T_) + 1 < NT) {                                                      \
      if ((T_) + 3 < NT) {                                                    \
        asm volatile("s_waitcnt vmcnt(4)\n\ts_barrier" ::: "memory");         \
      } else {                                                                \
        asm volatile("s_waitcnt vmcnt(0)\n\ts_barrier" ::: "memory");         \
      }                                                                       \
    }                                                                         \
  } while (0)

  for (int T = 0; T < NT; T += 2) {
    TILE(T, bF, bG);
    TILE(T + 1, bG, bF);
  }
#undef TILE
#undef MM1
#undef STG32
#undef RD_A32
#undef RD_B32

  // ---- epilogue: per-wave XOR-swizzled LDS transpose -> 16B stores ----
  __syncthreads();  // all waves done with main-loop LDS
  char* eb = smc + (unsigned)(w * 16384);  // wave-private 16KB (128 rows x 128B)
#pragma unroll
  for (int j = 0; j < 4; j++) {
    int gn = n0 + wn * 64 + j * 16 + r16;
    float p0 = 0.f, p1 = 0.f;
    if constexpr (EPI == 2) {
      p0 = scale[gn];
      p1 = shift[gn];
    } else {
      p0 = bias[gn];
    }
#pragma unroll
    for (int i = 0; i < 8; i++)
#pragma unroll
      for (int t = 0; t < 4; t++) {
        float v = acc[i][j][t];
        if constexpr (EPI == 0) {
          v += p0;
        } else if constexpr (EPI == 1) {
          v += p0; v = v > 0.f ? v : 0.f;
        } else if constexpr (EPI == 2) {
          v = v * p0 + p1; v = v > 0.f ? v : 0.f;
        } else {  // EPI 3 (leaky); EPI 4 unused by k_gemm8
          v += p0; v = v > 0.f ? v : 0.01f * v;
        }
        int row = i * 16 + quad * 4 + t;
        int col = j * 16 + r16;
        *(unsigned short*)(eb + row * 128 + (((col >> 3) ^ (row & 7)) << 4) +
                           ((col & 7) << 1)) = f2b(v);
      }
  }
  // read back own region (no cross-wave sync needed), 16B coalesced stores
#pragma unroll
  for (int r8 = 0; r8 < 16; r8++) {
    int row = r8 * 8 + (lane >> 3);
    int chunkG = lane & 7;
    bf16x8 vv = *(const bf16x8*)(eb + row * 128 + ((chunkG ^ (lane >> 3)) << 4));
    int gm = m0 + wm * 128 + row;
    if (gm < M)
      *(bf16x8*)(C + (size_t)gm * ldc + (n0 + wn * 64 + chunkG * 8)) = vv;
  }
}

// ---------------------------------------------------------------------------
extern "C" void kernel_launch(void* const* d_in, const int* in_sizes, int n_in,
                              void* d_out, int out_size, void* d_ws,
                              size_t ws_size, hipStream_t stream) {
  typedef const float* cf;
  cf x = (cf)d_in[0];
  const int* ei = (const int*)d_in[1];
  const int* srcI = ei;
  const int* dstI = ei + NE;
  cf w1a = (cf)d_in[2],  b1a = (cf)d_in[3];
  cf ga = (cf)d_in[4],   bea = (cf)d_in[5];
  cf mna = (cf)d_in[6],  vra = (cf)d_in[7];
  cf w2a = (cf)d_in[8],  b2a = (cf)d_in[9];
  cf w1b = (cf)d_in[10], b1b = (cf)d_in[11];
  cf gb = (cf)d_in[12],  beb = (cf)d_in[13];
  cf mnb = (cf)d_in[14], vrb = (cf)d_in[15];
  cf w2b = (cf)d_in[16], b2b = (cf)d_in[17];
  cf fc_w = (cf)d_in[18], fc_b = (cf)d_in[19];
  cf l1_w = (cf)d_in[20], l1_b = (cf)d_in[21];
  cf l2_w = (cf)d_in[22], l2_b = (cf)d_in[23];
  cf ow = (cf)d_in[24],   ob = (cf)d_in[25];
  float* outf = (float*)d_out;

  // ---- workspace carve-up ----------------------------------------------------
  char* ws = (char*)d_ws;
  size_t off = 0;
  auto carve = [&](size_t bytes) {
    void* p = ws + off;
    off += (bytes + 255) & ~(size_t)255;
    return p;
  };
  unsigned short* wt1ab = (unsigned short*)carve((size_t)DCAT * C_IN * 2);
  unsigned short* wt2a = (unsigned short*)carve((size_t)HID * HID * 2);
  unsigned short* wt2b = (unsigned short*)carve((size_t)HID * HID * 2);
  unsigned short* wtfc = (unsigned short*)carve((size_t)DFC * DCAT * 2);
  unsigned short* wtl1 = (unsigned short*)carve((size_t)DL1 * DFC * 2);
  unsigned short* wtl2 = (unsigned short*)carve((size_t)DFC * DL1 * 2);
  unsigned short* wtout = (unsigned short*)carve((size_t)OUTC * DFC * 2);
  float* scale_ab = (float*)carve(DCAT * 4);
  float* shift_ab = (float*)carve(DCAT * 4);
  unsigned short* h0 = (unsigned short*)carve((size_t)NN * C_IN * 2);

  // phase-1-only CSR arrays, OVERLAID with phase-2 activation buffers
  size_t off_overlay = off;
  int* deg = (int*)carve((size_t)NN * 4);
  int* offs = (int*)carve((size_t)(NN + 1) * 4);
  int* cursor = (int*)carve((size_t)NN * 4);
  int* bsum = (int*)carve(256 * 4);
  int* esrc = (int*)carve((size_t)NE * 4);

  off = off_overlay;
  size_t rem = (ws_size > off + 4096) ? (ws_size - off - 4096) : 0;
  int mchunk = (int)(rem / ((DFC + DL1) * 2));
  if (mchunk > 15104) mchunk = 15104;
  mchunk &= ~127;
  if (mchunk < 128) mchunk = 128;
  unsigned short* bufA = (unsigned short*)carve((size_t)mchunk * DFC * 2);
  unsigned short* bufB = (unsigned short*)carve((size_t)mchunk * DL1 * 2);
  (void)in_sizes; (void)n_in; (void)out_size;

  // ---- phase 0: params + weight transposes ----------------------------------
  k_bnparams<<<2, 256, 0, stream>>>(ga, bea, mna, vra, b1a, scale_ab, shift_ab);
  k_bnparams<<<2, 256, 0, stream>>>(gb, beb, mnb, vrb, b1b, scale_ab + HID,
                                    shift_ab + HID);
  k_transpose<<<dim3(HID / 32, C_IN / 32), 256, 0, stream>>>(w1a, wt1ab, C_IN, HID);
  k_transpose<<<dim3(HID / 32, C_IN / 32), 256, 0, stream>>>(
      w1b, wt1ab + (size_t)HID * C_IN, C_IN, HID);
  k_transpose<<<dim3(HID / 32, HID / 32), 256, 0, stream>>>(w2a, wt2a, HID, HID);
  k_transpose<<<dim3(HID / 32, HID / 32), 256, 0, stream>>>(w2b, wt2b, HID, HID);
  k_transpose<<<dim3(DFC / 32, DCAT / 32), 256, 0, stream>>>(fc_w, wtfc, DCAT, DFC);
  k_transpose<<<dim3(DL1 / 32, DFC / 32), 256, 0, stream>>>(l1_w, wtl1, DFC, DL1);
  k_transpose<<<dim3(DFC / 32, DL1 / 32), 256, 0, stream>>>(l2_w, wtl2, DL1, DFC);
  k_transpose<<<dim3(OUTC / 32, DFC / 32), 256, 0, stream>>>(ow, wtout, DFC, OUTC);

  // ---- phase 1: CSR build + gather aggregation -------------------------------
  const int NB_NODE = (NN + 255) / 256;
  hipMemsetAsync(deg, 0, (size_t)NN * 4, stream);
  k_deg<<<(NE + 255) / 256, 256, 0, stream>>>(dstI, deg);
  k_scan1<<<NB_NODE, 256, 0, stream>>>(deg, offs, bsum);
  k_scan2<<<1, 256, 0, stream>>>(bsum, NB_NODE);
  k_scan3<<<NB_NODE, 256, 0, stream>>>(offs, bsum, cursor);
  k_bucket<<<(NE + 255) / 256, 256, 0, stream>>>(srcI, dstI, cursor, esrc);
  k_agg<<<(NN + 3) / 4, 256, 0, stream>>>((const float2*)x, offs, esrc,
                                          (unsigned int*)h0);

  // ---- phase 2: GEMM chain ---------------------------------------------------
  // var 1 = G (128x256, B-direct);  var 2 = v6 256x256 (N%256==0, K%64==0)
  auto gemm = [&](int var, int epi, const unsigned short* A,
                  const unsigned short* Bt, unsigned short* Cp, cf bias,
                  const float* sc, const float* sh, int M, int N, int K,
                  int lda, int ldc) {
    if (var == 2) {
      dim3 g(((M + 255) / 256) * (N / 256));
      switch (epi) {
        case 0: k_gemm8<0><<<g, 512, 0, stream>>>(A, Bt, Cp, bias, sc, sh, M, N, K, lda, ldc); break;
        default: k_gemm8<3><<<g, 512, 0, stream>>>(A, Bt, Cp, bias, sc, sh, M, N, K, lda, ldc); break;
      }
    } else {
      dim3 g(((M + 127) / 128) * ((N + 255) / 256));
      switch (epi) {
        case 0: k_gemm_g<0><<<g, 256, 0, stream>>>(A, Bt, Cp, bias, sc, sh, M, N, K, lda, ldc); break;
        case 1: k_gemm_g<1><<<g, 256, 0, stream>>>(A, Bt, Cp, bias, sc, sh, M, N, K, lda, ldc); break;
        case 2: k_gemm_g<2><<<g, 256, 0, stream>>>(A, Bt, Cp, bias, sc, sh, M, N, K, lda, ldc); break;
        case 3: k_gemm_g<3><<<g, 256, 0, stream>>>(A, Bt, Cp, bias, sc, sh, M, N, K, lda, ldc); break;
        default: k_gemm_g<4><<<g, 256, 0, stream>>>(A, Bt, Cp, bias, sc, sh, M, N, K, lda, ldc); break;
      }
    }
  };

  for (int m0 = 0; m0 < NN; m0 += mchunk) {
    const int M = (NN - m0 < mchunk) ? (NN - m0) : mchunk;
    const unsigned short* h0c = h0 + (size_t)m0 * C_IN;
    unsigned short* outc = (unsigned short*)(outf + (size_t)m0 * OUTC);
    // fused branch-1: t1 = BN+ReLU(h0 @ [w1a|w1b])  (M x 1024), bufA ld=1024
    gemm(1, 2, h0c, wt1ab, bufA, nullptr, scale_ab, shift_ab, M, DCAT, C_IN, C_IN, DCAT);
    // branch-2a/b: xcat halves (bufB, ld=1024)
    gemm(1, 1, bufA, wt2a, bufB, b2a, nullptr, nullptr, M, HID, HID, DCAT, DCAT);
    gemm(1, 1, bufA + HID, wt2b, bufB + HID, b2b, nullptr, nullptr, M, HID, HID, DCAT, DCAT);
    // head: xcat(bufB,1024) -> hfc(bufA,2048) -> hl1(bufB,4096) -> hl2(bufA,2048) -> out
    gemm(2, 3, bufB, wtfc, bufA, fc_b, nullptr, nullptr, M, DFC, DCAT, DCAT, DFC);
    gemm(2, 0, bufA, wtl1, bufB, l1_b, nullptr, nullptr, M, DL1, DFC, DFC, DL1);
    gemm(2, 0, bufB, wtl2, bufA, l2_b, nullptr, nullptr, M, DFC, DL1, DL1, DFC);
    gemm(1, 4, bufA, wtout, outc, ob, nullptr, nullptr, M, OUTC, DFC, DFC, OUTC);
  }
}

// Round 8
// 3235.398 us; speedup vs baseline: 1.2520x; 1.0258x over previous
//
#include <hip/hip_runtime.h>

// ---------------------------------------------------------------------------
// GCNConvNet: 2x GIN conv (shared aggregation) + dense head. fp32 I/O,
// bf16 MFMA internally (harness grants bf16 tolerance).
// Round 16: r15 (v6) structural schedule worked (VGPR 100, no spill, ideal
// FETCH/WRITE) but SQ_LDS_BANK_CONFLICT 0->2.32e7: with 64B rows the swizzle
// chunk = quad^(row&3) repeats every 4 lanes -> 4-way conflict (1.58x).
// v7 = v6 with f(row) = (row>>1)&3 on BOTH sides (same involution):
//   write: csrc = (lane&3) ^ ((lane>>3)&3)
//   read:  chunk = quad ^ ((r16>>1)&3)
// -> addr mod 128 spans 8 slots x 2 lanes per quad (free, matches the
// measured-clean BK=64 pattern). Everything else in v6 kept: BK=32 quad-
// buffer, stage distance 3, vmcnt(4) publish, C3 barrier-free pre-read.
// ---------------------------------------------------------------------------

#define NN 60000
#define NE 960000
#define C_IN 128
#define HID 512
#define DCAT 1024
#define DFC 2048
#define DL1 4096
#define OUTC 64

typedef __bf16 bf16x8 __attribute__((ext_vector_type(8)));
typedef float floatx4 __attribute__((ext_vector_type(4)));

__device__ __forceinline__ unsigned short f2b(float f) {
  unsigned int u = __float_as_uint(f);
  unsigned int r = (u + 0x7fffu + ((u >> 16) & 1u)) >> 16;  // RNE, finite inputs
  return (unsigned short)r;
}

// async global->LDS, 16B per lane; LDS dest = wave-uniform base + lane*16
#define GLOAD_LDS16(g, l)                                                     \
  __builtin_amdgcn_global_load_lds(                                           \
      (__attribute__((address_space(1))) void*)(g),                           \
      (__attribute__((address_space(3))) void*)(l), 16, 0, 0)

// ---------------------------------------------------------------------------
__global__ void k_bnparams(const float* __restrict__ g,
                           const float* __restrict__ be,
                           const float* __restrict__ mn,
                           const float* __restrict__ vr,
                           const float* __restrict__ b1,
                           float* __restrict__ scale, float* __restrict__ shift) {
  int i = blockIdx.x * 256 + threadIdx.x;
  if (i < HID) {
    float s = g[i] * rsqrtf(vr[i] + 1e-5f);
    scale[i] = s;
    shift[i] = (b1[i] - mn[i]) * s + be[i];
  }
}

// fp32 [K,N] -> bf16 [N,K] transpose+downcast, 32x32 tiles
__global__ void k_transpose(const float* __restrict__ in,
                            unsigned short* __restrict__ out, int K, int N) {
  __shared__ float t[32][33];
  int n0 = blockIdx.x * 32, k0 = blockIdx.y * 32;
  int tx = threadIdx.x & 31, ty = threadIdx.x >> 5;  // 32 x 8
#pragma unroll
  for (int i = 0; i < 32; i += 8)
    t[ty + i][tx] = in[(size_t)(k0 + ty + i) * N + n0 + tx];
  __syncthreads();
#pragma unroll
  for (int i = 0; i < 32; i += 8)
    out[(size_t)(n0 + ty + i) * K + k0 + tx] = f2b(t[tx][ty + i]);
}

// ---------------------------------------------------------------------------
// CSR build: deg -> exclusive scan (3 kernels) -> bucket src ids -> gather.
__global__ void k_deg(const int* __restrict__ dst, int* __restrict__ deg) {
  int e = blockIdx.x * 256 + threadIdx.x;
  if (e < NE) atomicAdd(&deg[dst[e]], 1);
}

__global__ void k_scan1(const int* __restrict__ deg, int* __restrict__ offs,
                        int* __restrict__ bsum) {
  __shared__ int t[256];
  int i = blockIdx.x * 256 + threadIdx.x;
  int v = (i < NN) ? deg[i] : 0;
  t[threadIdx.x] = v;
  __syncthreads();
#pragma unroll
  for (int d = 1; d < 256; d <<= 1) {
    int add = (threadIdx.x >= d) ? t[threadIdx.x - d] : 0;
    __syncthreads();
    t[threadIdx.x] += add;
    __syncthreads();
  }
  if (i < NN) offs[i] = t[threadIdx.x] - v;
  if (threadIdx.x == 255) bsum[blockIdx.x] = t[255];
}

__global__ void k_scan2(int* __restrict__ bsum, int nb) {
  __shared__ int t[256];
  int v = (threadIdx.x < nb) ? bsum[threadIdx.x] : 0;
  t[threadIdx.x] = v;
  __syncthreads();
#pragma unroll
  for (int d = 1; d < 256; d <<= 1) {
    int add = (threadIdx.x >= d) ? t[threadIdx.x - d] : 0;
    __syncthreads();
    t[threadIdx.x] += add;
    __syncthreads();
  }
  if (threadIdx.x < nb) bsum[threadIdx.x] = t[threadIdx.x] - v;
}

__global__ void k_scan3(int* __restrict__ offs, const int* __restrict__ bsum,
                        int* __restrict__ cursor) {
  int i = blockIdx.x * 256 + threadIdx.x;
  if (i < NN) {
    int o = offs[i] + bsum[blockIdx.x];
    offs[i] = o;
    cursor[i] = o;
  }
  if (i == 0) offs[NN] = NE;
}

__global__ void k_bucket(const int* __restrict__ src, const int* __restrict__ dst,
                         int* __restrict__ cursor, int* __restrict__ esrc) {
  int e = blockIdx.x * 256 + threadIdx.x;
  if (e < NE) {
    int slot = atomicAdd(&cursor[dst[e]], 1);
    esrc[slot] = src[e];
  }
}

// one wave per node: h0[node] = bf16(x[node] + sum_j x[esrc[j]]), f32 accum
__global__ void k_agg(const float2* __restrict__ x2, const int* __restrict__ offs,
                      const int* __restrict__ esrc, unsigned int* __restrict__ h0u) {
  int node = blockIdx.x * 4 + (threadIdx.x >> 6);
  if (node >= NN) return;
  int lane = threadIdx.x & 63;
  int beg = offs[node], end = offs[node + 1];
  float2 acc = x2[(size_t)node * 64 + lane];
  for (int j = beg; j < end; j++) {
    int s = esrc[j];  // wave-uniform -> broadcast load
    float2 v = x2[(size_t)s * 64 + lane];
    acc.x += v.x;
    acc.y += v.y;
  }
  h0u[(size_t)node * 64 + lane] =
      (unsigned)f2b(acc.x) | ((unsigned)f2b(acc.y) << 16);
}

// ---------------------------------------------------------------------------
// shared epilogue (k_gemm_g): C/D layout col=lane&15, row=quad*4+reg
template <int EPI>
__device__ __forceinline__ void gemm_epilogue(
    floatx4 (&acc)[8][4], unsigned short* C, const float* bias,
    const float* scale, const float* shift, int M, int N, int ldc, int m0,
    int n0, int w, int quad, int r16) {
#pragma unroll
  for (int j = 0; j < 4; j++) {
    int gn = n0 + w * 64 + j * 16 + r16;
    int cn = gn < N ? gn : 0;
    float p0, p1 = 0.f;
    if constexpr (EPI == 2) {
      p0 = scale[cn];
      p1 = shift[cn];
    } else {
      p0 = bias[cn];
    }
#pragma unroll
    for (int i = 0; i < 8; i++) {
#pragma unroll
      for (int t = 0; t < 4; t++) {
        int gm = m0 + i * 16 + quad * 4 + t;
        if (gm < M && gn < N) {
          float v = acc[i][j][t];
          if constexpr (EPI == 0) {
            v += p0;
            C[(size_t)gm * ldc + gn] = f2b(v);
          } else if constexpr (EPI == 1) {
            v += p0; v = v > 0.f ? v : 0.f;
            C[(size_t)gm * ldc + gn] = f2b(v);
          } else if constexpr (EPI == 2) {
            v = v * p0 + p1; v = v > 0.f ? v : 0.f;
            C[(size_t)gm * ldc + gn] = f2b(v);
          } else if constexpr (EPI == 3) {
            v += p0; v = v > 0.f ? v : 0.01f * v;
            C[(size_t)gm * ldc + gn] = f2b(v);
          } else {  // sigmoid -> fp32 network output
            v += p0;
            v = 1.f / (1.f + __expf(-v));
            ((float*)C)[(size_t)gm * ldc + gn] = v;
          }
        }
      }
    }
  }
}

__device__ __forceinline__ void gemm_swizzle(int M, int N, int& m0, int& n0) {
  const int mt_total = (M + 127) >> 7, nt_total = (N + 255) >> 8;
  int mt, nt;
  if ((nt_total & 7) == 0) {
    const int ntpx = nt_total >> 3;
    const int x = blockIdx.x & 7;
    const int s = blockIdx.x >> 3;
    nt = x * ntpx + (s % ntpx);
    mt = s / ntpx;
  } else {
    const int GM = 8;
    const int full = (mt_total / GM) * GM;
    const int boundary = full * nt_total;
    int id = blockIdx.x;
    if (id < boundary) {
      int per_group = GM * nt_total;
      int g = id / per_group, r = id % per_group;
      mt = g * GM + r % GM;
      nt = r / GM;
    } else {
      int r = id - boundary, gm = mt_total - full;
      mt = full + r % gm;
      nt = r / gm;
    }
  }
  m0 = mt << 7;
  n0 = nt << 8;
}

__device__ __forceinline__ void gemm_swizzle256(int M, int N, int& m0, int& n0) {
  const int mt_total = (M + 255) >> 8, nt_total = N >> 8;
  int mt, nt;
  if ((nt_total & 7) == 0) {
    const int ntpx = nt_total >> 3;
    const int x = blockIdx.x & 7;
    const int s = blockIdx.x >> 3;
    nt = x * ntpx + (s % ntpx);
    mt = s / ntpx;
  } else {
    const int GM = 8;
    const int full = (mt_total / GM) * GM;
    const int boundary = full * nt_total;
    int id = blockIdx.x;
    if (id < boundary) {
      int per_group = GM * nt_total;
      int g = id / per_group, r = id % per_group;
      mt = g * GM + r % GM;
      nt = r / GM;
    } else {
      int r = id - boundary, gm = mt_total - full;
      mt = full + r % gm;
      nt = r / gm;
    }
  }
  m0 = mt << 8;
  n0 = nt << 8;
}

// ---------------------------------------------------------------------------
// k_gemm_g (r8 verified): B direct global->reg; A via 4-stage glds pipeline,
// prefetch distance 3. Used for small layers (K=128, K=512, N=64 out).
template <int EPI>
__global__ __launch_bounds__(256, 2) void k_gemm_g(
    const unsigned short* __restrict__ A, const unsigned short* __restrict__ Bt,
    unsigned short* __restrict__ C, const float* __restrict__ bias,
    const float* __restrict__ scale, const float* __restrict__ shift,
    int M, int N, int K, int lda, int ldc) {
  __shared__ __align__(16) unsigned short lsA[4][4][128][8];  // 32 KB

  const int tid = threadIdx.x;
  const int w = tid >> 6;
  const int lane = tid & 63;
  const int quad = lane >> 4;
  const int r16 = lane & 15;

  int m0, n0;
  gemm_swizzle(M, N, m0, n0);

  const int ra0 = min(m0 + lane, M - 1);
  const int ra1 = min(m0 + 64 + lane, M - 1);
  const unsigned short* pA0 = A + (size_t)ra0 * lda + w * 8;
  const unsigned short* pA1 = A + (size_t)ra1 * lda + w * 8;
  const unsigned short* pB[4];
#pragma unroll
  for (int j = 0; j < 4; j++) {
    int rb = min(n0 + w * 64 + j * 16 + r16, N - 1);
    pB[j] = Bt + (size_t)rb * K + quad * 8;
  }

  floatx4 acc[8][4];
#pragma unroll
  for (int i = 0; i < 8; i++)
#pragma unroll
    for (int j = 0; j < 4; j++) acc[i][j] = (floatx4){0.f, 0.f, 0.f, 0.f};

  const int niter = K >> 5;

#define ISSUE_A(st)                                                           \
  do {                                                                        \
    GLOAD_LDS16(pA0, &lsA[st][w][0][0]);                                      \
    GLOAD_LDS16(pA1, &lsA[st][w][64][0]);                                     \
    pA0 += 32; pA1 += 32;                                                     \
  } while (0)

  ISSUE_A(0);
  if (niter > 1) ISSUE_A(1);
  if (niter > 2) ISSUE_A(2);
  bf16x8 bcur[4], bnxt[4];
#pragma unroll
  for (int j = 0; j < 4; j++) {
    bcur[j] = *(const bf16x8*)pB[j];
    pB[j] += 32;
  }

  int st = 0;
  for (int t = 0; t < niter; t++) {
    if (t + 2 < niter) {
      asm volatile("s_waitcnt vmcnt(8)\n\ts_barrier" ::: "memory");
    } else if (t + 1 < niter) {
      asm volatile("s_waitcnt vmcnt(6)\n\ts_barrier" ::: "memory");
    } else {
      asm volatile("s_waitcnt vmcnt(4)\n\ts_barrier" ::: "memory");
    }
    if (t + 3 < niter) {
      int s3 = st + 3;
      if (s3 >= 4) s3 -= 4;
      ISSUE_A(s3);
    }
    if (t + 1 < niter) {
#pragma unroll
      for (int j = 0; j < 4; j++) {
        bnxt[j] = *(const bf16x8*)pB[j];
        pB[j] += 32;
      }
    }

    bf16x8 af[8];
#pragma unroll
    for (int i = 0; i < 8; i++)
      af[i] = *(const bf16x8*)&lsA[st][quad][i * 16 + r16][0];
#pragma unroll
    for (int j = 0; j < 4; j++)
#pragma unroll
      for (int i = 0; i < 8; i++)
        acc[i][j] = __builtin_amdgcn_mfma_f32_16x16x32_bf16(af[i], bcur[j],
                                                            acc[i][j], 0, 0, 0);
#pragma unroll
    for (int j = 0; j < 4; j++) bcur[j] = bnxt[j];
    st = (st + 1) & 3;
  }
#undef ISSUE_A

  gemm_epilogue<EPI>(acc, C, bias, scale, shift, M, N, ldc, m0, n0, w, quad, r16);
}

// ---------------------------------------------------------------------------
// k_gemm8 v7: 256x256 tile, BK=32, 512 threads (8 waves, 2M x 4N), QUAD-
// buffered LDS (4 x [A 16KB | B 16KB] = 128 KB). Swizzle f(row)=(row>>1)&3
// on both sides: write source chunk (lane&3)^((lane>>3)&3); read chunk
// quad^((r16>>1)&3) -> addr mod 128 covers 8 slots x 2 lanes (conflict-free,
// same pattern as the measured-clean BK=64 layout). Stage distance 3:
// stage(T+3) issued at top of T; end-of-T barrier waits vmcnt(4) (keeps
// stage(T+3), publishes stage(T+2)). Per tile 4 clusters x 8 MFMA; C0-C2
// lookahead A reads; C3 pre-reads NEXT tile's B(4)+A(i0-1) barrier-free.
// Requires N%256==0, K%64==0 (NT even); M edge via row clamp + store guard.
// Epilogue: per-wave XOR-swizzled LDS transpose -> 16B coalesced C stores.
template <int EPI>
__global__ __launch_bounds__(512, 2) void k_gemm8(
    const unsigned short* __restrict__ A, const unsigned short* __restrict__ Bt,
    unsigned short* __restrict__ C, const float* __restrict__ bias,
    const float* __restrict__ scale, const float* __restrict__ shift,
    int M, int N, int K, int lda, int ldc) {
  __shared__ __align__(16) unsigned short smem[4][2][256][32];  // 128 KB

  const int tid = threadIdx.x;
  const int w = tid >> 6;   // wave 0..7
  const int lane = tid & 63;
  const int wm = w >> 2;    // 0..1  (M half: rows wm*128..)
  const int wn = w & 3;     // 0..3  (N quarter: cols wn*64..)
  const int quad = lane >> 4;
  const int r16 = lane & 15;

  int m0, n0;
  gemm_swizzle256(M, N, m0, n0);

  // ---- staging addresses (pre-swizzled global source; 64B rows, 4 chunks) --
  // LDS[row][pos] holds global chunk pos ^ ((row>>1)&3)
  const int w16l = w * 16 + (lane >> 2);             // row within 128-row half
  const int csrc = (lane & 3) ^ ((lane >> 3) & 3);   // = (lane&3) ^ f(row)
  unsigned offA[2], offB[2];                         // byte offsets, [h]
#pragma unroll
  for (int h = 0; h < 2; h++) {
    int ra = m0 + h * 128 + w16l;
    ra = ra < M ? ra : (M - 1);
    offA[h] = (unsigned)ra * (unsigned)(lda * 2) + (unsigned)(csrc * 16);
    int rb = n0 + h * 128 + w16l;                    // N%256==0: no clamp
    offB[h] = (unsigned)rb * (unsigned)(K * 2) + (unsigned)(csrc * 16);
  }
  const char* Ac = (const char*)A;
  const char* Bc = (const char*)Bt;
  char* smc = (char*)smem;
  const unsigned wdst = (unsigned)(w * 1024);  // wave's 16-row slice (16*64 B)

  // stage full tile T_ (A 16KB + B 16KB) into buf T_&3; 4 glds per thread
#define STG32(T_)                                                             \
  do {                                                                        \
    unsigned kb_ = (unsigned)(T_) * 64u;                                      \
    unsigned db_ = (unsigned)(((T_) & 3) * 32768) + wdst;                     \
    GLOAD_LDS16(Ac + offA[0] + kb_, smc + db_);                               \
    GLOAD_LDS16(Ac + offA[1] + kb_, smc + db_ + 8192u);                       \
    GLOAD_LDS16(Bc + offB[0] + kb_, smc + db_ + 16384u);                      \
    GLOAD_LDS16(Bc + offB[1] + kb_, smc + db_ + 24576u);                      \
  } while (0)

  // ---- fragment read offsets (chunk pos = quad ^ f(row), f=(row>>1)&3) ----
  const unsigned cKq = (unsigned)(((quad ^ ((r16 >> 1) & 3)) & 3) * 16);
  const unsigned rdA = (unsigned)((wm * 128 + r16) * 64) + cKq;
  const unsigned rdB = 16384u + (unsigned)((wn * 64 + r16) * 64) + cKq;

#define RD_A32(so_, i_) (*(const bf16x8*)(smc + (so_) + rdA + (unsigned)((i_)*1024)))
#define RD_B32(so_, j_) (*(const bf16x8*)(smc + (so_) + rdB + (unsigned)((j_)*1024)))

  floatx4 acc[8][4];
#pragma unroll
  for (int i = 0; i < 8; i++)
#pragma unroll
    for (int j = 0; j < 4; j++) acc[i][j] = (floatx4){0.f, 0.f, 0.f, 0.f};

  const int NT = K >> 5;  // even (K%64==0 for all var-2 layers)

  // 8-MFMA cluster: i-pair (i0_, i0_+1) x j0-3, one K-step of 32
#define MM1(i0_, AF, BF)                                                      \
  do {                                                                        \
    __builtin_amdgcn_s_setprio(1);                                            \
    _Pragma("unroll")                                                         \
    for (int jj = 0; jj < 4; jj++) {                                          \
      acc[(i0_)][jj] = __builtin_amdgcn_mfma_f32_16x16x32_bf16(               \
          AF[0], BF[jj], acc[(i0_)][jj], 0, 0, 0);                            \
      acc[(i0_) + 1][jj] = __builtin_amdgcn_mfma_f32_16x16x32_bf16(           \
          AF[1], BF[jj], acc[(i0_) + 1][jj], 0, 0, 0);                        \
    }                                                                         \
    __builtin_amdgcn_s_setprio(0);                                            \
  } while (0)

  // ---- prologue: stage 0,1,2; publish 0 AND 1 (keep 2); pre-read tile 0 ----
  STG32(0);
  if (NT > 1) STG32(1);
  if (NT > 2) STG32(2);
  if (NT > 2) {
    asm volatile("s_waitcnt vmcnt(4)\n\ts_barrier" ::: "memory");
  } else {
    asm volatile("s_waitcnt vmcnt(0)\n\ts_barrier" ::: "memory");
  }

  bf16x8 bF[4], bG[4], aX[2], aY[2];
#pragma unroll
  for (int j = 0; j < 4; j++) bF[j] = RD_B32(0u, j);
  aX[0] = RD_A32(0u, 0);
  aX[1] = RD_A32(0u, 1);

  // tile body: BC = current B regs, BN = next tile's B regs (pre-read in C3)
#define TILE(T_, BC, BN)                                                      \
  do {                                                                        \
    const unsigned so = (unsigned)(((T_) & 3) * 32768);                       \
    const unsigned so1 = (unsigned)((((T_) + 1) & 3) * 32768);                \
    if ((T_) + 3 < NT) STG32((T_) + 3);                                       \
    /* C0: read aY(i2-3); MFMA i0-1 */                                        \
    aY[0] = RD_A32(so, 2); aY[1] = RD_A32(so, 3);                             \
    MM1(0, aX, BC);                                                           \
    /* C1: read aX(i4-5); MFMA i2-3 */                                        \
    aX[0] = RD_A32(so, 4); aX[1] = RD_A32(so, 5);                             \
    MM1(2, aY, BC);                                                           \
    /* C2: read aY(i6-7); MFMA i4-5 */                                        \
    aY[0] = RD_A32(so, 6); aY[1] = RD_A32(so, 7);                             \
    MM1(4, aX, BC);                                                           \
    /* C3: pre-read next tile's B + A(i0-1) (buffer published at end of T-1); \
       MFMA i6-7 rides over the reads */                                      \
    if ((T_) + 1 < NT) {                                                      \
      BN[0] = RD_B32(so1, 0); BN[1] = RD_B32(so1, 1);                         \
      BN[2] = RD_B32(so1, 2); BN[3] = RD_B32(so1, 3);                         \
      aX[0] = RD_A32(so1, 0); aX[1] = RD_A32(so1, 1);                         \
    }                                                                         \
    MM1(6, aY, BC);                                                           \
    /* boundary: publish stage(T+2), keep stage(T+3) in flight */             \
    if ((T_) + 1 < NT) {                                                      \
      if ((T_) + 3 < NT) {                                                    \
        asm volatile("s_waitcnt vmcnt(4)\n\ts_barrier" ::: "memory");         \
      } else {                                                                \
        asm volatile("s_waitcnt vmcnt(0)\n\ts_barrier" ::: "memory");         \
      }                                                                       \
    }                                                                         \
  } while (0)

  for (int T = 0; T < NT; T += 2) {
    TILE(T, bF, bG);
    TILE(T + 1, bG, bF);
  }
#undef TILE
#undef MM1
#undef STG32
#undef RD_A32
#undef RD_B32

  // ---- epilogue: per-wave XOR-swizzled LDS transpose -> 16B stores ----
  __syncthreads();  // all waves done with main-loop LDS
  char* eb = smc + (unsigned)(w * 16384);  // wave-private 16KB (128 rows x 128B)
#pragma unroll
  for (int j = 0; j < 4; j++) {
    int gn = n0 + wn * 64 + j * 16 + r16;
    float p0 = 0.f, p1 = 0.f;
    if constexpr (EPI == 2) {
      p0 = scale[gn];
      p1 = shift[gn];
    } else {
      p0 = bias[gn];
    }
#pragma unroll
    for (int i = 0; i < 8; i++)
#pragma unroll
      for (int t = 0; t < 4; t++) {
        float v = acc[i][j][t];
        if constexpr (EPI == 0) {
          v += p0;
        } else if constexpr (EPI == 1) {
          v += p0; v = v > 0.f ? v : 0.f;
        } else if constexpr (EPI == 2) {
          v = v * p0 + p1; v = v > 0.f ? v : 0.f;
        } else {  // EPI 3 (leaky); EPI 4 unused by k_gemm8
          v += p0; v = v > 0.f ? v : 0.01f * v;
        }
        int row = i * 16 + quad * 4 + t;
        int col = j * 16 + r16;
        *(unsigned short*)(eb + row * 128 + (((col >> 3) ^ (row & 7)) << 4) +
                           ((col & 7) << 1)) = f2b(v);
      }
  }
  // read back own region (no cross-wave sync needed), 16B coalesced stores
#pragma unroll
  for (int r8 = 0; r8 < 16; r8++) {
    int row = r8 * 8 + (lane >> 3);
    int chunkG = lane & 7;
    bf16x8 vv = *(const bf16x8*)(eb + row * 128 + ((chunkG ^ (lane >> 3)) << 4));
    int gm = m0 + wm * 128 + row;
    if (gm < M)
      *(bf16x8*)(C + (size_t)gm * ldc + (n0 + wn * 64 + chunkG * 8)) = vv;
  }
}

// ---------------------------------------------------------------------------
extern "C" void kernel_launch(void* const* d_in, const int* in_sizes, int n_in,
                              void* d_out, int out_size, void* d_ws,
                              size_t ws_size, hipStream_t stream) {
  typedef const float* cf;
  cf x = (cf)d_in[0];
  const int* ei = (const int*)d_in[1];
  const int* srcI = ei;
  const int* dstI = ei + NE;
  cf w1a = (cf)d_in[2],  b1a = (cf)d_in[3];
  cf ga = (cf)d_in[4],   bea = (cf)d_in[5];
  cf mna = (cf)d_in[6],  vra = (cf)d_in[7];
  cf w2a = (cf)d_in[8],  b2a = (cf)d_in[9];
  cf w1b = (cf)d_in[10], b1b = (cf)d_in[11];
  cf gb = (cf)d_in[12],  beb = (cf)d_in[13];
  cf mnb = (cf)d_in[14], vrb = (cf)d_in[15];
  cf w2b = (cf)d_in[16], b2b = (cf)d_in[17];
  cf fc_w = (cf)d_in[18], fc_b = (cf)d_in[19];
  cf l1_w = (cf)d_in[20], l1_b = (cf)d_in[21];
  cf l2_w = (cf)d_in[22], l2_b = (cf)d_in[23];
  cf ow = (cf)d_in[24],   ob = (cf)d_in[25];
  float* outf = (float*)d_out;

  // ---- workspace carve-up ----------------------------------------------------
  char* ws = (char*)d_ws;
  size_t off = 0;
  auto carve = [&](size_t bytes) {
    void* p = ws + off;
    off += (bytes + 255) & ~(size_t)255;
    return p;
  };
  unsigned short* wt1ab = (unsigned short*)carve((size_t)DCAT * C_IN * 2);
  unsigned short* wt2a = (unsigned short*)carve((size_t)HID * HID * 2);
  unsigned short* wt2b = (unsigned short*)carve((size_t)HID * HID * 2);
  unsigned short* wtfc = (unsigned short*)carve((size_t)DFC * DCAT * 2);
  unsigned short* wtl1 = (unsigned short*)carve((size_t)DL1 * DFC * 2);
  unsigned short* wtl2 = (unsigned short*)carve((size_t)DFC * DL1 * 2);
  unsigned short* wtout = (unsigned short*)carve((size_t)OUTC * DFC * 2);
  float* scale_ab = (float*)carve(DCAT * 4);
  float* shift_ab = (float*)carve(DCAT * 4);
  unsigned short* h0 = (unsigned short*)carve((size_t)NN * C_IN * 2);

  // phase-1-only CSR arrays, OVERLAID with phase-2 activation buffers
  size_t off_overlay = off;
  int* deg = (int*)carve((size_t)NN * 4);
  int* offs = (int*)carve((size_t)(NN + 1) * 4);
  int* cursor = (int*)carve((size_t)NN * 4);
  int* bsum = (int*)carve(256 * 4);
  int* esrc = (int*)carve((size_t)NE * 4);

  off = off_overlay;
  size_t rem = (ws_size > off + 4096) ? (ws_size - off - 4096) : 0;
  int mchunk = (int)(rem / ((DFC + DL1) * 2));
  if (mchunk > 15104) mchunk = 15104;
  mchunk &= ~127;
  if (mchunk < 128) mchunk = 128;
  unsigned short* bufA = (unsigned short*)carve((size_t)mchunk * DFC * 2);
  unsigned short* bufB = (unsigned short*)carve((size_t)mchunk * DL1 * 2);
  (void)in_sizes; (void)n_in; (void)out_size;

  // ---- phase 0: params + weight transposes ----------------------------------
  k_bnparams<<<2, 256, 0, stream>>>(ga, bea, mna, vra, b1a, scale_ab, shift_ab);
  k_bnparams<<<2, 256, 0, stream>>>(gb, beb, mnb, vrb, b1b, scale_ab + HID,
                                    shift_ab + HID);
  k_transpose<<<dim3(HID / 32, C_IN / 32), 256, 0, stream>>>(w1a, wt1ab, C_IN, HID);
  k_transpose<<<dim3(HID / 32, C_IN / 32), 256, 0, stream>>>(
      w1b, wt1ab + (size_t)HID * C_IN, C_IN, HID);
  k_transpose<<<dim3(HID / 32, HID / 32), 256, 0, stream>>>(w2a, wt2a, HID, HID);
  k_transpose<<<dim3(HID / 32, HID / 32), 256, 0, stream>>>(w2b, wt2b, HID, HID);
  k_transpose<<<dim3(DFC / 32, DCAT / 32), 256, 0, stream>>>(fc_w, wtfc, DCAT, DFC);
  k_transpose<<<dim3(DL1 / 32, DFC / 32), 256, 0, stream>>>(l1_w, wtl1, DFC, DL1);
  k_transpose<<<dim3(DFC / 32, DL1 / 32), 256, 0, stream>>>(l2_w, wtl2, DL1, DFC);
  k_transpose<<<dim3(OUTC / 32, DFC / 32), 256, 0, stream>>>(ow, wtout, DFC, OUTC);

  // ---- phase 1: CSR build + gather aggregation -------------------------------
  const int NB_NODE = (NN + 255) / 256;
  hipMemsetAsync(deg, 0, (size_t)NN * 4, stream);
  k_deg<<<(NE + 255) / 256, 256, 0, stream>>>(dstI, deg);
  k_scan1<<<NB_NODE, 256, 0, stream>>>(deg, offs, bsum);
  k_scan2<<<1, 256, 0, stream>>>(bsum, NB_NODE);
  k_scan3<<<NB_NODE, 256, 0, stream>>>(offs, bsum, cursor);
  k_bucket<<<(NE + 255) / 256, 256, 0, stream>>>(srcI, dstI, cursor, esrc);
  k_agg<<<(NN + 3) / 4, 256, 0, stream>>>((const float2*)x, offs, esrc,
                                          (unsigned int*)h0);

  // ---- phase 2: GEMM chain ---------------------------------------------------
  // var 1 = G (128x256, B-direct);  var 2 = v7 256x256 (N%256==0, K%64==0)
  auto gemm = [&](int var, int epi, const unsigned short* A,
                  const unsigned short* Bt, unsigned short* Cp, cf bias,
                  const float* sc, const float* sh, int M, int N, int K,
                  int lda, int ldc) {
    if (var == 2) {
      dim3 g(((M + 255) / 256) * (N / 256));
      switch (epi) {
        case 0: k_gemm8<0><<<g, 512, 0, stream>>>(A, Bt, Cp, bias, sc, sh, M, N, K, lda, ldc); break;
        default: k_gemm8<3><<<g, 512, 0, stream>>>(A, Bt, Cp, bias, sc, sh, M, N, K, lda, ldc); break;
      }
    } else {
      dim3 g(((M + 127) / 128) * ((N + 255) / 256));
      switch (epi) {
        case 0: k_gemm_g<0><<<g, 256, 0, stream>>>(A, Bt, Cp, bias, sc, sh, M, N, K, lda, ldc); break;
        case 1: k_gemm_g<1><<<g, 256, 0, stream>>>(A, Bt, Cp, bias, sc, sh, M, N, K, lda, ldc); break;
        case 2: k_gemm_g<2><<<g, 256, 0, stream>>>(A, Bt, Cp, bias, sc, sh, M, N, K, lda, ldc); break;
        case 3: k_gemm_g<3><<<g, 256, 0, stream>>>(A, Bt, Cp, bias, sc, sh, M, N, K, lda, ldc); break;
        default: k_gemm_g<4><<<g, 256, 0, stream>>>(A, Bt, Cp, bias, sc, sh, M, N, K, lda, ldc); break;
      }
    }
  };

  for (int m0 = 0; m0 < NN; m0 += mchunk) {
    const int M = (NN - m0 < mchunk) ? (NN - m0) : mchunk;
    const unsigned short* h0c = h0 + (size_t)m0 * C_IN;
    unsigned short* outc = (unsigned short*)(outf + (size_t)m0 * OUTC);
    // fused branch-1: t1 = BN+ReLU(h0 @ [w1a|w1b])  (M x 1024), bufA ld=1024
    gemm(1, 2, h0c, wt1ab, bufA, nullptr, scale_ab, shift_ab, M, DCAT, C_IN, C_IN, DCAT);
    // branch-2a/b: xcat halves (bufB, ld=1024)
    gemm(1, 1, bufA, wt2a, bufB, b2a, nullptr, nullptr, M, HID, HID, DCAT, DCAT);
    gemm(1, 1, bufA + HID, wt2b, bufB + HID, b2b, nullptr, nullptr, M, HID, HID, DCAT, DCAT);
    // head: xcat(bufB,1024) -> hfc(bufA,2048) -> hl1(bufB,4096) -> hl2(bufA,2048) -> out
    gemm(2, 3, bufB, wtfc, bufA, fc_b, nullptr, nullptr, M, DFC, DCAT, DCAT, DFC);
    gemm(2, 0, bufA, wtl1, bufB, l1_b, nullptr, nullptr, M, DL1, DFC, DFC, DL1);
    gemm(2, 0, bufB, wtl2, bufA, l2_b, nullptr, nullptr, M, DFC, DL1, DL1, DFC);
    gemm(1, 4, bufA, wtout, outc, ob, nullptr, nullptr, M, OUTC, DFC, DFC, OUTC);
  }
}

// Round 10
// 3183.941 us; speedup vs baseline: 1.2722x; 1.0162x over previous
//
#include <hip/hip_runtime.h>

// ---------------------------------------------------------------------------
// GCNConvNet: 2x GIN conv (shared aggregation) + dense head. fp32 I/O,
// bf16 MFMA internally (harness grants bf16 tolerance).
// Round 18: r17 (v8) never benched (container died) but had a fatal bug:
// __launch_bounds__(512,4) demands <=128 regs/wave vs our ~228 (100 arch +
// 128 acc) -> forced spill storm. Register math: pool ~512 wave-regs/SIMD
// -> 2 waves/SIMD max at acc[8][4]; two 8-wave blocks can NEVER co-reside.
// v9: recover with r12/v3 (verified 236us l1) as control, plus k_gemm8b:
// v7's verified BK=32 quad-buffer components rescheduled as TILE PAIRS --
// one vmcnt(0)+s_barrier per 128 K-elems (half of v3's barrier rate). t1's
// operands pre-read mid-pair (buffer published at previous pair's barrier).
// A/B in one launch: l1 = v3 control, l2 + fc = pair variant.
// ---------------------------------------------------------------------------

#define NN 60000
#define NE 960000
#define C_IN 128
#define HID 512
#define DCAT 1024
#define DFC 2048
#define DL1 4096
#define OUTC 64

typedef __bf16 bf16x8 __attribute__((ext_vector_type(8)));
typedef float floatx4 __attribute__((ext_vector_type(4)));

__device__ __forceinline__ unsigned short f2b(float f) {
  unsigned int u = __float_as_uint(f);
  unsigned int r = (u + 0x7fffu + ((u >> 16) & 1u)) >> 16;  // RNE, finite inputs
  return (unsigned short)r;
}

// async global->LDS, 16B per lane; LDS dest = wave-uniform base + lane*16
#define GLOAD_LDS16(g, l)                                                     \
  __builtin_amdgcn_global_load_lds(                                           \
      (__attribute__((address_space(1))) void*)(g),                           \
      (__attribute__((address_space(3))) void*)(l), 16, 0, 0)

// ---------------------------------------------------------------------------
__global__ void k_bnparams(const float* __restrict__ g,
                           const float* __restrict__ be,
                           const float* __restrict__ mn,
                           const float* __restrict__ vr,
                           const float* __restrict__ b1,
                           float* __restrict__ scale, float* __restrict__ shift) {
  int i = blockIdx.x * 256 + threadIdx.x;
  if (i < HID) {
    float s = g[i] * rsqrtf(vr[i] + 1e-5f);
    scale[i] = s;
    shift[i] = (b1[i] - mn[i]) * s + be[i];
  }
}

// fp32 [K,N] -> bf16 [N,K] transpose+downcast, 32x32 tiles
__global__ void k_transpose(const float* __restrict__ in,
                            unsigned short* __restrict__ out, int K, int N) {
  __shared__ float t[32][33];
  int n0 = blockIdx.x * 32, k0 = blockIdx.y * 32;
  int tx = threadIdx.x & 31, ty = threadIdx.x >> 5;  // 32 x 8
#pragma unroll
  for (int i = 0; i < 32; i += 8)
    t[ty + i][tx] = in[(size_t)(k0 + ty + i) * N + n0 + tx];
  __syncthreads();
#pragma unroll
  for (int i = 0; i < 32; i += 8)
    out[(size_t)(n0 + ty + i) * K + k0 + tx] = f2b(t[tx][ty + i]);
}

// ---------------------------------------------------------------------------
// CSR build: deg -> exclusive scan (3 kernels) -> bucket src ids -> gather.
__global__ void k_deg(const int* __restrict__ dst, int* __restrict__ deg) {
  int e = blockIdx.x * 256 + threadIdx.x;
  if (e < NE) atomicAdd(&deg[dst[e]], 1);
}

__global__ void k_scan1(const int* __restrict__ deg, int* __restrict__ offs,
                        int* __restrict__ bsum) {
  __shared__ int t[256];
  int i = blockIdx.x * 256 + threadIdx.x;
  int v = (i < NN) ? deg[i] : 0;
  t[threadIdx.x] = v;
  __syncthreads();
#pragma unroll
  for (int d = 1; d < 256; d <<= 1) {
    int add = (threadIdx.x >= d) ? t[threadIdx.x - d] : 0;
    __syncthreads();
    t[threadIdx.x] += add;
    __syncthreads();
  }
  if (i < NN) offs[i] = t[threadIdx.x] - v;
  if (threadIdx.x == 255) bsum[blockIdx.x] = t[255];
}

__global__ void k_scan2(int* __restrict__ bsum, int nb) {
  __shared__ int t[256];
  int v = (threadIdx.x < nb) ? bsum[threadIdx.x] : 0;
  t[threadIdx.x] = v;
  __syncthreads();
#pragma unroll
  for (int d = 1; d < 256; d <<= 1) {
    int add = (threadIdx.x >= d) ? t[threadIdx.x - d] : 0;
    __syncthreads();
    t[threadIdx.x] += add;
    __syncthreads();
  }
  if (threadIdx.x < nb) bsum[threadIdx.x] = t[threadIdx.x] - v;
}

__global__ void k_scan3(int* __restrict__ offs, const int* __restrict__ bsum,
                        int* __restrict__ cursor) {
  int i = blockIdx.x * 256 + threadIdx.x;
  if (i < NN) {
    int o = offs[i] + bsum[blockIdx.x];
    offs[i] = o;
    cursor[i] = o;
  }
  if (i == 0) offs[NN] = NE;
}

__global__ void k_bucket(const int* __restrict__ src, const int* __restrict__ dst,
                         int* __restrict__ cursor, int* __restrict__ esrc) {
  int e = blockIdx.x * 256 + threadIdx.x;
  if (e < NE) {
    int slot = atomicAdd(&cursor[dst[e]], 1);
    esrc[slot] = src[e];
  }
}

// one wave per node: h0[node] = bf16(x[node] + sum_j x[esrc[j]]), f32 accum
__global__ void k_agg(const float2* __restrict__ x2, const int* __restrict__ offs,
                      const int* __restrict__ esrc, unsigned int* __restrict__ h0u) {
  int node = blockIdx.x * 4 + (threadIdx.x >> 6);
  if (node >= NN) return;
  int lane = threadIdx.x & 63;
  int beg = offs[node], end = offs[node + 1];
  float2 acc = x2[(size_t)node * 64 + lane];
  for (int j = beg; j < end; j++) {
    int s = esrc[j];  // wave-uniform -> broadcast load
    float2 v = x2[(size_t)s * 64 + lane];
    acc.x += v.x;
    acc.y += v.y;
  }
  h0u[(size_t)node * 64 + lane] =
      (unsigned)f2b(acc.x) | ((unsigned)f2b(acc.y) << 16);
}

// ---------------------------------------------------------------------------
// shared epilogue (k_gemm_g): C/D layout col=lane&15, row=quad*4+reg
template <int EPI>
__device__ __forceinline__ void gemm_epilogue(
    floatx4 (&acc)[8][4], unsigned short* C, const float* bias,
    const float* scale, const float* shift, int M, int N, int ldc, int m0,
    int n0, int w, int quad, int r16) {
#pragma unroll
  for (int j = 0; j < 4; j++) {
    int gn = n0 + w * 64 + j * 16 + r16;
    int cn = gn < N ? gn : 0;
    float p0, p1 = 0.f;
    if constexpr (EPI == 2) {
      p0 = scale[cn];
      p1 = shift[cn];
    } else {
      p0 = bias[cn];
    }
#pragma unroll
    for (int i = 0; i < 8; i++) {
#pragma unroll
      for (int t = 0; t < 4; t++) {
        int gm = m0 + i * 16 + quad * 4 + t;
        if (gm < M && gn < N) {
          float v = acc[i][j][t];
          if constexpr (EPI == 0) {
            v += p0;
            C[(size_t)gm * ldc + gn] = f2b(v);
          } else if constexpr (EPI == 1) {
            v += p0; v = v > 0.f ? v : 0.f;
            C[(size_t)gm * ldc + gn] = f2b(v);
          } else if constexpr (EPI == 2) {
            v = v * p0 + p1; v = v > 0.f ? v : 0.f;
            C[(size_t)gm * ldc + gn] = f2b(v);
          } else if constexpr (EPI == 3) {
            v += p0; v = v > 0.f ? v : 0.01f * v;
            C[(size_t)gm * ldc + gn] = f2b(v);
          } else {  // sigmoid -> fp32 network output
            v += p0;
            v = 1.f / (1.f + __expf(-v));
            ((float*)C)[(size_t)gm * ldc + gn] = v;
          }
        }
      }
    }
  }
}

__device__ __forceinline__ void gemm_swizzle(int M, int N, int& m0, int& n0) {
  const int mt_total = (M + 127) >> 7, nt_total = (N + 255) >> 8;
  int mt, nt;
  if ((nt_total & 7) == 0) {
    const int ntpx = nt_total >> 3;
    const int x = blockIdx.x & 7;
    const int s = blockIdx.x >> 3;
    nt = x * ntpx + (s % ntpx);
    mt = s / ntpx;
  } else {
    const int GM = 8;
    const int full = (mt_total / GM) * GM;
    const int boundary = full * nt_total;
    int id = blockIdx.x;
    if (id < boundary) {
      int per_group = GM * nt_total;
      int g = id / per_group, r = id % per_group;
      mt = g * GM + r % GM;
      nt = r / GM;
    } else {
      int r = id - boundary, gm = mt_total - full;
      mt = full + r % gm;
      nt = r / gm;
    }
  }
  m0 = mt << 7;
  n0 = nt << 8;
}

__device__ __forceinline__ void gemm_swizzle256(int M, int N, int& m0, int& n0) {
  const int mt_total = (M + 255) >> 8, nt_total = N >> 8;
  int mt, nt;
  if ((nt_total & 7) == 0) {
    const int ntpx = nt_total >> 3;
    const int x = blockIdx.x & 7;
    const int s = blockIdx.x >> 3;
    nt = x * ntpx + (s % ntpx);
    mt = s / ntpx;
  } else {
    const int GM = 8;
    const int full = (mt_total / GM) * GM;
    const int boundary = full * nt_total;
    int id = blockIdx.x;
    if (id < boundary) {
      int per_group = GM * nt_total;
      int g = id / per_group, r = id % per_group;
      mt = g * GM + r % GM;
      nt = r / GM;
    } else {
      int r = id - boundary, gm = mt_total - full;
      mt = full + r % gm;
      nt = r / gm;
    }
  }
  m0 = mt << 8;
  n0 = nt << 8;
}

// ---------------------------------------------------------------------------
// k_gemm_g (r8 verified): B direct global->reg; A via 4-stage glds pipeline,
// prefetch distance 3. Used for small layers (K=128, K=512, N=64 out).
template <int EPI>
__global__ __launch_bounds__(256, 2) void k_gemm_g(
    const unsigned short* __restrict__ A, const unsigned short* __restrict__ Bt,
    unsigned short* __restrict__ C, const float* __restrict__ bias,
    const float* __restrict__ scale, const float* __restrict__ shift,
    int M, int N, int K, int lda, int ldc) {
  __shared__ __align__(16) unsigned short lsA[4][4][128][8];  // 32 KB

  const int tid = threadIdx.x;
  const int w = tid >> 6;
  const int lane = tid & 63;
  const int quad = lane >> 4;
  const int r16 = lane & 15;

  int m0, n0;
  gemm_swizzle(M, N, m0, n0);

  const int ra0 = min(m0 + lane, M - 1);
  const int ra1 = min(m0 + 64 + lane, M - 1);
  const unsigned short* pA0 = A + (size_t)ra0 * lda + w * 8;
  const unsigned short* pA1 = A + (size_t)ra1 * lda + w * 8;
  const unsigned short* pB[4];
#pragma unroll
  for (int j = 0; j < 4; j++) {
    int rb = min(n0 + w * 64 + j * 16 + r16, N - 1);
    pB[j] = Bt + (size_t)rb * K + quad * 8;
  }

  floatx4 acc[8][4];
#pragma unroll
  for (int i = 0; i < 8; i++)
#pragma unroll
    for (int j = 0; j < 4; j++) acc[i][j] = (floatx4){0.f, 0.f, 0.f, 0.f};

  const int niter = K >> 5;

#define ISSUE_A(st)                                                           \
  do {                                                                        \
    GLOAD_LDS16(pA0, &lsA[st][w][0][0]);                                      \
    GLOAD_LDS16(pA1, &lsA[st][w][64][0]);                                     \
    pA0 += 32; pA1 += 32;                                                     \
  } while (0)

  ISSUE_A(0);
  if (niter > 1) ISSUE_A(1);
  if (niter > 2) ISSUE_A(2);
  bf16x8 bcur[4], bnxt[4];
#pragma unroll
  for (int j = 0; j < 4; j++) {
    bcur[j] = *(const bf16x8*)pB[j];
    pB[j] += 32;
  }

  int st = 0;
  for (int t = 0; t < niter; t++) {
    if (t + 2 < niter) {
      asm volatile("s_waitcnt vmcnt(8)\n\ts_barrier" ::: "memory");
    } else if (t + 1 < niter) {
      asm volatile("s_waitcnt vmcnt(6)\n\ts_barrier" ::: "memory");
    } else {
      asm volatile("s_waitcnt vmcnt(4)\n\ts_barrier" ::: "memory");
    }
    if (t + 3 < niter) {
      int s3 = st + 3;
      if (s3 >= 4) s3 -= 4;
      ISSUE_A(s3);
    }
    if (t + 1 < niter) {
#pragma unroll
      for (int j = 0; j < 4; j++) {
        bnxt[j] = *(const bf16x8*)pB[j];
        pB[j] += 32;
      }
    }

    bf16x8 af[8];
#pragma unroll
    for (int i = 0; i < 8; i++)
      af[i] = *(const bf16x8*)&lsA[st][quad][i * 16 + r16][0];
#pragma unroll
    for (int j = 0; j < 4; j++)
#pragma unroll
      for (int i = 0; i < 8; i++)
        acc[i][j] = __builtin_amdgcn_mfma_f32_16x16x32_bf16(af[i], bcur[j],
                                                            acc[i][j], 0, 0, 0);
#pragma unroll
    for (int j = 0; j < 4; j++) bcur[j] = bnxt[j];
    st = (st + 1) & 3;
  }
#undef ISSUE_A

  gemm_epilogue<EPI>(acc, C, bias, scale, shift, M, N, ldc, m0, n0, w, quad, r16);
}

// ---------------------------------------------------------------------------
// k_gemm8 (r12/v3 CONTROL, verified 236us l1): 256x256, BK=64, 8 waves,
// 128KB A+B dbuf, XOR chunk swizzle, ONE vmcnt(0)+barrier per BK64 tile,
// 4 MFMA clusters with 1-cluster-lookahead A reads.
template <int EPI>
__global__ __launch_bounds__(512, 2) void k_gemm8(
    const unsigned short* __restrict__ A, const unsigned short* __restrict__ Bt,
    unsigned short* __restrict__ C, const float* __restrict__ bias,
    const float* __restrict__ scale, const float* __restrict__ shift,
    int M, int N, int K, int lda, int ldc) {
  __shared__ __align__(16) unsigned short smem[2][2][256][64];  // 128 KB

  const int tid = threadIdx.x;
  const int w = tid >> 6;   // wave 0..7
  const int lane = tid & 63;
  const int wm = w >> 2;    // 0..1  (M half: rows wm*128..)
  const int wn = w & 3;     // 0..3  (N quarter: cols wn*64..)
  const int quad = lane >> 4;
  const int r16 = lane & 15;

  int m0, n0;
  gemm_swizzle256(M, N, m0, n0);

  const int w8l = w * 8 + (lane >> 3);               // row within 64-row q-block
  const int csrc = (lane & 7) ^ ((lane >> 3) & 7);   // source chunk for lane
  unsigned offA[2][2], offB[2][2];                   // byte offsets
#pragma unroll
  for (int h = 0; h < 2; h++)
#pragma unroll
    for (int q = 0; q < 2; q++) {
      int ra = m0 + h * 128 + q * 64 + w8l;
      ra = ra < M ? ra : (M - 1);
      offA[h][q] = (unsigned)ra * (unsigned)(lda * 2) + (unsigned)(csrc * 16);
      int rb = n0 + h * 128 + q * 64 + w8l;          // N%256==0: no clamp
      offB[h][q] = (unsigned)rb * (unsigned)(K * 2) + (unsigned)(csrc * 16);
    }
  const char* Ac = (const char*)A;
  const char* Bc = (const char*)Bt;
  char* smc = (char*)smem;
  const unsigned wdst = (unsigned)(w * 1024);  // wave's 8-row slice (8*128 B)

#define STG_A(T_, h_)                                                          \
  do {                                                                         \
    unsigned kb_ = (unsigned)(T_) * 128u;                                      \
    unsigned db_ = (unsigned)(((T_) & 1) << 16) + (unsigned)((h_) * 16384) + wdst; \
    GLOAD_LDS16(Ac + offA[h_][0] + kb_, smc + db_);                            \
    GLOAD_LDS16(Ac + offA[h_][1] + kb_, smc + db_ + 8192u);                    \
  } while (0)
#define STG_B(T_, h_)                                                          \
  do {                                                                         \
    unsigned kb_ = (unsigned)(T_) * 128u;                                      \
    unsigned db_ = (unsigned)(((T_) & 1) << 16) + 32768u +                     \
                   (unsigned)((h_) * 16384) + wdst;                            \
    GLOAD_LDS16(Bc + offB[h_][0] + kb_, smc + db_);                            \
    GLOAD_LDS16(Bc + offB[h_][1] + kb_, smc + db_ + 8192u);                    \
  } while (0)

  const int swz = r16 & 7;
  const unsigned cK0 = (unsigned)(((quad) ^ swz) * 16);       // ks=0
  const unsigned cK1 = (unsigned)(((4 + quad) ^ swz) * 16);   // ks=1
  const unsigned rdA = (unsigned)((wm * 128 + r16) * 128);
  const unsigned rdB = 32768u + (unsigned)((wn * 64 + r16) * 128);

#define RD_A(bo_, i_, c_) (*(const bf16x8*)(smc + (bo_) + rdA + (unsigned)((i_)*2048) + (c_)))
#define RD_B(bo_, j_, c_) (*(const bf16x8*)(smc + (bo_) + rdB + (unsigned)((j_)*2048) + (c_)))

  floatx4 acc[8][4];
#pragma unroll
  for (int i = 0; i < 8; i++)
#pragma unroll
    for (int j = 0; j < 4; j++) acc[i][j] = (floatx4){0.f, 0.f, 0.f, 0.f};

  const int NT = K >> 6;

#define MM2(i0_, AF)                                                          \
  do {                                                                        \
    __builtin_amdgcn_s_setprio(1);                                            \
    _Pragma("unroll")                                                         \
    for (int jj = 0; jj < 4; jj++) {                                          \
      acc[(i0_)][jj] = __builtin_amdgcn_mfma_f32_16x16x32_bf16(               \
          AF[0][0], bF[jj][0], acc[(i0_)][jj], 0, 0, 0);                      \
      acc[(i0_)][jj] = __builtin_amdgcn_mfma_f32_16x16x32_bf16(               \
          AF[0][1], bF[jj][1], acc[(i0_)][jj], 0, 0, 0);                      \
      acc[(i0_) + 1][jj] = __builtin_amdgcn_mfma_f32_16x16x32_bf16(           \
          AF[1][0], bF[jj][0], acc[(i0_) + 1][jj], 0, 0, 0);                  \
      acc[(i0_) + 1][jj] = __builtin_amdgcn_mfma_f32_16x16x32_bf16(           \
          AF[1][1], bF[jj][1], acc[(i0_) + 1][jj], 0, 0, 0);                  \
    }                                                                         \
    __builtin_amdgcn_s_setprio(0);                                            \
  } while (0)

  STG_A(0, 0); STG_A(0, 1); STG_B(0, 0); STG_B(0, 1);
  asm volatile("s_waitcnt vmcnt(0)\n\ts_barrier" ::: "memory");

  bf16x8 bF[4][2], aP[2][2], aQ[2][2];

  for (int T = 0; T < NT; T++) {
    const unsigned bo = (unsigned)((T & 1) << 16);
#pragma unroll
    for (int j = 0; j < 4; j++) { bF[j][0] = RD_B(bo, j, cK0); bF[j][1] = RD_B(bo, j, cK1); }
    aP[0][0] = RD_A(bo, 0, cK0); aP[0][1] = RD_A(bo, 0, cK1);
    aP[1][0] = RD_A(bo, 1, cK0); aP[1][1] = RD_A(bo, 1, cK1);
    if (T + 1 < NT) { STG_A(T + 1, 0); STG_A(T + 1, 1); STG_B(T + 1, 0); STG_B(T + 1, 1); }
    aQ[0][0] = RD_A(bo, 2, cK0); aQ[0][1] = RD_A(bo, 2, cK1);
    aQ[1][0] = RD_A(bo, 3, cK0); aQ[1][1] = RD_A(bo, 3, cK1);
    MM2(0, aP);
    aP[0][0] = RD_A(bo, 4, cK0); aP[0][1] = RD_A(bo, 4, cK1);
    aP[1][0] = RD_A(bo, 5, cK0); aP[1][1] = RD_A(bo, 5, cK1);
    MM2(2, aQ);
    aQ[0][0] = RD_A(bo, 6, cK0); aQ[0][1] = RD_A(bo, 6, cK1);
    aQ[1][0] = RD_A(bo, 7, cK0); aQ[1][1] = RD_A(bo, 7, cK1);
    MM2(4, aP);
    MM2(6, aQ);
    if (T + 1 < NT) {
      asm volatile("s_waitcnt vmcnt(0)\n\ts_barrier" ::: "memory");
    }
  }
#undef MM2
#undef STG_A
#undef STG_B
#undef RD_A
#undef RD_B

  // ---- epilogue: per-wave XOR-swizzled LDS transpose -> 16B stores ----
  __syncthreads();
  char* eb = smc + (unsigned)(w * 16384);  // wave-private 16KB
#pragma unroll
  for (int j = 0; j < 4; j++) {
    int gn = n0 + wn * 64 + j * 16 + r16;
    float p0 = 0.f, p1 = 0.f;
    if constexpr (EPI == 2) {
      p0 = scale[gn];
      p1 = shift[gn];
    } else {
      p0 = bias[gn];
    }
#pragma unroll
    for (int i = 0; i < 8; i++)
#pragma unroll
      for (int t = 0; t < 4; t++) {
        float v = acc[i][j][t];
        if constexpr (EPI == 0) {
          v += p0;
        } else if constexpr (EPI == 1) {
          v += p0; v = v > 0.f ? v : 0.f;
        } else if constexpr (EPI == 2) {
          v = v * p0 + p1; v = v > 0.f ? v : 0.f;
        } else {
          v += p0; v = v > 0.f ? v : 0.01f * v;
        }
        int row = i * 16 + quad * 4 + t;
        int col = j * 16 + r16;
        *(unsigned short*)(eb + row * 128 + (((col >> 3) ^ (row & 7)) << 4) +
                           ((col & 7) << 1)) = f2b(v);
      }
  }
#pragma unroll
  for (int r8 = 0; r8 < 16; r8++) {
    int row = r8 * 8 + (lane >> 3);
    int chunkG = lane & 7;
    bf16x8 vv = *(const bf16x8*)(eb + row * 128 + ((chunkG ^ (lane >> 3)) << 4));
    int gm = m0 + wm * 128 + row;
    if (gm < M)
      *(bf16x8*)(C + (size_t)gm * ldc + (n0 + wn * 64 + chunkG * 8)) = vv;
  }
}

// ---------------------------------------------------------------------------
// k_gemm8b (PAIR variant): 256x256, BK=32, QUAD-buffered LDS (4x32KB=128KB),
// v7's verified conflict-free swizzle (write chunk (lane&3)^((lane>>3)&3),
// read chunk quad^((r16>>1)&3); measured 0 conflicts). ONE vmcnt(0)+barrier
// per TILE PAIR (128 K-elems, half of v3's rate): pair p computes tiles
// 2p,2p+1 from bufs published at the previous barrier, stages 2p+2,2p+3
// (8 glds) at pair top. t1's B+A(i0-1) pre-read mid-pair (its buffer was
// published one barrier ago -> race-free). Registers = v7's set (~100).
// Requires N%256==0, K%64==0 (NT even).
template <int EPI>
__global__ __launch_bounds__(512, 2) void k_gemm8b(
    const unsigned short* __restrict__ A, const unsigned short* __restrict__ Bt,
    unsigned short* __restrict__ C, const float* __restrict__ bias,
    const float* __restrict__ scale, const float* __restrict__ shift,
    int M, int N, int K, int lda, int ldc) {
  __shared__ __align__(16) unsigned short smem[4][2][256][32];  // 128 KB

  const int tid = threadIdx.x;
  const int w = tid >> 6;   // wave 0..7
  const int lane = tid & 63;
  const int wm = w >> 2;    // 0..1
  const int wn = w & 3;     // 0..3
  const int quad = lane >> 4;
  const int r16 = lane & 15;

  int m0, n0;
  gemm_swizzle256(M, N, m0, n0);

  // staging (v7): 64B rows, 4 chunks; LDS[row][pos] = global chunk pos^f(row)
  const int w16l = w * 16 + (lane >> 2);             // row within 128-row half
  const int csrc = (lane & 3) ^ ((lane >> 3) & 3);   // (lane&3) ^ f(row)
  unsigned offA[2], offB[2];
#pragma unroll
  for (int h = 0; h < 2; h++) {
    int ra = m0 + h * 128 + w16l;
    ra = ra < M ? ra : (M - 1);
    offA[h] = (unsigned)ra * (unsigned)(lda * 2) + (unsigned)(csrc * 16);
    int rb = n0 + h * 128 + w16l;                    // N%256==0
    offB[h] = (unsigned)rb * (unsigned)(K * 2) + (unsigned)(csrc * 16);
  }
  const char* Ac = (const char*)A;
  const char* Bc = (const char*)Bt;
  char* smc = (char*)smem;
  const unsigned wdst = (unsigned)(w * 1024);

#define STG32(T_)                                                             \
  do {                                                                        \
    unsigned kb_ = (unsigned)(T_) * 64u;                                      \
    unsigned db_ = (unsigned)(((T_) & 3) * 32768) + wdst;                     \
    GLOAD_LDS16(Ac + offA[0] + kb_, smc + db_);                               \
    GLOAD_LDS16(Ac + offA[1] + kb_, smc + db_ + 8192u);                       \
    GLOAD_LDS16(Bc + offB[0] + kb_, smc + db_ + 16384u);                      \
    GLOAD_LDS16(Bc + offB[1] + kb_, smc + db_ + 24576u);                      \
  } while (0)

  const unsigned cKq = (unsigned)(((quad ^ ((r16 >> 1) & 3)) & 3) * 16);
  const unsigned rdA = (unsigned)((wm * 128 + r16) * 64) + cKq;
  const unsigned rdB = 16384u + (unsigned)((wn * 64 + r16) * 64) + cKq;

#define RD_A32(so_, i_) (*(const bf16x8*)(smc + (so_) + rdA + (unsigned)((i_)*1024)))
#define RD_B32(so_, j_) (*(const bf16x8*)(smc + (so_) + rdB + (unsigned)((j_)*1024)))

  floatx4 acc[8][4];
#pragma unroll
  for (int i = 0; i < 8; i++)
#pragma unroll
    for (int j = 0; j < 4; j++) acc[i][j] = (floatx4){0.f, 0.f, 0.f, 0.f};

  const int NT = K >> 5;   // even
  const int NP = NT >> 1;  // pairs

#define MM1(i0_, AF, BF)                                                      \
  do {                                                                        \
    __builtin_amdgcn_s_setprio(1);                                            \
    _Pragma("unroll")                                                         \
    for (int jj = 0; jj < 4; jj++) {                                          \
      acc[(i0_)][jj] = __builtin_amdgcn_mfma_f32_16x16x32_bf16(               \
          AF[0], BF[jj], acc[(i0_)][jj], 0, 0, 0);                            \
      acc[(i0_) + 1][jj] = __builtin_amdgcn_mfma_f32_16x16x32_bf16(           \
          AF[1], BF[jj], acc[(i0_) + 1][jj], 0, 0, 0);                        \
    }                                                                         \
    __builtin_amdgcn_s_setprio(0);                                            \
  } while (0)

  // prologue: stage tiles 0,1 (pair 0's operands), land them
  STG32(0);
  STG32(1);
  asm volatile("s_waitcnt vmcnt(0)\n\ts_barrier" ::: "memory");

  bf16x8 bF[4], bG[4], aX[2], aY[2];

  for (int p = 0; p < NP; p++) {
    const int t0 = 2 * p, t1 = 2 * p + 1;
    const unsigned so0 = (unsigned)((t0 & 3) * 32768);
    const unsigned so1 = (unsigned)((t1 & 3) * 32768);
    // top: read t0's B + A(i0-1); stage pair p+1's tiles (other 2 bufs)
#pragma unroll
    for (int j = 0; j < 4; j++) bF[j] = RD_B32(so0, j);
    aX[0] = RD_A32(so0, 0); aX[1] = RD_A32(so0, 1);
    if (p + 1 < NP) { STG32(t0 + 2); STG32(t1 + 2); }
    // t0 clusters
    aY[0] = RD_A32(so0, 2); aY[1] = RD_A32(so0, 3);
    MM1(0, aX, bF);
    aX[0] = RD_A32(so0, 4); aX[1] = RD_A32(so0, 5);
    MM1(2, aY, bF);
    aY[0] = RD_A32(so0, 6); aY[1] = RD_A32(so0, 7);
    MM1(4, aX, bF);
    // pre-read t1 (its buffer was published at the previous barrier)
#pragma unroll
    for (int j = 0; j < 4; j++) bG[j] = RD_B32(so1, j);
    aX[0] = RD_A32(so1, 0); aX[1] = RD_A32(so1, 1);
    MM1(6, aY, bF);
    // t1 clusters
    aY[0] = RD_A32(so1, 2); aY[1] = RD_A32(so1, 3);
    MM1(0, aX, bG);
    aX[0] = RD_A32(so1, 4); aX[1] = RD_A32(so1, 5);
    MM1(2, aY, bG);
    aY[0] = RD_A32(so1, 6); aY[1] = RD_A32(so1, 7);
    MM1(4, aX, bG);
    MM1(6, aY, bG);
    // pair boundary: drain this pair's 8 glds, publish for pair p+1
    if (p + 1 < NP) {
      asm volatile("s_waitcnt vmcnt(0)\n\ts_barrier" ::: "memory");
    }
  }
#undef MM1
#undef STG32
#undef RD_A32
#undef RD_B32

  // ---- epilogue: per-wave XOR-swizzled LDS transpose (v7-verified) ----
  __syncthreads();
  char* eb = smc + (unsigned)(w * 16384);  // wave-private 16KB
#pragma unroll
  for (int j = 0; j < 4; j++) {
    int gn = n0 + wn * 64 + j * 16 + r16;
    float p0 = 0.f, p1 = 0.f;
    if constexpr (EPI == 2) {
      p0 = scale[gn];
      p1 = shift[gn];
    } else {
      p0 = bias[gn];
    }
#pragma unroll
    for (int i = 0; i < 8; i++)
#pragma unroll
      for (int t = 0; t < 4; t++) {
        float v = acc[i][j][t];
        if constexpr (EPI == 0) {
          v += p0;
        } else if constexpr (EPI == 1) {
          v += p0; v = v > 0.f ? v : 0.f;
        } else if constexpr (EPI == 2) {
          v = v * p0 + p1; v = v > 0.f ? v : 0.f;
        } else {
          v += p0; v = v > 0.f ? v : 0.01f * v;
        }
        int row = i * 16 + quad * 4 + t;
        int col = j * 16 + r16;
        *(unsigned short*)(eb + row * 128 + (((col >> 3) ^ (row & 7)) << 4) +
                           ((col & 7) << 1)) = f2b(v);
      }
  }
#pragma unroll
  for (int r8 = 0; r8 < 16; r8++) {
    int row = r8 * 8 + (lane >> 3);
    int chunkG = lane & 7;
    bf16x8 vv = *(const bf16x8*)(eb + row * 128 + ((chunkG ^ (lane >> 3)) << 4));
    int gm = m0 + wm * 128 + row;
    if (gm < M)
      *(bf16x8*)(C + (size_t)gm * ldc + (n0 + wn * 64 + chunkG * 8)) = vv;
  }
}

// ---------------------------------------------------------------------------
extern "C" void kernel_launch(void* const* d_in, const int* in_sizes, int n_in,
                              void* d_out, int out_size, void* d_ws,
                              size_t ws_size, hipStream_t stream) {
  typedef const float* cf;
  cf x = (cf)d_in[0];
  const int* ei = (const int*)d_in[1];
  const int* srcI = ei;
  const int* dstI = ei + NE;
  cf w1a = (cf)d_in[2],  b1a = (cf)d_in[3];
  cf ga = (cf)d_in[4],   bea = (cf)d_in[5];
  cf mna = (cf)d_in[6],  vra = (cf)d_in[7];
  cf w2a = (cf)d_in[8],  b2a = (cf)d_in[9];
  cf w1b = (cf)d_in[10], b1b = (cf)d_in[11];
  cf gb = (cf)d_in[12],  beb = (cf)d_in[13];
  cf mnb = (cf)d_in[14], vrb = (cf)d_in[15];
  cf w2b = (cf)d_in[16], b2b = (cf)d_in[17];
  cf fc_w = (cf)d_in[18], fc_b = (cf)d_in[19];
  cf l1_w = (cf)d_in[20], l1_b = (cf)d_in[21];
  cf l2_w = (cf)d_in[22], l2_b = (cf)d_in[23];
  cf ow = (cf)d_in[24],   ob = (cf)d_in[25];
  float* outf = (float*)d_out;

  // ---- workspace carve-up ----------------------------------------------------
  char* ws = (char*)d_ws;
  size_t off = 0;
  auto carve = [&](size_t bytes) {
    void* p = ws + off;
    off += (bytes + 255) & ~(size_t)255;
    return p;
  };
  unsigned short* wt1ab = (unsigned short*)carve((size_t)DCAT * C_IN * 2);
  unsigned short* wt2a = (unsigned short*)carve((size_t)HID * HID * 2);
  unsigned short* wt2b = (unsigned short*)carve((size_t)HID * HID * 2);
  unsigned short* wtfc = (unsigned short*)carve((size_t)DFC * DCAT * 2);
  unsigned short* wtl1 = (unsigned short*)carve((size_t)DL1 * DFC * 2);
  unsigned short* wtl2 = (unsigned short*)carve((size_t)DFC * DL1 * 2);
  unsigned short* wtout = (unsigned short*)carve((size_t)OUTC * DFC * 2);
  float* scale_ab = (float*)carve(DCAT * 4);
  float* shift_ab = (float*)carve(DCAT * 4);
  unsigned short* h0 = (unsigned short*)carve((size_t)NN * C_IN * 2);

  // phase-1-only CSR arrays, OVERLAID with phase-2 activation buffers
  size_t off_overlay = off;
  int* deg = (int*)carve((size_t)NN * 4);
  int* offs = (int*)carve((size_t)(NN + 1) * 4);
  int* cursor = (int*)carve((size_t)NN * 4);
  int* bsum = (int*)carve(256 * 4);
  int* esrc = (int*)carve((size_t)NE * 4);

  off = off_overlay;
  size_t rem = (ws_size > off + 4096) ? (ws_size - off - 4096) : 0;
  int mchunk = (int)(rem / ((DFC + DL1) * 2));
  if (mchunk > 15104) mchunk = 15104;
  mchunk &= ~127;
  if (mchunk < 128) mchunk = 128;
  unsigned short* bufA = (unsigned short*)carve((size_t)mchunk * DFC * 2);
  unsigned short* bufB = (unsigned short*)carve((size_t)mchunk * DL1 * 2);
  (void)in_sizes; (void)n_in; (void)out_size;

  // ---- phase 0: params + weight transposes ----------------------------------
  k_bnparams<<<2, 256, 0, stream>>>(ga, bea, mna, vra, b1a, scale_ab, shift_ab);
  k_bnparams<<<2, 256, 0, stream>>>(gb, beb, mnb, vrb, b1b, scale_ab + HID,
                                    shift_ab + HID);
  k_transpose<<<dim3(HID / 32, C_IN / 32), 256, 0, stream>>>(w1a, wt1ab, C_IN, HID);
  k_transpose<<<dim3(HID / 32, C_IN / 32), 256, 0, stream>>>(
      w1b, wt1ab + (size_t)HID * C_IN, C_IN, HID);
  k_transpose<<<dim3(HID / 32, HID / 32), 256, 0, stream>>>(w2a, wt2a, HID, HID);
  k_transpose<<<dim3(HID / 32, HID / 32), 256, 0, stream>>>(w2b, wt2b, HID, HID);
  k_transpose<<<dim3(DFC / 32, DCAT / 32), 256, 0, stream>>>(fc_w, wtfc, DCAT, DFC);
  k_transpose<<<dim3(DL1 / 32, DFC / 32), 256, 0, stream>>>(l1_w, wtl1, DFC, DL1);
  k_transpose<<<dim3(DFC / 32, DL1 / 32), 256, 0, stream>>>(l2_w, wtl2, DL1, DFC);
  k_transpose<<<dim3(OUTC / 32, DFC / 32), 256, 0, stream>>>(ow, wtout, DFC, OUTC);

  // ---- phase 1: CSR build + gather aggregation -------------------------------
  const int NB_NODE = (NN + 255) / 256;
  hipMemsetAsync(deg, 0, (size_t)NN * 4, stream);
  k_deg<<<(NE + 255) / 256, 256, 0, stream>>>(dstI, deg);
  k_scan1<<<NB_NODE, 256, 0, stream>>>(deg, offs, bsum);
  k_scan2<<<1, 256, 0, stream>>>(bsum, NB_NODE);
  k_scan3<<<NB_NODE, 256, 0, stream>>>(offs, bsum, cursor);
  k_bucket<<<(NE + 255) / 256, 256, 0, stream>>>(srcI, dstI, cursor, esrc);
  k_agg<<<(NN + 3) / 4, 256, 0, stream>>>((const float2*)x, offs, esrc,
                                          (unsigned int*)h0);

  // ---- phase 2: GEMM chain ---------------------------------------------------
  // var 1 = G (128x256); var 2 = v3 control (BK64); var 3 = pair (BK32 x2)
  auto gemm = [&](int var, int epi, const unsigned short* A,
                  const unsigned short* Bt, unsigned short* Cp, cf bias,
                  const float* sc, const float* sh, int M, int N, int K,
                  int lda, int ldc) {
    if (var == 2) {
      dim3 g(((M + 255) / 256) * (N / 256));
      switch (epi) {
        case 0: k_gemm8<0><<<g, 512, 0, stream>>>(A, Bt, Cp, bias, sc, sh, M, N, K, lda, ldc); break;
        default: k_gemm8<3><<<g, 512, 0, stream>>>(A, Bt, Cp, bias, sc, sh, M, N, K, lda, ldc); break;
      }
    } else if (var == 3) {
      dim3 g(((M + 255) / 256) * (N / 256));
      switch (epi) {
        case 0: k_gemm8b<0><<<g, 512, 0, stream>>>(A, Bt, Cp, bias, sc, sh, M, N, K, lda, ldc); break;
        default: k_gemm8b<3><<<g, 512, 0, stream>>>(A, Bt, Cp, bias, sc, sh, M, N, K, lda, ldc); break;
      }
    } else {
      dim3 g(((M + 127) / 128) * ((N + 255) / 256));
      switch (epi) {
        case 0: k_gemm_g<0><<<g, 256, 0, stream>>>(A, Bt, Cp, bias, sc, sh, M, N, K, lda, ldc); break;
        case 1: k_gemm_g<1><<<g, 256, 0, stream>>>(A, Bt, Cp, bias, sc, sh, M, N, K, lda, ldc); break;
        case 2: k_gemm_g<2><<<g, 256, 0, stream>>>(A, Bt, Cp, bias, sc, sh, M, N, K, lda, ldc); break;
        case 3: k_gemm_g<3><<<g, 256, 0, stream>>>(A, Bt, Cp, bias, sc, sh, M, N, K, lda, ldc); break;
        default: k_gemm_g<4><<<g, 256, 0, stream>>>(A, Bt, Cp, bias, sc, sh, M, N, K, lda, ldc); break;
      }
    }
  };

  for (int m0 = 0; m0 < NN; m0 += mchunk) {
    const int M = (NN - m0 < mchunk) ? (NN - m0) : mchunk;
    const unsigned short* h0c = h0 + (size_t)m0 * C_IN;
    unsigned short* outc = (unsigned short*)(outf + (size_t)m0 * OUTC);
    // fused branch-1: t1 = BN+ReLU(h0 @ [w1a|w1b])  (M x 1024), bufA ld=1024
    gemm(1, 2, h0c, wt1ab, bufA, nullptr, scale_ab, shift_ab, M, DCAT, C_IN, C_IN, DCAT);
    // branch-2a/b: xcat halves (bufB, ld=1024)
    gemm(1, 1, bufA, wt2a, bufB, b2a, nullptr, nullptr, M, HID, HID, DCAT, DCAT);
    gemm(1, 1, bufA + HID, wt2b, bufB + HID, b2b, nullptr, nullptr, M, HID, HID, DCAT, DCAT);
    // head: xcat(bufB,1024) -> hfc(bufA,2048) -> hl1(bufB,4096) -> hl2(bufA,2048) -> out
    gemm(3, 3, bufB, wtfc, bufA, fc_b, nullptr, nullptr, M, DFC, DCAT, DCAT, DFC);
    gemm(2, 0, bufA, wtl1, bufB, l1_b, nullptr, nullptr, M, DL1, DFC, DFC, DL1);   // CONTROL (v3)
    gemm(3, 0, bufB, wtl2, bufA, l2_b, nullptr, nullptr, M, DFC, DL1, DL1, DFC);   // PAIR
    gemm(1, 4, bufA, wtout, outc, ob, nullptr, nullptr, M, OUTC, DFC, DFC, OUTC);
  }
}

// Round 11
// 3094.115 us; speedup vs baseline: 1.3092x; 1.0290x over previous
//
#include <hip/hip_runtime.h>

// ---------------------------------------------------------------------------
// GCNConvNet: 2x GIN conv (shared aggregation) + dense head. fp32 I/O,
// bf16 MFMA internally (harness grants bf16 tolerance).
// Round 19: r18 A/B verdict -- pair variant 277us with FETCH 528MB (2x ideal,
// L2/L3 hit-rate loss from BK32-pair staging) vs v3 control 236us/274MB.
// Structure space now fully measured: v3 (BK64 dbuf, 1 barrier/tile,
// lookahead clusters) is the optimum of this family; LDS-reads, conflicts,
// barrier rate, and co-residency are all exonerated/impossible.
// v10: revert fc/l1/l2 to v3 (verified 3151us config); drop k_gemm8b.
// One safe win: k_gemm_g wave-uniform `active` guard -- for the out layer
// (N=64), waves 1-3 computed entirely-clamped columns (75% padded MFMA).
// Inactive waves still stage A (glds/vmcnt counts unchanged) + barriers,
// but skip B loads, LDS reads, MFMA, epilogue. N>=256 layers unaffected.
// ---------------------------------------------------------------------------

#define NN 60000
#define NE 960000
#define C_IN 128
#define HID 512
#define DCAT 1024
#define DFC 2048
#define DL1 4096
#define OUTC 64

typedef __bf16 bf16x8 __attribute__((ext_vector_type(8)));
typedef float floatx4 __attribute__((ext_vector_type(4)));

__device__ __forceinline__ unsigned short f2b(float f) {
  unsigned int u = __float_as_uint(f);
  unsigned int r = (u + 0x7fffu + ((u >> 16) & 1u)) >> 16;  // RNE, finite inputs
  return (unsigned short)r;
}

// async global->LDS, 16B per lane; LDS dest = wave-uniform base + lane*16
#define GLOAD_LDS16(g, l)                                                     \
  __builtin_amdgcn_global_load_lds(                                           \
      (__attribute__((address_space(1))) void*)(g),                           \
      (__attribute__((address_space(3))) void*)(l), 16, 0, 0)

// ---------------------------------------------------------------------------
__global__ void k_bnparams(const float* __restrict__ g,
                           const float* __restrict__ be,
                           const float* __restrict__ mn,
                           const float* __restrict__ vr,
                           const float* __restrict__ b1,
                           float* __restrict__ scale, float* __restrict__ shift) {
  int i = blockIdx.x * 256 + threadIdx.x;
  if (i < HID) {
    float s = g[i] * rsqrtf(vr[i] + 1e-5f);
    scale[i] = s;
    shift[i] = (b1[i] - mn[i]) * s + be[i];
  }
}

// fp32 [K,N] -> bf16 [N,K] transpose+downcast, 32x32 tiles
__global__ void k_transpose(const float* __restrict__ in,
                            unsigned short* __restrict__ out, int K, int N) {
  __shared__ float t[32][33];
  int n0 = blockIdx.x * 32, k0 = blockIdx.y * 32;
  int tx = threadIdx.x & 31, ty = threadIdx.x >> 5;  // 32 x 8
#pragma unroll
  for (int i = 0; i < 32; i += 8)
    t[ty + i][tx] = in[(size_t)(k0 + ty + i) * N + n0 + tx];
  __syncthreads();
#pragma unroll
  for (int i = 0; i < 32; i += 8)
    out[(size_t)(n0 + ty + i) * K + k0 + tx] = f2b(t[tx][ty + i]);
}

// ---------------------------------------------------------------------------
// CSR build: deg -> exclusive scan (3 kernels) -> bucket src ids -> gather.
__global__ void k_deg(const int* __restrict__ dst, int* __restrict__ deg) {
  int e = blockIdx.x * 256 + threadIdx.x;
  if (e < NE) atomicAdd(&deg[dst[e]], 1);
}

__global__ void k_scan1(const int* __restrict__ deg, int* __restrict__ offs,
                        int* __restrict__ bsum) {
  __shared__ int t[256];
  int i = blockIdx.x * 256 + threadIdx.x;
  int v = (i < NN) ? deg[i] : 0;
  t[threadIdx.x] = v;
  __syncthreads();
#pragma unroll
  for (int d = 1; d < 256; d <<= 1) {
    int add = (threadIdx.x >= d) ? t[threadIdx.x - d] : 0;
    __syncthreads();
    t[threadIdx.x] += add;
    __syncthreads();
  }
  if (i < NN) offs[i] = t[threadIdx.x] - v;
  if (threadIdx.x == 255) bsum[blockIdx.x] = t[255];
}

__global__ void k_scan2(int* __restrict__ bsum, int nb) {
  __shared__ int t[256];
  int v = (threadIdx.x < nb) ? bsum[threadIdx.x] : 0;
  t[threadIdx.x] = v;
  __syncthreads();
#pragma unroll
  for (int d = 1; d < 256; d <<= 1) {
    int add = (threadIdx.x >= d) ? t[threadIdx.x - d] : 0;
    __syncthreads();
    t[threadIdx.x] += add;
    __syncthreads();
  }
  if (threadIdx.x < nb) bsum[threadIdx.x] = t[threadIdx.x] - v;
}

__global__ void k_scan3(int* __restrict__ offs, const int* __restrict__ bsum,
                        int* __restrict__ cursor) {
  int i = blockIdx.x * 256 + threadIdx.x;
  if (i < NN) {
    int o = offs[i] + bsum[blockIdx.x];
    offs[i] = o;
    cursor[i] = o;
  }
  if (i == 0) offs[NN] = NE;
}

__global__ void k_bucket(const int* __restrict__ src, const int* __restrict__ dst,
                         int* __restrict__ cursor, int* __restrict__ esrc) {
  int e = blockIdx.x * 256 + threadIdx.x;
  if (e < NE) {
    int slot = atomicAdd(&cursor[dst[e]], 1);
    esrc[slot] = src[e];
  }
}

// one wave per node: h0[node] = bf16(x[node] + sum_j x[esrc[j]]), f32 accum
__global__ void k_agg(const float2* __restrict__ x2, const int* __restrict__ offs,
                      const int* __restrict__ esrc, unsigned int* __restrict__ h0u) {
  int node = blockIdx.x * 4 + (threadIdx.x >> 6);
  if (node >= NN) return;
  int lane = threadIdx.x & 63;
  int beg = offs[node], end = offs[node + 1];
  float2 acc = x2[(size_t)node * 64 + lane];
  for (int j = beg; j < end; j++) {
    int s = esrc[j];  // wave-uniform -> broadcast load
    float2 v = x2[(size_t)s * 64 + lane];
    acc.x += v.x;
    acc.y += v.y;
  }
  h0u[(size_t)node * 64 + lane] =
      (unsigned)f2b(acc.x) | ((unsigned)f2b(acc.y) << 16);
}

// ---------------------------------------------------------------------------
// shared epilogue (k_gemm_g): C/D layout col=lane&15, row=quad*4+reg
template <int EPI>
__device__ __forceinline__ void gemm_epilogue(
    floatx4 (&acc)[8][4], unsigned short* C, const float* bias,
    const float* scale, const float* shift, int M, int N, int ldc, int m0,
    int n0, int w, int quad, int r16) {
#pragma unroll
  for (int j = 0; j < 4; j++) {
    int gn = n0 + w * 64 + j * 16 + r16;
    int cn = gn < N ? gn : 0;
    float p0, p1 = 0.f;
    if constexpr (EPI == 2) {
      p0 = scale[cn];
      p1 = shift[cn];
    } else {
      p0 = bias[cn];
    }
#pragma unroll
    for (int i = 0; i < 8; i++) {
#pragma unroll
      for (int t = 0; t < 4; t++) {
        int gm = m0 + i * 16 + quad * 4 + t;
        if (gm < M && gn < N) {
          float v = acc[i][j][t];
          if constexpr (EPI == 0) {
            v += p0;
            C[(size_t)gm * ldc + gn] = f2b(v);
          } else if constexpr (EPI == 1) {
            v += p0; v = v > 0.f ? v : 0.f;
            C[(size_t)gm * ldc + gn] = f2b(v);
          } else if constexpr (EPI == 2) {
            v = v * p0 + p1; v = v > 0.f ? v : 0.f;
            C[(size_t)gm * ldc + gn] = f2b(v);
          } else if constexpr (EPI == 3) {
            v += p0; v = v > 0.f ? v : 0.01f * v;
            C[(size_t)gm * ldc + gn] = f2b(v);
          } else {  // sigmoid -> fp32 network output
            v += p0;
            v = 1.f / (1.f + __expf(-v));
            ((float*)C)[(size_t)gm * ldc + gn] = v;
          }
        }
      }
    }
  }
}

__device__ __forceinline__ void gemm_swizzle(int M, int N, int& m0, int& n0) {
  const int mt_total = (M + 127) >> 7, nt_total = (N + 255) >> 8;
  int mt, nt;
  if ((nt_total & 7) == 0) {
    const int ntpx = nt_total >> 3;
    const int x = blockIdx.x & 7;
    const int s = blockIdx.x >> 3;
    nt = x * ntpx + (s % ntpx);
    mt = s / ntpx;
  } else {
    const int GM = 8;
    const int full = (mt_total / GM) * GM;
    const int boundary = full * nt_total;
    int id = blockIdx.x;
    if (id < boundary) {
      int per_group = GM * nt_total;
      int g = id / per_group, r = id % per_group;
      mt = g * GM + r % GM;
      nt = r / GM;
    } else {
      int r = id - boundary, gm = mt_total - full;
      mt = full + r % gm;
      nt = r / gm;
    }
  }
  m0 = mt << 7;
  n0 = nt << 8;
}

__device__ __forceinline__ void gemm_swizzle256(int M, int N, int& m0, int& n0) {
  const int mt_total = (M + 255) >> 8, nt_total = N >> 8;
  int mt, nt;
  if ((nt_total & 7) == 0) {
    const int ntpx = nt_total >> 3;
    const int x = blockIdx.x & 7;
    const int s = blockIdx.x >> 3;
    nt = x * ntpx + (s % ntpx);
    mt = s / ntpx;
  } else {
    const int GM = 8;
    const int full = (mt_total / GM) * GM;
    const int boundary = full * nt_total;
    int id = blockIdx.x;
    if (id < boundary) {
      int per_group = GM * nt_total;
      int g = id / per_group, r = id % per_group;
      mt = g * GM + r % GM;
      nt = r / GM;
    } else {
      int r = id - boundary, gm = mt_total - full;
      mt = full + r % gm;
      nt = r / gm;
    }
  }
  m0 = mt << 8;
  n0 = nt << 8;
}

// ---------------------------------------------------------------------------
// k_gemm_g (r8 verified): B direct global->reg; A via 4-stage glds pipeline,
// prefetch distance 3. Used for small layers (K=128, K=512, N=64 out).
// r19: wave-uniform `active` guard -- waves whose 64-col slice lies entirely
// past N skip B loads / LDS reads / MFMA / epilogue (75% of the N=64 out
// layer's padded work). They still stage A (glds/vmcnt counts unchanged)
// and hit every barrier. N>=256 layers: guard uniformly true, no change.
template <int EPI>
__global__ __launch_bounds__(256, 2) void k_gemm_g(
    const unsigned short* __restrict__ A, const unsigned short* __restrict__ Bt,
    unsigned short* __restrict__ C, const float* __restrict__ bias,
    const float* __restrict__ scale, const float* __restrict__ shift,
    int M, int N, int K, int lda, int ldc) {
  __shared__ __align__(16) unsigned short lsA[4][4][128][8];  // 32 KB

  const int tid = threadIdx.x;
  const int w = tid >> 6;
  const int lane = tid & 63;
  const int quad = lane >> 4;
  const int r16 = lane & 15;

  int m0, n0;
  gemm_swizzle(M, N, m0, n0);

  const bool active = (n0 + w * 64) < N;  // wave-uniform

  const int ra0 = min(m0 + lane, M - 1);
  const int ra1 = min(m0 + 64 + lane, M - 1);
  const unsigned short* pA0 = A + (size_t)ra0 * lda + w * 8;
  const unsigned short* pA1 = A + (size_t)ra1 * lda + w * 8;
  const unsigned short* pB[4];
#pragma unroll
  for (int j = 0; j < 4; j++) {
    int rb = min(n0 + w * 64 + j * 16 + r16, N - 1);
    pB[j] = Bt + (size_t)rb * K + quad * 8;
  }

  floatx4 acc[8][4];
#pragma unroll
  for (int i = 0; i < 8; i++)
#pragma unroll
    for (int j = 0; j < 4; j++) acc[i][j] = (floatx4){0.f, 0.f, 0.f, 0.f};

  const int niter = K >> 5;

#define ISSUE_A(st)                                                           \
  do {                                                                        \
    GLOAD_LDS16(pA0, &lsA[st][w][0][0]);                                      \
    GLOAD_LDS16(pA1, &lsA[st][w][64][0]);                                     \
    pA0 += 32; pA1 += 32;                                                     \
  } while (0)

  ISSUE_A(0);
  if (niter > 1) ISSUE_A(1);
  if (niter > 2) ISSUE_A(2);
  bf16x8 bcur[4], bnxt[4];
  if (active) {
#pragma unroll
    for (int j = 0; j < 4; j++) {
      bcur[j] = *(const bf16x8*)pB[j];
      pB[j] += 32;
    }
  }

  int st = 0;
  for (int t = 0; t < niter; t++) {
    if (t + 2 < niter) {
      asm volatile("s_waitcnt vmcnt(8)\n\ts_barrier" ::: "memory");
    } else if (t + 1 < niter) {
      asm volatile("s_waitcnt vmcnt(6)\n\ts_barrier" ::: "memory");
    } else {
      asm volatile("s_waitcnt vmcnt(4)\n\ts_barrier" ::: "memory");
    }
    if (t + 3 < niter) {
      int s3 = st + 3;
      if (s3 >= 4) s3 -= 4;
      ISSUE_A(s3);
    }
    if (active) {
      if (t + 1 < niter) {
#pragma unroll
        for (int j = 0; j < 4; j++) {
          bnxt[j] = *(const bf16x8*)pB[j];
          pB[j] += 32;
        }
      }

      bf16x8 af[8];
#pragma unroll
      for (int i = 0; i < 8; i++)
        af[i] = *(const bf16x8*)&lsA[st][quad][i * 16 + r16][0];
#pragma unroll
      for (int j = 0; j < 4; j++)
#pragma unroll
        for (int i = 0; i < 8; i++)
          acc[i][j] = __builtin_amdgcn_mfma_f32_16x16x32_bf16(af[i], bcur[j],
                                                              acc[i][j], 0, 0, 0);
#pragma unroll
      for (int j = 0; j < 4; j++) bcur[j] = bnxt[j];
    }
    st = (st + 1) & 3;
  }
#undef ISSUE_A

  if (active)
    gemm_epilogue<EPI>(acc, C, bias, scale, shift, M, N, ldc, m0, n0, w, quad, r16);
}

// ---------------------------------------------------------------------------
// k_gemm8 (r12/v3, verified 236us l1, structure optimum of this family):
// 256x256, BK=64, 8 waves, 128KB A+B dbuf, XOR chunk swizzle (measured 0
// conflicts), ONE vmcnt(0)+barrier per BK64 tile, 4 MFMA clusters with
// 1-cluster-lookahead A reads. Epilogue: per-wave XOR-swizzled LDS
// transpose -> 16B coalesced C stores (WRITE_SIZE ideal).
template <int EPI>
__global__ __launch_bounds__(512, 2) void k_gemm8(
    const unsigned short* __restrict__ A, const unsigned short* __restrict__ Bt,
    unsigned short* __restrict__ C, const float* __restrict__ bias,
    const float* __restrict__ scale, const float* __restrict__ shift,
    int M, int N, int K, int lda, int ldc) {
  __shared__ __align__(16) unsigned short smem[2][2][256][64];  // 128 KB

  const int tid = threadIdx.x;
  const int w = tid >> 6;   // wave 0..7
  const int lane = tid & 63;
  const int wm = w >> 2;    // 0..1  (M half: rows wm*128..)
  const int wn = w & 3;     // 0..3  (N quarter: cols wn*64..)
  const int quad = lane >> 4;
  const int r16 = lane & 15;

  int m0, n0;
  gemm_swizzle256(M, N, m0, n0);

  const int w8l = w * 8 + (lane >> 3);               // row within 64-row q-block
  const int csrc = (lane & 7) ^ ((lane >> 3) & 7);   // source chunk for lane
  unsigned offA[2][2], offB[2][2];                   // byte offsets
#pragma unroll
  for (int h = 0; h < 2; h++)
#pragma unroll
    for (int q = 0; q < 2; q++) {
      int ra = m0 + h * 128 + q * 64 + w8l;
      ra = ra < M ? ra : (M - 1);
      offA[h][q] = (unsigned)ra * (unsigned)(lda * 2) + (unsigned)(csrc * 16);
      int rb = n0 + h * 128 + q * 64 + w8l;          // N%256==0: no clamp
      offB[h][q] = (unsigned)rb * (unsigned)(K * 2) + (unsigned)(csrc * 16);
    }
  const char* Ac = (const char*)A;
  const char* Bc = (const char*)Bt;
  char* smc = (char*)smem;
  const unsigned wdst = (unsigned)(w * 1024);  // wave's 8-row slice (8*128 B)

#define STG_A(T_, h_)                                                          \
  do {                                                                         \
    unsigned kb_ = (unsigned)(T_) * 128u;                                      \
    unsigned db_ = (unsigned)(((T_) & 1) << 16) + (unsigned)((h_) * 16384) + wdst; \
    GLOAD_LDS16(Ac + offA[h_][0] + kb_, smc + db_);                            \
    GLOAD_LDS16(Ac + offA[h_][1] + kb_, smc + db_ + 8192u);                    \
  } while (0)
#define STG_B(T_, h_)                                                          \
  do {                                                                         \
    unsigned kb_ = (unsigned)(T_) * 128u;                                      \
    unsigned db_ = (unsigned)(((T_) & 1) << 16) + 32768u +                     \
                   (unsigned)((h_) * 16384) + wdst;                            \
    GLOAD_LDS16(Bc + offB[h_][0] + kb_, smc + db_);                            \
    GLOAD_LDS16(Bc + offB[h_][1] + kb_, smc + db_ + 8192u);                    \
  } while (0)

  const int swz = r16 & 7;
  const unsigned cK0 = (unsigned)(((quad) ^ swz) * 16);       // ks=0
  const unsigned cK1 = (unsigned)(((4 + quad) ^ swz) * 16);   // ks=1
  const unsigned rdA = (unsigned)((wm * 128 + r16) * 128);
  const unsigned rdB = 32768u + (unsigned)((wn * 64 + r16) * 128);

#define RD_A(bo_, i_, c_) (*(const bf16x8*)(smc + (bo_) + rdA + (unsigned)((i_)*2048) + (c_)))
#define RD_B(bo_, j_, c_) (*(const bf16x8*)(smc + (bo_) + rdB + (unsigned)((j_)*2048) + (c_)))

  floatx4 acc[8][4];
#pragma unroll
  for (int i = 0; i < 8; i++)
#pragma unroll
    for (int j = 0; j < 4; j++) acc[i][j] = (floatx4){0.f, 0.f, 0.f, 0.f};

  const int NT = K >> 6;

#define MM2(i0_, AF)                                                          \
  do {                                                                        \
    __builtin_amdgcn_s_setprio(1);                                            \
    _Pragma("unroll")                                                         \
    for (int jj = 0; jj < 4; jj++) {                                          \
      acc[(i0_)][jj] = __builtin_amdgcn_mfma_f32_16x16x32_bf16(               \
          AF[0][0], bF[jj][0], acc[(i0_)][jj], 0, 0, 0);                      \
      acc[(i0_)][jj] = __builtin_amdgcn_mfma_f32_16x16x32_bf16(               \
          AF[0][1], bF[jj][1], acc[(i0_)][jj], 0, 0, 0);                      \
      acc[(i0_) + 1][jj] = __builtin_amdgcn_mfma_f32_16x16x32_bf16(           \
          AF[1][0], bF[jj][0], acc[(i0_) + 1][jj], 0, 0, 0);                  \
      acc[(i0_) + 1][jj] = __builtin_amdgcn_mfma_f32_16x16x32_bf16(           \
          AF[1][1], bF[jj][1], acc[(i0_) + 1][jj], 0, 0, 0);                  \
    }                                                                         \
    __builtin_amdgcn_s_setprio(0);                                            \
  } while (0)

  STG_A(0, 0); STG_A(0, 1); STG_B(0, 0); STG_B(0, 1);
  asm volatile("s_waitcnt vmcnt(0)\n\ts_barrier" ::: "memory");

  bf16x8 bF[4][2], aP[2][2], aQ[2][2];

  for (int T = 0; T < NT; T++) {
    const unsigned bo = (unsigned)((T & 1) << 16);
#pragma unroll
    for (int j = 0; j < 4; j++) { bF[j][0] = RD_B(bo, j, cK0); bF[j][1] = RD_B(bo, j, cK1); }
    aP[0][0] = RD_A(bo, 0, cK0); aP[0][1] = RD_A(bo, 0, cK1);
    aP[1][0] = RD_A(bo, 1, cK0); aP[1][1] = RD_A(bo, 1, cK1);
    if (T + 1 < NT) { STG_A(T + 1, 0); STG_A(T + 1, 1); STG_B(T + 1, 0); STG_B(T + 1, 1); }
    aQ[0][0] = RD_A(bo, 2, cK0); aQ[0][1] = RD_A(bo, 2, cK1);
    aQ[1][0] = RD_A(bo, 3, cK0); aQ[1][1] = RD_A(bo, 3, cK1);
    MM2(0, aP);
    aP[0][0] = RD_A(bo, 4, cK0); aP[0][1] = RD_A(bo, 4, cK1);
    aP[1][0] = RD_A(bo, 5, cK0); aP[1][1] = RD_A(bo, 5, cK1);
    MM2(2, aQ);
    aQ[0][0] = RD_A(bo, 6, cK0); aQ[0][1] = RD_A(bo, 6, cK1);
    aQ[1][0] = RD_A(bo, 7, cK0); aQ[1][1] = RD_A(bo, 7, cK1);
    MM2(4, aP);
    MM2(6, aQ);
    if (T + 1 < NT) {
      asm volatile("s_waitcnt vmcnt(0)\n\ts_barrier" ::: "memory");
    }
  }
#undef MM2
#undef STG_A
#undef STG_B
#undef RD_A
#undef RD_B

  // ---- epilogue: per-wave XOR-swizzled LDS transpose -> 16B stores ----
  __syncthreads();
  char* eb = smc + (unsigned)(w * 16384);  // wave-private 16KB
#pragma unroll
  for (int j = 0; j < 4; j++) {
    int gn = n0 + wn * 64 + j * 16 + r16;
    float p0 = 0.f, p1 = 0.f;
    if constexpr (EPI == 2) {
      p0 = scale[gn];
      p1 = shift[gn];
    } else {
      p0 = bias[gn];
    }
#pragma unroll
    for (int i = 0; i < 8; i++)
#pragma unroll
      for (int t = 0; t < 4; t++) {
        float v = acc[i][j][t];
        if constexpr (EPI == 0) {
          v += p0;
        } else if constexpr (EPI == 1) {
          v += p0; v = v > 0.f ? v : 0.f;
        } else if constexpr (EPI == 2) {
          v = v * p0 + p1; v = v > 0.f ? v : 0.f;
        } else {
          v += p0; v = v > 0.f ? v : 0.01f * v;
        }
        int row = i * 16 + quad * 4 + t;
        int col = j * 16 + r16;
        *(unsigned short*)(eb + row * 128 + (((col >> 3) ^ (row & 7)) << 4) +
                           ((col & 7) << 1)) = f2b(v);
      }
  }
#pragma unroll
  for (int r8 = 0; r8 < 16; r8++) {
    int row = r8 * 8 + (lane >> 3);
    int chunkG = lane & 7;
    bf16x8 vv = *(const bf16x8*)(eb + row * 128 + ((chunkG ^ (lane >> 3)) << 4));
    int gm = m0 + wm * 128 + row;
    if (gm < M)
      *(bf16x8*)(C + (size_t)gm * ldc + (n0 + wn * 64 + chunkG * 8)) = vv;
  }
}

// ---------------------------------------------------------------------------
extern "C" void kernel_launch(void* const* d_in, const int* in_sizes, int n_in,
                              void* d_out, int out_size, void* d_ws,
                              size_t ws_size, hipStream_t stream) {
  typedef const float* cf;
  cf x = (cf)d_in[0];
  const int* ei = (const int*)d_in[1];
  const int* srcI = ei;
  const int* dstI = ei + NE;
  cf w1a = (cf)d_in[2],  b1a = (cf)d_in[3];
  cf ga = (cf)d_in[4],   bea = (cf)d_in[5];
  cf mna = (cf)d_in[6],  vra = (cf)d_in[7];
  cf w2a = (cf)d_in[8],  b2a = (cf)d_in[9];
  cf w1b = (cf)d_in[10], b1b = (cf)d_in[11];
  cf gb = (cf)d_in[12],  beb = (cf)d_in[13];
  cf mnb = (cf)d_in[14], vrb = (cf)d_in[15];
  cf w2b = (cf)d_in[16], b2b = (cf)d_in[17];
  cf fc_w = (cf)d_in[18], fc_b = (cf)d_in[19];
  cf l1_w = (cf)d_in[20], l1_b = (cf)d_in[21];
  cf l2_w = (cf)d_in[22], l2_b = (cf)d_in[23];
  cf ow = (cf)d_in[24],   ob = (cf)d_in[25];
  float* outf = (float*)d_out;

  // ---- workspace carve-up ----------------------------------------------------
  char* ws = (char*)d_ws;
  size_t off = 0;
  auto carve = [&](size_t bytes) {
    void* p = ws + off;
    off += (bytes + 255) & ~(size_t)255;
    return p;
  };
  unsigned short* wt1ab = (unsigned short*)carve((size_t)DCAT * C_IN * 2);
  unsigned short* wt2a = (unsigned short*)carve((size_t)HID * HID * 2);
  unsigned short* wt2b = (unsigned short*)carve((size_t)HID * HID * 2);
  unsigned short* wtfc = (unsigned short*)carve((size_t)DFC * DCAT * 2);
  unsigned short* wtl1 = (unsigned short*)carve((size_t)DL1 * DFC * 2);
  unsigned short* wtl2 = (unsigned short*)carve((size_t)DFC * DL1 * 2);
  unsigned short* wtout = (unsigned short*)carve((size_t)OUTC * DFC * 2);
  float* scale_ab = (float*)carve(DCAT * 4);
  float* shift_ab = (float*)carve(DCAT * 4);
  unsigned short* h0 = (unsigned short*)carve((size_t)NN * C_IN * 2);

  // phase-1-only CSR arrays, OVERLAID with phase-2 activation buffers
  size_t off_overlay = off;
  int* deg = (int*)carve((size_t)NN * 4);
  int* offs = (int*)carve((size_t)(NN + 1) * 4);
  int* cursor = (int*)carve((size_t)NN * 4);
  int* bsum = (int*)carve(256 * 4);
  int* esrc = (int*)carve((size_t)NE * 4);

  off = off_overlay;
  size_t rem = (ws_size > off + 4096) ? (ws_size - off - 4096) : 0;
  int mchunk = (int)(rem / ((DFC + DL1) * 2));
  if (mchunk > 15104) mchunk = 15104;
  mchunk &= ~127;
  if (mchunk < 128) mchunk = 128;
  unsigned short* bufA = (unsigned short*)carve((size_t)mchunk * DFC * 2);
  unsigned short* bufB = (unsigned short*)carve((size_t)mchunk * DL1 * 2);
  (void)in_sizes; (void)n_in; (void)out_size;

  // ---- phase 0: params + weight transposes ----------------------------------
  k_bnparams<<<2, 256, 0, stream>>>(ga, bea, mna, vra, b1a, scale_ab, shift_ab);
  k_bnparams<<<2, 256, 0, stream>>>(gb, beb, mnb, vrb, b1b, scale_ab + HID,
                                    shift_ab + HID);
  k_transpose<<<dim3(HID / 32, C_IN / 32), 256, 0, stream>>>(w1a, wt1ab, C_IN, HID);
  k_transpose<<<dim3(HID / 32, C_IN / 32), 256, 0, stream>>>(
      w1b, wt1ab + (size_t)HID * C_IN, C_IN, HID);
  k_transpose<<<dim3(HID / 32, HID / 32), 256, 0, stream>>>(w2a, wt2a, HID, HID);
  k_transpose<<<dim3(HID / 32, HID / 32), 256, 0, stream>>>(w2b, wt2b, HID, HID);
  k_transpose<<<dim3(DFC / 32, DCAT / 32), 256, 0, stream>>>(fc_w, wtfc, DCAT, DFC);
  k_transpose<<<dim3(DL1 / 32, DFC / 32), 256, 0, stream>>>(l1_w, wtl1, DFC, DL1);
  k_transpose<<<dim3(DFC / 32, DL1 / 32), 256, 0, stream>>>(l2_w, wtl2, DL1, DFC);
  k_transpose<<<dim3(OUTC / 32, DFC / 32), 256, 0, stream>>>(ow, wtout, DFC, OUTC);

  // ---- phase 1: CSR build + gather aggregation -------------------------------
  const int NB_NODE = (NN + 255) / 256;
  hipMemsetAsync(deg, 0, (size_t)NN * 4, stream);
  k_deg<<<(NE + 255) / 256, 256, 0, stream>>>(dstI, deg);
  k_scan1<<<NB_NODE, 256, 0, stream>>>(deg, offs, bsum);
  k_scan2<<<1, 256, 0, stream>>>(bsum, NB_NODE);
  k_scan3<<<NB_NODE, 256, 0, stream>>>(offs, bsum, cursor);
  k_bucket<<<(NE + 255) / 256, 256, 0, stream>>>(srcI, dstI, cursor, esrc);
  k_agg<<<(NN + 3) / 4, 256, 0, stream>>>((const float2*)x, offs, esrc,
                                          (unsigned int*)h0);

  // ---- phase 2: GEMM chain ---------------------------------------------------
  // var 1 = G (128x256, B-direct);  var 2 = v3 256x256 (N%256==0, K%64==0)
  auto gemm = [&](int var, int epi, const unsigned short* A,
                  const unsigned short* Bt, unsigned short* Cp, cf bias,
                  const float* sc, const float* sh, int M, int N, int K,
                  int lda, int ldc) {
    if (var == 2) {
      dim3 g(((M + 255) / 256) * (N / 256));
      switch (epi) {
        case 0: k_gemm8<0><<<g, 512, 0, stream>>>(A, Bt, Cp, bias, sc, sh, M, N, K, lda, ldc); break;
        default: k_gemm8<3><<<g, 512, 0, stream>>>(A, Bt, Cp, bias, sc, sh, M, N, K, lda, ldc); break;
      }
    } else {
      dim3 g(((M + 127) / 128) * ((N + 255) / 256));
      switch (epi) {
        case 0: k_gemm_g<0><<<g, 256, 0, stream>>>(A, Bt, Cp, bias, sc, sh, M, N, K, lda, ldc); break;
        case 1: k_gemm_g<1><<<g, 256, 0, stream>>>(A, Bt, Cp, bias, sc, sh, M, N, K, lda, ldc); break;
        case 2: k_gemm_g<2><<<g, 256, 0, stream>>>(A, Bt, Cp, bias, sc, sh, M, N, K, lda, ldc); break;
        case 3: k_gemm_g<3><<<g, 256, 0, stream>>>(A, Bt, Cp, bias, sc, sh, M, N, K, lda, ldc); break;
        default: k_gemm_g<4><<<g, 256, 0, stream>>>(A, Bt, Cp, bias, sc, sh, M, N, K, lda, ldc); break;
      }
    }
  };

  for (int m0 = 0; m0 < NN; m0 += mchunk) {
    const int M = (NN - m0 < mchunk) ? (NN - m0) : mchunk;
    const unsigned short* h0c = h0 + (size_t)m0 * C_IN;
    unsigned short* outc = (unsigned short*)(outf + (size_t)m0 * OUTC);
    // fused branch-1: t1 = BN+ReLU(h0 @ [w1a|w1b])  (M x 1024), bufA ld=1024
    gemm(1, 2, h0c, wt1ab, bufA, nullptr, scale_ab, shift_ab, M, DCAT, C_IN, C_IN, DCAT);
    // branch-2a/b: xcat halves (bufB, ld=1024)
    gemm(1, 1, bufA, wt2a, bufB, b2a, nullptr, nullptr, M, HID, HID, DCAT, DCAT);
    gemm(1, 1, bufA + HID, wt2b, bufB + HID, b2b, nullptr, nullptr, M, HID, HID, DCAT, DCAT);
    // head: xcat(bufB,1024) -> hfc(bufA,2048) -> hl1(bufB,4096) -> hl2(bufA,2048) -> out
    gemm(2, 3, bufB, wtfc, bufA, fc_b, nullptr, nullptr, M, DFC, DCAT, DCAT, DFC);
    gemm(2, 0, bufA, wtl1, bufB, l1_b, nullptr, nullptr, M, DL1, DFC, DFC, DL1);
    gemm(2, 0, bufB, wtl2, bufA, l2_b, nullptr, nullptr, M, DFC, DL1, DL1, DFC);
    gemm(1, 4, bufA, wtout, outc, ob, nullptr, nullptr, M, OUTC, DFC, DFC, OUTC);
  }
}

// Round 12
// 3029.155 us; speedup vs baseline: 1.3372x; 1.0214x over previous
//
#include <hip/hip_runtime.h>

// ---------------------------------------------------------------------------
// GCNConvNet: 2x GIN conv (shared aggregation) + dense head. fp32 I/O,
// bf16 MFMA internally (harness grants bf16 tolerance).
// Round 20: negative-results ledger complete (conflicts/barrier-rate/
// co-residency/B-direct/BK32 all exonerated or impossible). Remaining lever
// from r12's cost model: the tile-top 12-read burst. v11 = the register-free
// half of v5: boundary (vmcnt(0)+s_barrier) moved BETWEEN C2 and C3; next
// tile's A(i0-1) pre-read into the DEAD aP regs (free after C2) under C3's
// MFMA shadow. B stays at tile top (buffer already published one barrier
// earlier -> no second B set, zero extra registers -- v5's spill mode
// removed). Burst 12 -> 8 reads. Hazards: stage(T+1)@top drained by T's
// pre-C3 barrier (3 clusters ~1860cyc > 900 HBM); stage(T+2)@top-of-T+1
// writes buf T&1 whose last reader (C2 of T) precedes that barrier.
// ---------------------------------------------------------------------------

#define NN 60000
#define NE 960000
#define C_IN 128
#define HID 512
#define DCAT 1024
#define DFC 2048
#define DL1 4096
#define OUTC 64

typedef __bf16 bf16x8 __attribute__((ext_vector_type(8)));
typedef float floatx4 __attribute__((ext_vector_type(4)));

__device__ __forceinline__ unsigned short f2b(float f) {
  unsigned int u = __float_as_uint(f);
  unsigned int r = (u + 0x7fffu + ((u >> 16) & 1u)) >> 16;  // RNE, finite inputs
  return (unsigned short)r;
}

// async global->LDS, 16B per lane; LDS dest = wave-uniform base + lane*16
#define GLOAD_LDS16(g, l)                                                     \
  __builtin_amdgcn_global_load_lds(                                           \
      (__attribute__((address_space(1))) void*)(g),                           \
      (__attribute__((address_space(3))) void*)(l), 16, 0, 0)

// ---------------------------------------------------------------------------
__global__ void k_bnparams(const float* __restrict__ g,
                           const float* __restrict__ be,
                           const float* __restrict__ mn,
                           const float* __restrict__ vr,
                           const float* __restrict__ b1,
                           float* __restrict__ scale, float* __restrict__ shift) {
  int i = blockIdx.x * 256 + threadIdx.x;
  if (i < HID) {
    float s = g[i] * rsqrtf(vr[i] + 1e-5f);
    scale[i] = s;
    shift[i] = (b1[i] - mn[i]) * s + be[i];
  }
}

// fp32 [K,N] -> bf16 [N,K] transpose+downcast, 32x32 tiles
__global__ void k_transpose(const float* __restrict__ in,
                            unsigned short* __restrict__ out, int K, int N) {
  __shared__ float t[32][33];
  int n0 = blockIdx.x * 32, k0 = blockIdx.y * 32;
  int tx = threadIdx.x & 31, ty = threadIdx.x >> 5;  // 32 x 8
#pragma unroll
  for (int i = 0; i < 32; i += 8)
    t[ty + i][tx] = in[(size_t)(k0 + ty + i) * N + n0 + tx];
  __syncthreads();
#pragma unroll
  for (int i = 0; i < 32; i += 8)
    out[(size_t)(n0 + ty + i) * K + k0 + tx] = f2b(t[tx][ty + i]);
}

// ---------------------------------------------------------------------------
// CSR build: deg -> exclusive scan (3 kernels) -> bucket src ids -> gather.
__global__ void k_deg(const int* __restrict__ dst, int* __restrict__ deg) {
  int e = blockIdx.x * 256 + threadIdx.x;
  if (e < NE) atomicAdd(&deg[dst[e]], 1);
}

__global__ void k_scan1(const int* __restrict__ deg, int* __restrict__ offs,
                        int* __restrict__ bsum) {
  __shared__ int t[256];
  int i = blockIdx.x * 256 + threadIdx.x;
  int v = (i < NN) ? deg[i] : 0;
  t[threadIdx.x] = v;
  __syncthreads();
#pragma unroll
  for (int d = 1; d < 256; d <<= 1) {
    int add = (threadIdx.x >= d) ? t[threadIdx.x - d] : 0;
    __syncthreads();
    t[threadIdx.x] += add;
    __syncthreads();
  }
  if (i < NN) offs[i] = t[threadIdx.x] - v;
  if (threadIdx.x == 255) bsum[blockIdx.x] = t[255];
}

__global__ void k_scan2(int* __restrict__ bsum, int nb) {
  __shared__ int t[256];
  int v = (threadIdx.x < nb) ? bsum[threadIdx.x] : 0;
  t[threadIdx.x] = v;
  __syncthreads();
#pragma unroll
  for (int d = 1; d < 256; d <<= 1) {
    int add = (threadIdx.x >= d) ? t[threadIdx.x - d] : 0;
    __syncthreads();
    t[threadIdx.x] += add;
    __syncthreads();
  }
  if (threadIdx.x < nb) bsum[threadIdx.x] = t[threadIdx.x] - v;
}

__global__ void k_scan3(int* __restrict__ offs, const int* __restrict__ bsum,
                        int* __restrict__ cursor) {
  int i = blockIdx.x * 256 + threadIdx.x;
  if (i < NN) {
    int o = offs[i] + bsum[blockIdx.x];
    offs[i] = o;
    cursor[i] = o;
  }
  if (i == 0) offs[NN] = NE;
}

__global__ void k_bucket(const int* __restrict__ src, const int* __restrict__ dst,
                         int* __restrict__ cursor, int* __restrict__ esrc) {
  int e = blockIdx.x * 256 + threadIdx.x;
  if (e < NE) {
    int slot = atomicAdd(&cursor[dst[e]], 1);
    esrc[slot] = src[e];
  }
}

// one wave per node: h0[node] = bf16(x[node] + sum_j x[esrc[j]]), f32 accum
__global__ void k_agg(const float2* __restrict__ x2, const int* __restrict__ offs,
                      const int* __restrict__ esrc, unsigned int* __restrict__ h0u) {
  int node = blockIdx.x * 4 + (threadIdx.x >> 6);
  if (node >= NN) return;
  int lane = threadIdx.x & 63;
  int beg = offs[node], end = offs[node + 1];
  float2 acc = x2[(size_t)node * 64 + lane];
  for (int j = beg; j < end; j++) {
    int s = esrc[j];  // wave-uniform -> broadcast load
    float2 v = x2[(size_t)s * 64 + lane];
    acc.x += v.x;
    acc.y += v.y;
  }
  h0u[(size_t)node * 64 + lane] =
      (unsigned)f2b(acc.x) | ((unsigned)f2b(acc.y) << 16);
}

// ---------------------------------------------------------------------------
// shared epilogue (k_gemm_g): C/D layout col=lane&15, row=quad*4+reg
template <int EPI>
__device__ __forceinline__ void gemm_epilogue(
    floatx4 (&acc)[8][4], unsigned short* C, const float* bias,
    const float* scale, const float* shift, int M, int N, int ldc, int m0,
    int n0, int w, int quad, int r16) {
#pragma unroll
  for (int j = 0; j < 4; j++) {
    int gn = n0 + w * 64 + j * 16 + r16;
    int cn = gn < N ? gn : 0;
    float p0, p1 = 0.f;
    if constexpr (EPI == 2) {
      p0 = scale[cn];
      p1 = shift[cn];
    } else {
      p0 = bias[cn];
    }
#pragma unroll
    for (int i = 0; i < 8; i++) {
#pragma unroll
      for (int t = 0; t < 4; t++) {
        int gm = m0 + i * 16 + quad * 4 + t;
        if (gm < M && gn < N) {
          float v = acc[i][j][t];
          if constexpr (EPI == 0) {
            v += p0;
            C[(size_t)gm * ldc + gn] = f2b(v);
          } else if constexpr (EPI == 1) {
            v += p0; v = v > 0.f ? v : 0.f;
            C[(size_t)gm * ldc + gn] = f2b(v);
          } else if constexpr (EPI == 2) {
            v = v * p0 + p1; v = v > 0.f ? v : 0.f;
            C[(size_t)gm * ldc + gn] = f2b(v);
          } else if constexpr (EPI == 3) {
            v += p0; v = v > 0.f ? v : 0.01f * v;
            C[(size_t)gm * ldc + gn] = f2b(v);
          } else {  // sigmoid -> fp32 network output
            v += p0;
            v = 1.f / (1.f + __expf(-v));
            ((float*)C)[(size_t)gm * ldc + gn] = v;
          }
        }
      }
    }
  }
}

__device__ __forceinline__ void gemm_swizzle(int M, int N, int& m0, int& n0) {
  const int mt_total = (M + 127) >> 7, nt_total = (N + 255) >> 8;
  int mt, nt;
  if ((nt_total & 7) == 0) {
    const int ntpx = nt_total >> 3;
    const int x = blockIdx.x & 7;
    const int s = blockIdx.x >> 3;
    nt = x * ntpx + (s % ntpx);
    mt = s / ntpx;
  } else {
    const int GM = 8;
    const int full = (mt_total / GM) * GM;
    const int boundary = full * nt_total;
    int id = blockIdx.x;
    if (id < boundary) {
      int per_group = GM * nt_total;
      int g = id / per_group, r = id % per_group;
      mt = g * GM + r % GM;
      nt = r / GM;
    } else {
      int r = id - boundary, gm = mt_total - full;
      mt = full + r % gm;
      nt = r / gm;
    }
  }
  m0 = mt << 7;
  n0 = nt << 8;
}

__device__ __forceinline__ void gemm_swizzle256(int M, int N, int& m0, int& n0) {
  const int mt_total = (M + 255) >> 8, nt_total = N >> 8;
  int mt, nt;
  if ((nt_total & 7) == 0) {
    const int ntpx = nt_total >> 3;
    const int x = blockIdx.x & 7;
    const int s = blockIdx.x >> 3;
    nt = x * ntpx + (s % ntpx);
    mt = s / ntpx;
  } else {
    const int GM = 8;
    const int full = (mt_total / GM) * GM;
    const int boundary = full * nt_total;
    int id = blockIdx.x;
    if (id < boundary) {
      int per_group = GM * nt_total;
      int g = id / per_group, r = id % per_group;
      mt = g * GM + r % GM;
      nt = r / GM;
    } else {
      int r = id - boundary, gm = mt_total - full;
      mt = full + r % gm;
      nt = r / gm;
    }
  }
  m0 = mt << 8;
  n0 = nt << 8;
}

// ---------------------------------------------------------------------------
// k_gemm_g (r8 verified): B direct global->reg; A via 4-stage glds pipeline,
// prefetch distance 3. Used for small layers (K=128, K=512, N=64 out).
// r19 `active` guard: waves past N skip B/LDS/MFMA/epilogue (out layer).
template <int EPI>
__global__ __launch_bounds__(256, 2) void k_gemm_g(
    const unsigned short* __restrict__ A, const unsigned short* __restrict__ Bt,
    unsigned short* __restrict__ C, const float* __restrict__ bias,
    const float* __restrict__ scale, const float* __restrict__ shift,
    int M, int N, int K, int lda, int ldc) {
  __shared__ __align__(16) unsigned short lsA[4][4][128][8];  // 32 KB

  const int tid = threadIdx.x;
  const int w = tid >> 6;
  const int lane = tid & 63;
  const int quad = lane >> 4;
  const int r16 = lane & 15;

  int m0, n0;
  gemm_swizzle(M, N, m0, n0);

  const bool active = (n0 + w * 64) < N;  // wave-uniform

  const int ra0 = min(m0 + lane, M - 1);
  const int ra1 = min(m0 + 64 + lane, M - 1);
  const unsigned short* pA0 = A + (size_t)ra0 * lda + w * 8;
  const unsigned short* pA1 = A + (size_t)ra1 * lda + w * 8;
  const unsigned short* pB[4];
#pragma unroll
  for (int j = 0; j < 4; j++) {
    int rb = min(n0 + w * 64 + j * 16 + r16, N - 1);
    pB[j] = Bt + (size_t)rb * K + quad * 8;
  }

  floatx4 acc[8][4];
#pragma unroll
  for (int i = 0; i < 8; i++)
#pragma unroll
    for (int j = 0; j < 4; j++) acc[i][j] = (floatx4){0.f, 0.f, 0.f, 0.f};

  const int niter = K >> 5;

#define ISSUE_A(st)                                                           \
  do {                                                                        \
    GLOAD_LDS16(pA0, &lsA[st][w][0][0]);                                      \
    GLOAD_LDS16(pA1, &lsA[st][w][64][0]);                                     \
    pA0 += 32; pA1 += 32;                                                     \
  } while (0)

  ISSUE_A(0);
  if (niter > 1) ISSUE_A(1);
  if (niter > 2) ISSUE_A(2);
  bf16x8 bcur[4], bnxt[4];
  if (active) {
#pragma unroll
    for (int j = 0; j < 4; j++) {
      bcur[j] = *(const bf16x8*)pB[j];
      pB[j] += 32;
    }
  }

  int st = 0;
  for (int t = 0; t < niter; t++) {
    if (t + 2 < niter) {
      asm volatile("s_waitcnt vmcnt(8)\n\ts_barrier" ::: "memory");
    } else if (t + 1 < niter) {
      asm volatile("s_waitcnt vmcnt(6)\n\ts_barrier" ::: "memory");
    } else {
      asm volatile("s_waitcnt vmcnt(4)\n\ts_barrier" ::: "memory");
    }
    if (t + 3 < niter) {
      int s3 = st + 3;
      if (s3 >= 4) s3 -= 4;
      ISSUE_A(s3);
    }
    if (active) {
      if (t + 1 < niter) {
#pragma unroll
        for (int j = 0; j < 4; j++) {
          bnxt[j] = *(const bf16x8*)pB[j];
          pB[j] += 32;
        }
      }

      bf16x8 af[8];
#pragma unroll
      for (int i = 0; i < 8; i++)
        af[i] = *(const bf16x8*)&lsA[st][quad][i * 16 + r16][0];
#pragma unroll
      for (int j = 0; j < 4; j++)
#pragma unroll
        for (int i = 0; i < 8; i++)
          acc[i][j] = __builtin_amdgcn_mfma_f32_16x16x32_bf16(af[i], bcur[j],
                                                              acc[i][j], 0, 0, 0);
#pragma unroll
      for (int j = 0; j < 4; j++) bcur[j] = bnxt[j];
    }
    st = (st + 1) & 3;
  }
#undef ISSUE_A

  if (active)
    gemm_epilogue<EPI>(acc, C, bias, scale, shift, M, N, ldc, m0, n0, w, quad, r16);
}

// ---------------------------------------------------------------------------
// k_gemm8 v11: 256x256 tile, BK=64, 8 waves, 128KB A+B dbuf, XOR chunk
// swizzle (measured 0 conflicts). ONE barrier per tile, placed BETWEEN C2
// and C3: publishes buf (T+1)&1 before C3, so (a) next tile's A(i0-1) is
// pre-read into the DEAD aP regs under C3's MFMA shadow (zero extra regs),
// (b) tile-top burst shrinks 12 -> 8 reads (B only). Stage T+1 at tile top
// (drained by this tile's pre-C3 barrier, ~3 clusters of slack).
// Epilogue: per-wave XOR-swizzled LDS transpose -> 16B coalesced C stores.
template <int EPI>
__global__ __launch_bounds__(512, 2) void k_gemm8(
    const unsigned short* __restrict__ A, const unsigned short* __restrict__ Bt,
    unsigned short* __restrict__ C, const float* __restrict__ bias,
    const float* __restrict__ scale, const float* __restrict__ shift,
    int M, int N, int K, int lda, int ldc) {
  __shared__ __align__(16) unsigned short smem[2][2][256][64];  // 128 KB

  const int tid = threadIdx.x;
  const int w = tid >> 6;   // wave 0..7
  const int lane = tid & 63;
  const int wm = w >> 2;    // 0..1  (M half: rows wm*128..)
  const int wn = w & 3;     // 0..3  (N quarter: cols wn*64..)
  const int quad = lane >> 4;
  const int r16 = lane & 15;

  int m0, n0;
  gemm_swizzle256(M, N, m0, n0);

  const int w8l = w * 8 + (lane >> 3);               // row within 64-row q-block
  const int csrc = (lane & 7) ^ ((lane >> 3) & 7);   // source chunk for lane
  unsigned offA[2][2], offB[2][2];                   // byte offsets
#pragma unroll
  for (int h = 0; h < 2; h++)
#pragma unroll
    for (int q = 0; q < 2; q++) {
      int ra = m0 + h * 128 + q * 64 + w8l;
      ra = ra < M ? ra : (M - 1);
      offA[h][q] = (unsigned)ra * (unsigned)(lda * 2) + (unsigned)(csrc * 16);
      int rb = n0 + h * 128 + q * 64 + w8l;          // N%256==0: no clamp
      offB[h][q] = (unsigned)rb * (unsigned)(K * 2) + (unsigned)(csrc * 16);
    }
  const char* Ac = (const char*)A;
  const char* Bc = (const char*)Bt;
  char* smc = (char*)smem;
  const unsigned wdst = (unsigned)(w * 1024);  // wave's 8-row slice (8*128 B)

#define STG_A(T_, h_)                                                          \
  do {                                                                         \
    unsigned kb_ = (unsigned)(T_) * 128u;                                      \
    unsigned db_ = (unsigned)(((T_) & 1) << 16) + (unsigned)((h_) * 16384) + wdst; \
    GLOAD_LDS16(Ac + offA[h_][0] + kb_, smc + db_);                            \
    GLOAD_LDS16(Ac + offA[h_][1] + kb_, smc + db_ + 8192u);                    \
  } while (0)
#define STG_B(T_, h_)                                                          \
  do {                                                                         \
    unsigned kb_ = (unsigned)(T_) * 128u;                                      \
    unsigned db_ = (unsigned)(((T_) & 1) << 16) + 32768u +                     \
                   (unsigned)((h_) * 16384) + wdst;                            \
    GLOAD_LDS16(Bc + offB[h_][0] + kb_, smc + db_);                            \
    GLOAD_LDS16(Bc + offB[h_][1] + kb_, smc + db_ + 8192u);                    \
  } while (0)

  const int swz = r16 & 7;
  const unsigned cK0 = (unsigned)(((quad) ^ swz) * 16);       // ks=0
  const unsigned cK1 = (unsigned)(((4 + quad) ^ swz) * 16);   // ks=1
  const unsigned rdA = (unsigned)((wm * 128 + r16) * 128);
  const unsigned rdB = 32768u + (unsigned)((wn * 64 + r16) * 128);

#define RD_A(bo_, i_, c_) (*(const bf16x8*)(smc + (bo_) + rdA + (unsigned)((i_)*2048) + (c_)))
#define RD_B(bo_, j_, c_) (*(const bf16x8*)(smc + (bo_) + rdB + (unsigned)((j_)*2048) + (c_)))

  floatx4 acc[8][4];
#pragma unroll
  for (int i = 0; i < 8; i++)
#pragma unroll
    for (int j = 0; j < 4; j++) acc[i][j] = (floatx4){0.f, 0.f, 0.f, 0.f};

  const int NT = K >> 6;

#define MM2(i0_, AF)                                                          \
  do {                                                                        \
    __builtin_amdgcn_s_setprio(1);                                            \
    _Pragma("unroll")                                                         \
    for (int jj = 0; jj < 4; jj++) {                                          \
      acc[(i0_)][jj] = __builtin_amdgcn_mfma_f32_16x16x32_bf16(               \
          AF[0][0], bF[jj][0], acc[(i0_)][jj], 0, 0, 0);                      \
      acc[(i0_)][jj] = __builtin_amdgcn_mfma_f32_16x16x32_bf16(               \
          AF[0][1], bF[jj][1], acc[(i0_)][jj], 0, 0, 0);                      \
      acc[(i0_) + 1][jj] = __builtin_amdgcn_mfma_f32_16x16x32_bf16(           \
          AF[1][0], bF[jj][0], acc[(i0_) + 1][jj], 0, 0, 0);                  \
      acc[(i0_) + 1][jj] = __builtin_amdgcn_mfma_f32_16x16x32_bf16(           \
          AF[1][1], bF[jj][1], acc[(i0_) + 1][jj], 0, 0, 0);                  \
    }                                                                         \
    __builtin_amdgcn_s_setprio(0);                                            \
  } while (0)

  // ---- prologue: stage tile 0, land it, pre-read its A(i0-1) ----
  STG_A(0, 0); STG_A(0, 1); STG_B(0, 0); STG_B(0, 1);
  asm volatile("s_waitcnt vmcnt(0)\n\ts_barrier" ::: "memory");

  bf16x8 bF[4][2], aP[2][2], aQ[2][2];
  aP[0][0] = RD_A(0u, 0, cK0); aP[0][1] = RD_A(0u, 0, cK1);
  aP[1][0] = RD_A(0u, 1, cK0); aP[1][1] = RD_A(0u, 1, cK1);

  for (int T = 0; T < NT; T++) {
    const unsigned bo = (unsigned)((T & 1) << 16);
    const unsigned bo1 = (unsigned)(((T + 1) & 1) << 16);
    // tile top: B reads (8, buffer published at previous pre-C3 barrier);
    // stage T+1 into the other buffer (last readers finished before that
    // same barrier).
#pragma unroll
    for (int j = 0; j < 4; j++) { bF[j][0] = RD_B(bo, j, cK0); bF[j][1] = RD_B(bo, j, cK1); }
    if (T + 1 < NT) { STG_A(T + 1, 0); STG_A(T + 1, 1); STG_B(T + 1, 0); STG_B(T + 1, 1); }
    // C0: issue A(i2-3); MFMA i0-1 (aP pre-read last tile / prologue)
    aQ[0][0] = RD_A(bo, 2, cK0); aQ[0][1] = RD_A(bo, 2, cK1);
    aQ[1][0] = RD_A(bo, 3, cK0); aQ[1][1] = RD_A(bo, 3, cK1);
    MM2(0, aP);
    // C1: issue A(i4-5); MFMA i2-3
    aP[0][0] = RD_A(bo, 4, cK0); aP[0][1] = RD_A(bo, 4, cK1);
    aP[1][0] = RD_A(bo, 5, cK0); aP[1][1] = RD_A(bo, 5, cK1);
    MM2(2, aQ);
    // C2: issue A(i6-7); MFMA i4-5 (last use of aP this tile)
    aQ[0][0] = RD_A(bo, 6, cK0); aQ[0][1] = RD_A(bo, 6, cK1);
    aQ[1][0] = RD_A(bo, 7, cK0); aQ[1][1] = RD_A(bo, 7, cK1);
    MM2(4, aP);
    // boundary BEFORE C3: drain stage(T+1), publish buf (T+1)&1
    if (T + 1 < NT) {
      asm volatile("s_waitcnt vmcnt(0)\n\ts_barrier" ::: "memory");
      // pre-read next tile's A(i0-1) into dead aP, under C3's MFMA shadow
      aP[0][0] = RD_A(bo1, 0, cK0); aP[0][1] = RD_A(bo1, 0, cK1);
      aP[1][0] = RD_A(bo1, 1, cK0); aP[1][1] = RD_A(bo1, 1, cK1);
    }
    // C3: MFMA i6-7 (pre-reads ride under this cluster)
    MM2(6, aQ);
  }
#undef MM2
#undef STG_A
#undef STG_B
#undef RD_A
#undef RD_B

  // ---- epilogue: per-wave XOR-swizzled LDS transpose -> 16B stores ----
  __syncthreads();
  char* eb = smc + (unsigned)(w * 16384);  // wave-private 16KB
#pragma unroll
  for (int j = 0; j < 4; j++) {
    int gn = n0 + wn * 64 + j * 16 + r16;
    float p0 = 0.f, p1 = 0.f;
    if constexpr (EPI == 2) {
      p0 = scale[gn];
      p1 = shift[gn];
    } else {
      p0 = bias[gn];
    }
#pragma unroll
    for (int i = 0; i < 8; i++)
#pragma unroll
      for (int t = 0; t < 4; t++) {
        float v = acc[i][j][t];
        if constexpr (EPI == 0) {
          v += p0;
        } else if constexpr (EPI == 1) {
          v += p0; v = v > 0.f ? v : 0.f;
        } else if constexpr (EPI == 2) {
          v = v * p0 + p1; v = v > 0.f ? v : 0.f;
        } else {
          v += p0; v = v > 0.f ? v : 0.01f * v;
        }
        int row = i * 16 + quad * 4 + t;
        int col = j * 16 + r16;
        *(unsigned short*)(eb + row * 128 + (((col >> 3) ^ (row & 7)) << 4) +
                           ((col & 7) << 1)) = f2b(v);
      }
  }
#pragma unroll
  for (int r8 = 0; r8 < 16; r8++) {
    int row = r8 * 8 + (lane >> 3);
    int chunkG = lane & 7;
    bf16x8 vv = *(const bf16x8*)(eb + row * 128 + ((chunkG ^ (lane >> 3)) << 4));
    int gm = m0 + wm * 128 + row;
    if (gm < M)
      *(bf16x8*)(C + (size_t)gm * ldc + (n0 + wn * 64 + chunkG * 8)) = vv;
  }
}

// ---------------------------------------------------------------------------
extern "C" void kernel_launch(void* const* d_in, const int* in_sizes, int n_in,
                              void* d_out, int out_size, void* d_ws,
                              size_t ws_size, hipStream_t stream) {
  typedef const float* cf;
  cf x = (cf)d_in[0];
  const int* ei = (const int*)d_in[1];
  const int* srcI = ei;
  const int* dstI = ei + NE;
  cf w1a = (cf)d_in[2],  b1a = (cf)d_in[3];
  cf ga = (cf)d_in[4],   bea = (cf)d_in[5];
  cf mna = (cf)d_in[6],  vra = (cf)d_in[7];
  cf w2a = (cf)d_in[8],  b2a = (cf)d_in[9];
  cf w1b = (cf)d_in[10], b1b = (cf)d_in[11];
  cf gb = (cf)d_in[12],  beb = (cf)d_in[13];
  cf mnb = (cf)d_in[14], vrb = (cf)d_in[15];
  cf w2b = (cf)d_in[16], b2b = (cf)d_in[17];
  cf fc_w = (cf)d_in[18], fc_b = (cf)d_in[19];
  cf l1_w = (cf)d_in[20], l1_b = (cf)d_in[21];
  cf l2_w = (cf)d_in[22], l2_b = (cf)d_in[23];
  cf ow = (cf)d_in[24],   ob = (cf)d_in[25];
  float* outf = (float*)d_out;

  // ---- workspace carve-up ----------------------------------------------------
  char* ws = (char*)d_ws;
  size_t off = 0;
  auto carve = [&](size_t bytes) {
    void* p = ws + off;
    off += (bytes + 255) & ~(size_t)255;
    return p;
  };
  unsigned short* wt1ab = (unsigned short*)carve((size_t)DCAT * C_IN * 2);
  unsigned short* wt2a = (unsigned short*)carve((size_t)HID * HID * 2);
  unsigned short* wt2b = (unsigned short*)carve((size_t)HID * HID * 2);
  unsigned short* wtfc = (unsigned short*)carve((size_t)DFC * DCAT * 2);
  unsigned short* wtl1 = (unsigned short*)carve((size_t)DL1 * DFC * 2);
  unsigned short* wtl2 = (unsigned short*)carve((size_t)DFC * DL1 * 2);
  unsigned short* wtout = (unsigned short*)carve((size_t)OUTC * DFC * 2);
  float* scale_ab = (float*)carve(DCAT * 4);
  float* shift_ab = (float*)carve(DCAT * 4);
  unsigned short* h0 = (unsigned short*)carve((size_t)NN * C_IN * 2);

  // phase-1-only CSR arrays, OVERLAID with phase-2 activation buffers
  size_t off_overlay = off;
  int* deg = (int*)carve((size_t)NN * 4);
  int* offs = (int*)carve((size_t)(NN + 1) * 4);
  int* cursor = (int*)carve((size_t)NN * 4);
  int* bsum = (int*)carve(256 * 4);
  int* esrc = (int*)carve((size_t)NE * 4);

  off = off_overlay;
  size_t rem = (ws_size > off + 4096) ? (ws_size - off - 4096) : 0;
  int mchunk = (int)(rem / ((DFC + DL1) * 2));
  if (mchunk > 15104) mchunk = 15104;
  mchunk &= ~127;
  if (mchunk < 128) mchunk = 128;
  unsigned short* bufA = (unsigned short*)carve((size_t)mchunk * DFC * 2);
  unsigned short* bufB = (unsigned short*)carve((size_t)mchunk * DL1 * 2);
  (void)in_sizes; (void)n_in; (void)out_size;

  // ---- phase 0: params + weight transposes ----------------------------------
  k_bnparams<<<2, 256, 0, stream>>>(ga, bea, mna, vra, b1a, scale_ab, shift_ab);
  k_bnparams<<<2, 256, 0, stream>>>(gb, beb, mnb, vrb, b1b, scale_ab + HID,
                                    shift_ab + HID);
  k_transpose<<<dim3(HID / 32, C_IN / 32), 256, 0, stream>>>(w1a, wt1ab, C_IN, HID);
  k_transpose<<<dim3(HID / 32, C_IN / 32), 256, 0, stream>>>(
      w1b, wt1ab + (size_t)HID * C_IN, C_IN, HID);
  k_transpose<<<dim3(HID / 32, HID / 32), 256, 0, stream>>>(w2a, wt2a, HID, HID);
  k_transpose<<<dim3(HID / 32, HID / 32), 256, 0, stream>>>(w2b, wt2b, HID, HID);
  k_transpose<<<dim3(DFC / 32, DCAT / 32), 256, 0, stream>>>(fc_w, wtfc, DCAT, DFC);
  k_transpose<<<dim3(DL1 / 32, DFC / 32), 256, 0, stream>>>(l1_w, wtl1, DFC, DL1);
  k_transpose<<<dim3(DFC / 32, DL1 / 32), 256, 0, stream>>>(l2_w, wtl2, DL1, DFC);
  k_transpose<<<dim3(OUTC / 32, DFC / 32), 256, 0, stream>>>(ow, wtout, DFC, OUTC);

  // ---- phase 1: CSR build + gather aggregation -------------------------------
  const int NB_NODE = (NN + 255) / 256;
  hipMemsetAsync(deg, 0, (size_t)NN * 4, stream);
  k_deg<<<(NE + 255) / 256, 256, 0, stream>>>(dstI, deg);
  k_scan1<<<NB_NODE, 256, 0, stream>>>(deg, offs, bsum);
  k_scan2<<<1, 256, 0, stream>>>(bsum, NB_NODE);
  k_scan3<<<NB_NODE, 256, 0, stream>>>(offs, bsum, cursor);
  k_bucket<<<(NE + 255) / 256, 256, 0, stream>>>(srcI, dstI, cursor, esrc);
  k_agg<<<(NN + 3) / 4, 256, 0, stream>>>((const float2*)x, offs, esrc,
                                          (unsigned int*)h0);

  // ---- phase 2: GEMM chain ---------------------------------------------------
  // var 1 = G (128x256, B-direct);  var 2 = v11 256x256 (N%256==0, K%64==0)
  auto gemm = [&](int var, int epi, const unsigned short* A,
                  const unsigned short* Bt, unsigned short* Cp, cf bias,
                  const float* sc, const float* sh, int M, int N, int K,
                  int lda, int ldc) {
    if (var == 2) {
      dim3 g(((M + 255) / 256) * (N / 256));
      switch (epi) {
        case 0: k_gemm8<0><<<g, 512, 0, stream>>>(A, Bt, Cp, bias, sc, sh, M, N, K, lda, ldc); break;
        default: k_gemm8<3><<<g, 512, 0, stream>>>(A, Bt, Cp, bias, sc, sh, M, N, K, lda, ldc); break;
      }
    } else {
      dim3 g(((M + 127) / 128) * ((N + 255) / 256));
      switch (epi) {
        case 0: k_gemm_g<0><<<g, 256, 0, stream>>>(A, Bt, Cp, bias, sc, sh, M, N, K, lda, ldc); break;
        case 1: k_gemm_g<1><<<g, 256, 0, stream>>>(A, Bt, Cp, bias, sc, sh, M, N, K, lda, ldc); break;
        case 2: k_gemm_g<2><<<g, 256, 0, stream>>>(A, Bt, Cp, bias, sc, sh, M, N, K, lda, ldc); break;
        case 3: k_gemm_g<3><<<g, 256, 0, stream>>>(A, Bt, Cp, bias, sc, sh, M, N, K, lda, ldc); break;
        default: k_gemm_g<4><<<g, 256, 0, stream>>>(A, Bt, Cp, bias, sc, sh, M, N, K, lda, ldc); break;
      }
    }
  };

  for (int m0 = 0; m0 < NN; m0 += mchunk) {
    const int M = (NN - m0 < mchunk) ? (NN - m0) : mchunk;
    const unsigned short* h0c = h0 + (size_t)m0 * C_IN;
    unsigned short* outc = (unsigned short*)(outf + (size_t)m0 * OUTC);
    // fused branch-1: t1 = BN+ReLU(h0 @ [w1a|w1b])  (M x 1024), bufA ld=1024
    gemm(1, 2, h0c, wt1ab, bufA, nullptr, scale_ab, shift_ab, M, DCAT, C_IN, C_IN, DCAT);
    // branch-2a/b: xcat halves (bufB, ld=1024)
    gemm(1, 1, bufA, wt2a, bufB, b2a, nullptr, nullptr, M, HID, HID, DCAT, DCAT);
    gemm(1, 1, bufA + HID, wt2b, bufB + HID, b2b, nullptr, nullptr, M, HID, HID, DCAT, DCAT);
    // head: xcat(bufB,1024) -> hfc(bufA,2048) -> hl1(bufB,4096) -> hl2(bufA,2048) -> out
    gemm(2, 3, bufB, wtfc, bufA, fc_b, nullptr, nullptr, M, DFC, DCAT, DCAT, DFC);
    gemm(2, 0, bufA, wtl1, bufB, l1_b, nullptr, nullptr, M, DL1, DFC, DFC, DL1);
    gemm(2, 0, bufB, wtl2, bufA, l2_b, nullptr, nullptr, M, DFC, DL1, DL1, DFC);
    gemm(1, 4, bufA, wtout, outc, ob, nullptr, nullptr, M, OUTC, DFC, DFC, OUTC);
  }
}